// Round 4
// baseline (499.163 us; speedup 1.0000x reference)
//
#include <hip/hip_runtime.h>
#include <hip/hip_bf16.h>
#include <math.h>

#define BATCH 8
#define SEQ   2048
#define DIM   512
#define NH    8
#define DHEAD 64
#define FFD   2048
#define TOPQ  39            // ceil(5*ln(2048)) with factor=5, min_k=5 (fixed harness inputs)
#define MROWS (BATCH*SEQ)   // 16384
#define KC    128           // keys per attention partial chunk (one wave)
#define NKC   (SEQ/KC)      // 16
#define PSTR  66            // partial stride: 64 ctx + m + l
#define QPAD  48            // TOPQ padded to 3 MFMA row-tiles

typedef __hip_bfloat16 bf16;
typedef __attribute__((ext_vector_type(8))) short short8;
typedef __attribute__((ext_vector_type(4))) short sh4;
typedef __attribute__((ext_vector_type(4))) float floatx4;

__device__ __forceinline__ float bf2f(short u){
    return __uint_as_float(((unsigned int)(unsigned short)u) << 16);
}
// RNE fp32->bf16 bits (matches hardware convert for finite values)
__device__ __forceinline__ unsigned int f2bf_bits(float f){
    unsigned int u = __float_as_uint(f);
    return (u + 0x7fffu + ((u >> 16) & 1u)) >> 16;
}
// fast gelu (tanh form): |err vs exact erf-gelu| < ~3e-3, << bf16 rounding here
__device__ __forceinline__ float gelu_f(float v){
    float u = v*(0.7978845608028654f + 0.0356774081363f*v*v);
    float e = __expf(2.f*u);
    return 0.5f*v*(2.f - 2.f/(e + 1.f));
}
__device__ __forceinline__ float wave_sum(float v){
    #pragma unroll
    for (int off = 32; off > 0; off >>= 1) v += __shfl_down(v, off);
    return v;
}
__device__ __forceinline__ double wave_sum_d(double v){
    #pragma unroll
    for (int off = 32; off > 0; off >>= 1) v += __shfl_down(v, off);
    return v;
}
// block = 256 threads (4 waves)
__device__ __forceinline__ float block_sum256(float v, float* sbuf){
    v = wave_sum(v);
    if ((threadIdx.x & 63) == 0) sbuf[threadIdx.x >> 6] = v;
    __syncthreads();
    float r = sbuf[0] + sbuf[1] + sbuf[2] + sbuf[3];
    __syncthreads();
    return r;
}
__device__ __forceinline__ double block_sum256d(double v, double* sbuf){
    v = wave_sum_d(v);
    if ((threadIdx.x & 63) == 0) sbuf[threadIdx.x >> 6] = v;
    __syncthreads();
    double r = sbuf[0] + sbuf[1] + sbuf[2] + sbuf[3];
    __syncthreads();
    return r;
}

// async global->LDS, 16 B per lane; LDS dest = wave-uniform base + lane*16
__device__ __forceinline__ void load_lds16(const void* g, void* l){
    auto gp = reinterpret_cast<const uint32_t __attribute__((address_space(1)))*>(
        reinterpret_cast<uintptr_t>(g));
    auto lp = reinterpret_cast<uint32_t __attribute__((address_space(3)))*>(
        reinterpret_cast<uintptr_t>(l));
    __builtin_amdgcn_global_load_lds(gp, lp, 16, 0, 0);
}

// 16x16x16 bf16 MFMA (K=16): A/B = 4 bf16/lane (k = (lane>>4)*4 + j), C/D std 16x16 map
__device__ __forceinline__ floatx4 mfma16(sh4 a, sh4 b, floatx4 c){
#if __has_builtin(__builtin_amdgcn_mfma_f32_16x16x16bf16_1k)
    return __builtin_amdgcn_mfma_f32_16x16x16bf16_1k(a, b, c, 0, 0, 0);
#elif __has_builtin(__builtin_amdgcn_mfma_f32_16x16x16_bf16)
    return __builtin_amdgcn_mfma_f32_16x16x16_bf16(a, b, c, 0, 0, 0);
#else
    asm volatile("v_mfma_f32_16x16x16_bf16 %0, %1, %2, %0\n\ts_nop 7\n\ts_nop 7"
                 : "+v"(c) : "v"(a), "v"(b));
    return c;
#endif
}

// transpose-read: 4 bf16 at elem strides {0,16,32,48} from per-lane LDS addr
__device__ __forceinline__ sh4 tr16_read(const short* p){
#if __has_builtin(__builtin_amdgcn_ds_read_tr16_b64_v4i16)
    auto lp = (__attribute__((address_space(3))) sh4*)(uintptr_t)p;
    return __builtin_amdgcn_ds_read_tr16_b64_v4i16(lp);
#elif __has_builtin(__builtin_amdgcn_ds_read_tr16_b64)
    auto lp = (__attribute__((address_space(3))) sh4*)(uintptr_t)p;
    return __builtin_amdgcn_ds_read_tr16_b64(lp);
#else
    sh4 r; r[0] = p[0]; r[1] = p[16]; r[2] = p[32]; r[3] = p[48]; return r;
#endif
}

__device__ __forceinline__ void store_out(bf16* p, float v){ *p = __float2bfloat16(v); }
__device__ __forceinline__ void store_out(float* p, float v){ *p = v; }

// ---------------------------------------------------------------------------
// Round-11: 256x256-tile 8-phase GEMM (T3+T4+T5 structure, plain-HIP port of
// the guide's verified template): C = A(MxK)·B(NxK)^T + bias.
//   512 thr = 8 waves (2M x 4N); per-wave output 128x64 (8x4 16x16 frags).
//   BK=64; LDS 128 KB = 2 dbuf x (A 32KB | B 32KB), row = 128 B = 8 16B-octets,
//   phys octet = logical ^ (row&7) (pre-swizzled global src, linear glds dest,
//   swizzled ds_read -> 2-way max bank aliasing = free).
//   Per K-tile: 4 phases; phase p = { ds_read A-frags m{2p,2p+1} (+ all B in
//   p0) ; 2-3 glds prefetch of tile t+1 ; barrier ; lgkmcnt(0) ; setprio(1) ;
//   16 MFMA ; setprio(0) ; [p3: vmcnt(0)] ; barrier }.
//   vmcnt drains once per K-tile, after its loads had 2-4 phases of cover.
// EPI: 1 = gelu->bf16 (FFN1), 3 = KV head-major scatter.
// ---------------------------------------------------------------------------
template<int EPI, typename OUT_T>
__global__ __launch_bounds__(512, 1) void gemm256_kernel(const bf16* __restrict__ A,
                                                         const bf16* __restrict__ Bm,
                                                         const float* __restrict__ bias,
                                                         OUT_T* __restrict__ C,
                                                         bf16* __restrict__ Vhm,
                                                         int K, int ldc, int lgGX)
{
    extern __shared__ __align__(16) char smem[];     // 131072 B dynamic

    const int bid = blockIdx.x;
    const int per = gridDim.x >> 3;
    const int lid = (bid & 7)*per + (bid >> 3);      // XCD-contiguous (nwg%8==0)
    const int bx  = lid & ((1 << lgGX) - 1);
    const int by  = lid >> lgGX;

    const int t    = threadIdx.x;                    // 0..511
    const int lane = t & 63;
    const int wid  = t >> 6;                         // 0..7
    const int wm   = wid >> 2;                       // 0..1  (M half)
    const int wn   = wid & 3;                        // 0..3  (N quarter)
    const int lf   = lane & 15;
    const int g    = lane >> 4;

    // staging thread map: within an 8KB chunk (64 rows x 128B), thread t covers
    // row (t>>3), phys octet (t&7); fetches logical octet sl = (t&7)^((t>>3)&7)
    const int srow = t >> 3;
    const int sl   = (t & 7) ^ (srow & 7);
    const short* gAsrc = (const short*)A  + ((size_t)by*256 + srow)*K + sl*8;
    const short* gBsrc = (const short*)Bm + ((size_t)bx*256 + srow)*K + sl*8;

    auto stageA = [&](int buf, int tile, int q){
        load_lds16(gAsrc + (size_t)q*64*K + (size_t)tile*64,
                   smem + buf*65536 + q*8192 + wid*1024);
    };
    auto stageB = [&](int buf, int tile, int q){
        load_lds16(gBsrc + (size_t)q*64*K + (size_t)tile*64,
                   smem + buf*65536 + 32768 + q*8192 + wid*1024);
    };
    // fragment reads: row&7 == lf&7 for all frag rows (offsets are mult of 8)
    auto ldsA = [&](int buf, int i, int s) -> short8 {
        int row  = wm*128 + i*16 + lf;
        int phys = (s*4 + g) ^ (lf & 7);
        return *(const short8*)(smem + buf*65536 + row*128 + phys*16);
    };
    auto ldsB = [&](int buf, int j, int s) -> short8 {
        int row  = wn*64 + j*16 + lf;
        int phys = (s*4 + g) ^ (lf & 7);
        return *(const short8*)(smem + buf*65536 + 32768 + row*128 + phys*16);
    };

    floatx4 acc[8][4];
    floatx4 z = {0.f,0.f,0.f,0.f};
    #pragma unroll
    for (int i = 0; i < 8; ++i)
        #pragma unroll
        for (int j = 0; j < 4; ++j) acc[i][j] = z;

    const int T = K >> 6;                            // K-tiles (K=512 -> 8)
    // prologue: tile 0 into buf 0, drain, all-waves barrier
    #pragma unroll
    for (int q = 0; q < 4; ++q) stageA(0, 0, q);
    #pragma unroll
    for (int q = 0; q < 4; ++q) stageB(0, 0, q);
    asm volatile("s_waitcnt vmcnt(0)" ::: "memory");
    __builtin_amdgcn_s_barrier();

    for (int tt = 0; tt < T; ++tt){
        const int c  = tt & 1, nc = c ^ 1;
        const bool pf = (tt + 1 < T);
        short8 bF[4][2];
        #pragma unroll
        for (int p = 0; p < 4; ++p){
            short8 aPh[2][2];
            aPh[0][0] = ldsA(c, 2*p,   0); aPh[0][1] = ldsA(c, 2*p,   1);
            aPh[1][0] = ldsA(c, 2*p+1, 0); aPh[1][1] = ldsA(c, 2*p+1, 1);
            if (p == 0){
                #pragma unroll
                for (int j = 0; j < 4; ++j){
                    bF[j][0] = ldsB(c, j, 0);
                    bF[j][1] = ldsB(c, j, 1);
                }
            }
            if (pf){                                  // 3/3/2/0 issue schedule
                if      (p == 0){ stageA(nc, tt+1, 0); stageA(nc, tt+1, 1); stageA(nc, tt+1, 2); }
                else if (p == 1){ stageA(nc, tt+1, 3); stageB(nc, tt+1, 0); stageB(nc, tt+1, 1); }
                else if (p == 2){ stageB(nc, tt+1, 2); stageB(nc, tt+1, 3); }
            }
            __builtin_amdgcn_s_barrier();
            asm volatile("s_waitcnt lgkmcnt(0)" ::: "memory");
            __builtin_amdgcn_s_setprio(1);
            #pragma unroll
            for (int mm = 0; mm < 2; ++mm)
                #pragma unroll
                for (int j = 0; j < 4; ++j){
                    acc[2*p+mm][j] = __builtin_amdgcn_mfma_f32_16x16x32_bf16(aPh[mm][0], bF[j][0], acc[2*p+mm][j], 0, 0, 0);
                    acc[2*p+mm][j] = __builtin_amdgcn_mfma_f32_16x16x32_bf16(aPh[mm][1], bF[j][1], acc[2*p+mm][j], 0, 0, 0);
                }
            __builtin_amdgcn_s_setprio(0);
            if (p == 3) asm volatile("s_waitcnt vmcnt(0)" ::: "memory");
            __builtin_amdgcn_s_barrier();
        }
    }
    __syncthreads();                                  // K-loop LDS dead -> overlay

    // epilogue: two 64x64 rounds per wave; same pack/LDS-stage/coalesced-store
    // pattern as the 128^2 kernel. cs = 64x72 shorts per wave (9 KB x8 = 72 KB).
    short* cs = (short*)smem + wid*(64*72);
    const int odd = lf & 1;
    const int rsel = odd*2;
    const int subrow = lane >> 3, cq = lane & 7;
    #pragma unroll
    for (int rr2 = 0; rr2 < 2; ++rr2){
        #pragma unroll
        for (int j = 0; j < 4; ++j){
            float bv = bias[bx*256 + wn*64 + j*16 + lf];
            #pragma unroll
            for (int i = 0; i < 4; ++i){
                int im = rr2*4 + i;
                unsigned long long self = 0;
                #pragma unroll
                for (int r = 0; r < 4; ++r){
                    float v = acc[im][j][r] + bv;
                    if constexpr (EPI == 1) v = gelu_f(v);
                    self |= ((unsigned long long)f2bf_bits(v)) << (16*r);
                }
                unsigned long long nbr = __shfl_xor(self, 1);
                unsigned long long lo = odd ? nbr : self;
                unsigned long long hi = odd ? self : nbr;
                int colb = 16*j + (lf & ~1);
                unsigned int w0 = (unsigned int)((lo >> (16*rsel)) & 0xffffu)
                                | ((unsigned int)((hi >> (16*rsel)) & 0xffffu) << 16);
                unsigned int w1 = (unsigned int)((lo >> (16*(rsel+1))) & 0xffffu)
                                | ((unsigned int)((hi >> (16*(rsel+1))) & 0xffffu) << 16);
                *(unsigned int*)(cs + (16*i + 4*g + rsel    )*72 + colb) = w0;
                *(unsigned int*)(cs + (16*i + 4*g + rsel + 1)*72 + colb) = w1;
            }
        }
        // same-wave read-back + coalesced stores (8 rows x 128 B per instr)
        #pragma unroll
        for (int rr = 0; rr < 8; ++rr){
            int rl = rr*8 + subrow;
            short8 vv = *(const short8*)(cs + rl*72 + cq*8);
            int grow = by*256 + wm*128 + rr2*64 + rl;
            int gc   = bx*256 + wn*64 + cq*8;
            if constexpr (EPI == 3){
                int b = grow >> 11, s = grow & 2047;
                int h = (gc >> 6) & 7, d = gc & 63;
                bf16* dst = (gc < 512) ? (bf16*)C : Vhm;
                *(short8*)((short*)dst + (((size_t)(b*NH + h))*SEQ + s)*DHEAD + d) = vv;
            } else {
                *(short8*)((short*)C + (size_t)grow*ldc + gc) = vv;
            }
        }
    }
}

// ---------------------------------------------------------------------------
// 128x128-tile GEMM (round-10 structure) — retained for FFN2 (N=512: only
// 128 blocks at 256^2 would idle half the GPU; 512 blocks here).
// ---------------------------------------------------------------------------
template<int EPI, typename OUT_T>
__global__ __launch_bounds__(256, 3) void gemm128_kernel(const bf16* __restrict__ A,
                                                         const bf16* __restrict__ Bm,
                                                         const float* __restrict__ bias,
                                                         OUT_T* __restrict__ C,
                                                         const float* __restrict__ x2,
                                                         bf16* __restrict__ Vhm,
                                                         int K, int ldc, int lgGX)
{
    __shared__ __align__(16) char smem[49152];   // 3 x (As 8KB | Bs 8KB)
    short* CsBase = (short*)smem;

    const int bid = blockIdx.x;
    const int per = gridDim.x >> 3;
    const int lid = (bid & 7)*per + (bid >> 3);
    const int bx  = lid & ((1 << lgGX) - 1);
    const int by  = lid >> lgGX;

    const int t    = threadIdx.x;
    const int lane = t & 63;
    const int w    = t >> 6;
    const int lf   = lane & 15;
    const int ko   = lane >> 4;
    const int slot = ko ^ ((lf >> 1) & 3);
    const int mrow = (w >> 1)*64, ncol = (w & 1)*64;

    floatx4 acc[4][4];
    floatx4 z = {0.f,0.f,0.f,0.f};
    #pragma unroll
    for (int i = 0; i < 4; ++i)
        #pragma unroll
        for (int j = 0; j < 4; ++j) acc[i][j] = z;

    const int srow = w*16 + (lane >> 2);
    const int sq   = lane & 3;
    const int r0 = srow,      kq0 = sq ^ ((r0 >> 1) & 3);
    const int r1 = 64 + srow, kq1 = sq ^ ((r1 >> 1) & 3);
    const short* ga0 = (const short*)A  + ((size_t)by*128 + r0)*K + kq0*8;
    const short* ga1 = (const short*)A  + ((size_t)by*128 + r1)*K + kq1*8;
    const short* gb0 = (const short*)Bm + ((size_t)bx*128 + r0)*K + kq0*8;
    const short* gb1 = (const short*)Bm + ((size_t)bx*128 + r1)*K + kq1*8;
    char* la0 = smem + w*1024;
    char* la1 = smem + 4096 + w*1024;
    char* lb0 = smem + 8192 + w*1024;
    char* lb1 = smem + 12288 + w*1024;

    auto stage = [&](int off){
        load_lds16(ga0, la0 + off); load_lds16(ga1, la1 + off);
        load_lds16(gb0, lb0 + off); load_lds16(gb1, lb1 + off);
        ga0 += 32; ga1 += 32; gb0 += 32; gb1 += 32;
    };
    auto compute = [&](int off){
        const short* As = (const short*)(smem + off);
        const short* Bs = (const short*)(smem + off + 8192);
        short8 af[4], bfr[4];
        #pragma unroll
        for (int i = 0; i < 4; ++i){
            af[i]  = *(const short8*)(As + (mrow + i*16 + lf)*32 + slot*8);
            bfr[i] = *(const short8*)(Bs + (ncol + i*16 + lf)*32 + slot*8);
        }
        #pragma unroll
        for (int i = 0; i < 4; ++i)
            #pragma unroll
            for (int j = 0; j < 4; ++j)
                acc[i][j] = __builtin_amdgcn_mfma_f32_16x16x32_bf16(af[i], bfr[j], acc[i][j], 0, 0, 0);
    };

    const int T = K >> 5;
    stage(0);
    stage(16384);
    int oc = 0, on = 16384, on2 = 32768;
    for (int kt = 0; kt < T - 2; ++kt){
        asm volatile("s_waitcnt vmcnt(4)" ::: "memory");
        __builtin_amdgcn_s_barrier();
        asm volatile("" ::: "memory");
        stage(on2);
        compute(oc);
        int tmp = oc; oc = on; on = on2; on2 = tmp;
    }
    asm volatile("s_waitcnt vmcnt(4)" ::: "memory");
    __builtin_amdgcn_s_barrier();
    asm volatile("" ::: "memory");
    compute(oc);
    { int tmp = oc; oc = on; on = on2; on2 = tmp; }
    asm volatile("s_waitcnt vmcnt(0)" ::: "memory");
    __builtin_amdgcn_s_barrier();
    asm volatile("" ::: "memory");
    compute(oc);
    __syncthreads();

    if constexpr (EPI == 2){
        const int lr = ko*4;
        #pragma unroll
        for (int j = 0; j < 4; ++j){
            int gcol = bx*128 + ncol + j*16 + lf;
            float bv = bias[gcol];
            #pragma unroll
            for (int i = 0; i < 4; ++i){
                #pragma unroll
                for (int r = 0; r < 4; ++r){
                    size_t grow = (size_t)by*128 + mrow + i*16 + lr + r;
                    float v = acc[i][j][r] + bv + x2[grow*ldc + gcol];
                    store_out(&C[grow*ldc + gcol], v);
                }
            }
        }
    } else {
        short* cs = CsBase + w*(64*72);
        const int odd = lf & 1;
        const int rsel = odd*2;
        #pragma unroll
        for (int j = 0; j < 4; ++j){
            float bv = bias[bx*128 + ncol + j*16 + lf];
            #pragma unroll
            for (int i = 0; i < 4; ++i){
                unsigned long long self = 0;
                #pragma unroll
                for (int r = 0; r < 4; ++r){
                    float v = acc[i][j][r] + bv;
                    if constexpr (EPI == 1) v = gelu_f(v);
                    self |= ((unsigned long long)f2bf_bits(v)) << (16*r);
                }
                unsigned long long nbr = __shfl_xor(self, 1);
                unsigned long long lo = odd ? nbr : self;
                unsigned long long hi = odd ? self : nbr;
                int colb = 16*j + (lf & ~1);
                unsigned int w0 = (unsigned int)((lo >> (16*rsel)) & 0xffffu)
                                | ((unsigned int)((hi >> (16*rsel)) & 0xffffu) << 16);
                unsigned int w1 = (unsigned int)((lo >> (16*(rsel+1))) & 0xffffu)
                                | ((unsigned int)((hi >> (16*(rsel+1))) & 0xffffu) << 16);
                *(unsigned int*)(cs + (16*i + 4*ko + rsel    )*72 + colb) = w0;
                *(unsigned int*)(cs + (16*i + 4*ko + rsel + 1)*72 + colb) = w1;
            }
        }
        const int subrow = lane >> 3, cq = lane & 7;
        #pragma unroll
        for (int rr = 0; rr < 8; ++rr){
            int rl = rr*8 + subrow;
            short8 vv = *(const short8*)(cs + rl*72 + cq*8);
            if constexpr (EPI == 3){
                int grow = by*128 + mrow + rl;
                int b = grow >> 11, s = grow & 2047;
                int gc = bx*128 + ncol + cq*8;
                int h = (gc >> 6) & 7, d = gc & 63;
                bf16* dst = (gc < 512) ? (bf16*)C : Vhm;
                *(short8*)((short*)dst + (((size_t)(b*NH + h))*SEQ + s)*DHEAD + d) = vv;
            } else {
                size_t grow = (size_t)by*128 + mrow + rl;
                int gcol = bx*128 + ncol + cq*8;
                *(short8*)((short*)C + grow*ldc + gcol) = vv;
            }
        }
    }
}

// ---------------------------------------------------------------------------
__global__ void init_kernel(int* selmap){
    int i = blockIdx.x*256 + threadIdx.x;
    if (i < MROWS) selmap[i] = -1;
}

// fp32 -> bf16 weight convert (n multiple of 4)
__global__ __launch_bounds__(256) void cvt_kernel(const float* __restrict__ src,
                                                  bf16* __restrict__ dst, int n){
    int i = (blockIdx.x*256 + threadIdx.x)*4;
    if (i < n){
        float4 v = *(const float4*)(src + i);
        dst[i+0] = __float2bfloat16(v.x);
        dst[i+1] = __float2bfloat16(v.y);
        dst[i+2] = __float2bfloat16(v.z);
        dst[i+3] = __float2bfloat16(v.w);
    }
}

// ---------------------------------------------------------------------------
// LN1 (fp32 in): x -> xn (f32), xnb (bf16), diag[row]=|xn|^2 in fp64 (ranking)
// ---------------------------------------------------------------------------
__global__ __launch_bounds__(256) void ln1_kernel(const float* __restrict__ x,
                                                  const float* __restrict__ g,
                                                  const float* __restrict__ bt,
                                                  float* __restrict__ xn,
                                                  bf16* __restrict__ xnb,
                                                  double* __restrict__ diag)
{
    __shared__ double sbuf[4];
    int row = blockIdx.x;
    int t = threadIdx.x;
    size_t base = (size_t)row*DIM;
    double x0 = (double)x[base + t];
    double x1 = (double)x[base + t + 256];
    double m  = block_sum256d(x0 + x1, sbuf) * (1.0/DIM);
    double d0 = x0 - m, d1 = x1 - m;
    double var = block_sum256d(d0*d0 + d1*d1, sbuf) * (1.0/DIM);
    double r = 1.0/sqrt(var + 1e-5);
    double y0 = d0*r*(double)g[t]     + (double)bt[t];
    double y1 = d1*r*(double)g[t+256] + (double)bt[t+256];
    xn[base+t] = (float)y0;       xn[base+t+256] = (float)y1;
    xnb[base+t] = __float2bfloat16((float)y0);
    xnb[base+t+256] = __float2bfloat16((float)y1);
    double dd = block_sum256d(y0*y0 + y1*y1, sbuf);
    if (t == 0) diag[row] = dd;
}

// column-mean of xn per batch, fp64 two-stage
__global__ __launch_bounds__(512) void xbar_part_kernel(const float* __restrict__ xn, double* __restrict__ part){
    int b = blockIdx.y, c = blockIdx.x, d = threadIdx.x;
    const float* p = xn + ((size_t)b*SEQ + c*64)*DIM + d;
    double s = 0.0;
    for (int i = 0; i < 64; ++i) s += (double)p[(size_t)i*DIM];
    part[((size_t)(b*32 + c))*DIM + d] = s;
}
__global__ __launch_bounds__(512) void xbar_fin_kernel(const double* __restrict__ part,
                                                       double* __restrict__ xbar_d,
                                                       float* __restrict__ xbar_f){
    int b = blockIdx.x, d = threadIdx.x;
    double s = 0.0;
    for (int c = 0; c < 32; ++c) s += part[((size_t)(b*32 + c))*DIM + d];
    s *= (1.0/SEQ);
    xbar_d[(size_t)b*DIM + d] = s;
    xbar_f[(size_t)b*DIM + d] = (float)s;
}

// sparsity*sqrt(D) = diag - dot(xn_row, xbar); fp64 so ranking error << ref fp32 noise
__global__ __launch_bounds__(256) void sparsity_kernel(const float* __restrict__ xn,
                                                       const double* __restrict__ xbar,
                                                       const double* __restrict__ diag,
                                                       double* __restrict__ sp)
{
    int row  = blockIdx.x*4 + (threadIdx.x >> 6);
    int lane = threadIdx.x & 63;
    int b    = row >> 11;
    const float* xr = xn + (size_t)row*DIM;
    const double* xb = xbar + (size_t)b*DIM;
    double s = 0.0;
    for (int e = lane; e < DIM; e += 64) s += (double)xr[e]*xb[e];
    s = wave_sum_d(s);
    if (lane == 0) sp[row] = diag[row] - s;
}

// top-39 per batch (iterative argmax; ties -> lowest index, matching jax top_k)
__global__ __launch_bounds__(256) void topk_kernel(const double* __restrict__ sp,
                                                   int* __restrict__ topidx,
                                                   int* __restrict__ selmap,
                                                   float* __restrict__ dout)
{
    __shared__ double vals[SEQ];
    __shared__ double rv[256];
    __shared__ int    ri[256];
    int b = blockIdx.x, t = threadIdx.x;
    for (int i = t; i < SEQ; i += 256) vals[i] = sp[(size_t)b*SEQ + i];
    __syncthreads();
    for (int it = 0; it < TOPQ; ++it){
        double bv = -1.0e300; int bi = 0;
        for (int i = t; i < SEQ; i += 256){
            double v = vals[i];
            if (v > bv){ bv = v; bi = i; }
        }
        rv[t] = bv; ri[t] = bi;
        __syncthreads();
        for (int stride = 128; stride > 0; stride >>= 1){
            if (t < stride){
                double ov = rv[t+stride]; int oi = ri[t+stride];
                if (ov > rv[t] || (ov == rv[t] && oi < ri[t])){ rv[t] = ov; ri[t] = oi; }
            }
            __syncthreads();
        }
        if (t == 0){
            int idx = ri[0];
            topidx[b*64 + it] = idx;
            selmap[(size_t)b*SEQ + idx] = it;
            vals[idx] = -1.0e300;
        }
        __syncthreads();
    }
    if (b == 0 && t == 0) dout[(size_t)MROWS*DIM] = (float)TOPQ/(float)SEQ;
}

// Q projection for the selected rows -> bf16 head-major Qhm[b][h][48][64]
// (rows TOPQ..47 zero-padded so the MFMA attention can use 3 full 16-row tiles)
__global__ __launch_bounds__(256) void qproj_kernel(const float* __restrict__ xn,
                                                    const float* __restrict__ in_w,
                                                    const float* __restrict__ in_b,
                                                    const int* __restrict__ topidx,
                                                    bf16* __restrict__ Qhm)
{
    int j = blockIdx.x, b = blockIdx.y, t = threadIdx.x;
    __shared__ float qr[DIM];
    if (j >= TOPQ){
        for (int d0 = t; d0 < DIM; d0 += 256){
            int h = d0 >> 6, d = d0 & 63;
            Qhm[((size_t)(b*NH + h)*QPAD + j)*DHEAD + d] = __float2bfloat16(0.f);
        }
        return;
    }
    int srow = topidx[b*64 + j];
    const float* xr = xn + ((size_t)(b*SEQ + srow))*DIM;
    for (int i = t; i < DIM; i += 256) qr[i] = xr[i];
    __syncthreads();
    for (int d0 = t; d0 < DIM; d0 += 256){
        const float* wr = in_w + (size_t)d0*DIM;   // Wq row d0
        float s = 0.f;
        for (int e = 0; e < DIM; e += 4){
            float4 wv = *(const float4*)(wr + e);
            s += qr[e]*wv.x + qr[e+1]*wv.y + qr[e+2]*wv.z + qr[e+3]*wv.w;
        }
        int h = d0 >> 6, d = d0 & 63;
        Qhm[((size_t)(b*NH + h)*QPAD + j)*DHEAD + d] = __float2bfloat16(s + in_b[d0]);
    }
}

// ---------------------------------------------------------------------------
// MFMA split-K attention partial (round-8 structure, unchanged).
// ---------------------------------------------------------------------------
__global__ __launch_bounds__(256, 1) void attn_mfma_kernel(const bf16* __restrict__ Qhm,
                                                           const bf16* __restrict__ Khm,
                                                           const bf16* __restrict__ Vhm,
                                                           float* __restrict__ part)
{
    __shared__ __align__(16) short vsm[4*8192];   // 64 KB: 4 waves x (128k x 64d)
    const int bh   = blockIdx.z*NH + blockIdx.y;
    const int w    = threadIdx.x >> 6;
    const int lane = threadIdx.x & 63;
    const int ch   = blockIdx.x*4 + w;           // chunk 0..15
    const int kb   = ch*KC;                      // first key of chunk
    const int lf   = lane & 15;
    const int g    = lane >> 4;

    short* vbase = vsm + w*8192;
    const short* vg = (const short*)Vhm + ((size_t)bh*SEQ + kb)*DHEAD;
    {
        const int kh = lane >> 1, dh = (lane & 1)*8;
        #pragma unroll
        for (int L = 0; L < 16; ++L){
            int k = (L & 3)*32 + kh;
            int d = (L >> 2)*16 + dh;
            load_lds16(vg + (size_t)k*DHEAD + d, vbase + L*512);
        }
    }

    short8 qf[3][2];
    const short* qp = (const short*)Qhm + (size_t)bh*QPAD*DHEAD;
    #pragma unroll
    for (int nt = 0; nt < 3; ++nt)
        #pragma unroll
        for (int s = 0; s < 2; ++s)
            qf[nt][s] = *(const short8*)(qp + (nt*16 + lf)*DHEAD + s*32 + g*8);

    floatx4 sa[8][3];
    floatx4 z = {0.f,0.f,0.f,0.f};
    #pragma unroll
    for (int mt = 0; mt < 8; ++mt)
        #pragma unroll
        for (int nt = 0; nt < 3; ++nt) sa[mt][nt] = z;

    const short* kp = (const short*)Khm + ((size_t)bh*SEQ + kb)*DHEAD;
    #pragma unroll
    for (int mt = 0; mt < 8; ++mt){
        const short* kr = kp + (size_t)(mt*16 + lf)*DHEAD + g*8;
        short8 kf0 = *(const short8*)(kr);
        short8 kf1 = *(const short8*)(kr + 32);
        #pragma unroll
        for (int nt = 0; nt < 3; ++nt){
            sa[mt][nt] = __builtin_amdgcn_mfma_f32_16x16x32_bf16(kf0, qf[nt][0], sa[mt][nt], 0, 0, 0);
            sa[mt][nt] = __builtin_amdgcn_mfma_f32_16x16x32_bf16(kf1, qf[nt][1], sa[mt][nt], 0, 0, 0);
        }
    }

    float mx[3], ls[3];
    #pragma unroll
    for (int nt = 0; nt < 3; ++nt){
        float m = sa[0][nt][0];
        #pragma unroll
        for (int mt = 0; mt < 8; ++mt)
            #pragma unroll
            for (int r = 0; r < 4; ++r) m = fmaxf(m, sa[mt][nt][r]);
        m = fmaxf(m, __shfl_xor(m, 16));
        m = fmaxf(m, __shfl_xor(m, 32));
        float l = 0.f;
        #pragma unroll
        for (int mt = 0; mt < 8; ++mt){
            #pragma unroll
            for (int r = 0; r < 4; ++r){
                float p = __expf((sa[mt][nt][r] - m)*0.125f);   // 1/sqrt(64)
                sa[mt][nt][r] = p;
                l += p;
            }
        }
        l += __shfl_xor(l, 16);
        l += __shfl_xor(l, 32);
        mx[nt] = m; ls[nt] = l;
    }

    asm volatile("s_waitcnt vmcnt(0)" ::: "memory");   // V staging landed
    floatx4 oacc[3][4];
    #pragma unroll
    for (int mi = 0; mi < 3; ++mi)
        #pragma unroll
        for (int dt = 0; dt < 4; ++dt) oacc[mi][dt] = z;

    #pragma unroll
    for (int t = 0; t < 8; ++t){
        sh4 pa[3];
        #pragma unroll
        for (int mi = 0; mi < 3; ++mi){
            union { sh4 v; unsigned u[2]; } pk;
            pk.u[0] = f2bf_bits(sa[t][mi][0]) | (f2bf_bits(sa[t][mi][1]) << 16);
            pk.u[1] = f2bf_bits(sa[t][mi][2]) | (f2bf_bits(sa[t][mi][3]) << 16);
            pa[mi] = pk.v;
        }
        #pragma unroll
        for (int dt = 0; dt < 4; ++dt){
            sh4 vf = tr16_read(vbase + dt*2048 + (t*16 + 4*g)*16 + lf);
            #pragma unroll
            for (int mi = 0; mi < 3; ++mi)
                oacc[mi][dt] = mfma16(pa[mi], vf, oacc[mi][dt]);
        }
    }

    float* pbase = part + ((size_t)bh*TOPQ*NKC + ch)*PSTR;
    #pragma unroll
    for (int mi = 0; mi < 3; ++mi){
        #pragma unroll
        for (int r = 0; r < 4; ++r){
            int q = mi*16 + 4*g + r;
            if (q < TOPQ){
                float* pp = pbase + (size_t)q*NKC*PSTR;
                #pragma unroll
                for (int dt = 0; dt < 4; ++dt)
                    pp[dt*16 + lf] = oacc[mi][dt][r];
            }
        }
    }
    #pragma unroll
    for (int nt = 0; nt < 3; ++nt){
        int q = nt*16 + lf;
        if (g == 3 && q < TOPQ){
            float* pp = pbase + (size_t)q*NKC*PSTR;
            pp[64] = mx[nt]*0.125f;
            pp[65] = ls[nt];
        }
    }
}

// pass 2: merge 16 partials per (b,h,q); wave per q (4 q per block)  (unchanged)
__global__ __launch_bounds__(256) void attn_reduce_kernel(const float* __restrict__ part,
                                                          float* __restrict__ ctx)
{
    int qc = blockIdx.x, h = blockIdx.y, b = blockIdx.z;
    int w = threadIdx.x >> 6, lane = threadIdx.x & 63;
    int q = qc*4 + w;
    if (q >= TOPQ) return;
    const float* pb = part + (((size_t)(b*NH + h))*TOPQ + q)*NKC*PSTR;
    float M = -3.402823466e38f;
    #pragma unroll
    for (int i = 0; i < NKC; ++i) M = fmaxf(M, pb[i*PSTR + 64]);
    float L = 0.f, a = 0.f;
    #pragma unroll
    for (int i = 0; i < NKC; ++i){
        float sc = __expf(pb[i*PSTR + 64] - M);
        L += pb[i*PSTR + 65]*sc;
        a += pb[i*PSTR + lane]*sc;
    }
    ctx[((size_t)(b*TOPQ + q))*DIM + h*DHEAD + lane] = a/L;
}

// output projection of the 39 ctx rows (fp32 weights)
__global__ __launch_bounds__(256) void outproj_kernel(const float* __restrict__ ctx,
                                                      const float* __restrict__ ow,
                                                      const float* __restrict__ ob,
                                                      float* __restrict__ sout)
{
    int j = blockIdx.x, b = blockIdx.y, t = threadIdx.x;
    __shared__ float cr[DIM];
    const float* xr = ctx + ((size_t)(b*TOPQ + j))*DIM;
    for (int i = t; i < DIM; i += 256) cr[i] = xr[i];
    __syncthreads();
    for (int d0 = t; d0 < DIM; d0 += 256){
        const float* wr = ow + (size_t)d0*DIM;
        float s = 0.f;
        for (int e = 0; e < DIM; e += 4){
            float4 wv = *(const float4*)(wr + e);
            s += cr[e]*wv.x + cr[e+1]*wv.y + cr[e+2]*wv.z + cr[e+3]*wv.w;
        }
        sout[((size_t)(b*TOPQ + j))*DIM + d0] = s + ob[d0];
    }
}

// residual (+ scatter sparse rows / broadcast xbar) then LN2 -> h (bf16), x2 (f32)
__global__ __launch_bounds__(256) void res_ln2_kernel(const float* __restrict__ x,
                                                      const float* __restrict__ xbar,
                                                      const float* __restrict__ sout,
                                                      const int* __restrict__ selmap,
                                                      const float* __restrict__ g2,
                                                      const float* __restrict__ bt2,
                                                      float* __restrict__ x2,
                                                      bf16* __restrict__ hb)
{
    __shared__ float sbuf[4];
    int row = blockIdx.x;
    int b = row >> 11;
    int t = threadIdx.x;
    int slot = selmap[row];
    const float* ar = (slot >= 0) ? (sout + ((size_t)(b*TOPQ + slot))*DIM)
                                  : (xbar + (size_t)b*DIM);
    size_t base = (size_t)row*DIM;
    float v0 = x[base + t]       + ar[t];
    float v1 = x[base + t + 256] + ar[t + 256];
    x2[base + t] = v0; x2[base + t + 256] = v1;
    float m = block_sum256(v0 + v1, sbuf) * (1.f/DIM);
    float d0 = v0 - m, d1 = v1 - m;
    float var = block_sum256(d0*d0 + d1*d1, sbuf) * (1.f/DIM);
    float r = 1.f/sqrtf(var + 1e-5f);
    hb[base + t]       = __float2bfloat16(d0*r*g2[t]     + bt2[t]);
    hb[base + t + 256] = __float2bfloat16(d1*r*g2[t+256] + bt2[t+256]);
}

// ---------------------------------------------------------------------------
extern "C" void kernel_launch(void* const* d_in, const int* in_sizes, int n_in,
                              void* d_out, int out_size, void* d_ws, size_t ws_size,
                              hipStream_t stream)
{
    (void)in_sizes; (void)n_in; (void)out_size; (void)ws_size;
    const float* x     = (const float*)d_in[0];
    const float* ln1_g = (const float*)d_in[1];
    const float* ln1_b = (const float*)d_in[2];
    const float* in_w  = (const float*)d_in[3];
    const float* in_b  = (const float*)d_in[4];
    const float* out_w = (const float*)d_in[5];
    const float* out_b = (const float*)d_in[6];
    const float* ln2_g = (const float*)d_in[7];
    const float* ln2_b = (const float*)d_in[8];
    const float* w1    = (const float*)d_in[9];
    const float* b1    = (const float*)d_in[10];
    const float* w2    = (const float*)d_in[11];
    const float* b2    = (const float*)d_in[12];
    float* out = (float*)d_out;

    const size_t MB = 1024*1024;
    char* base = (char*)d_ws;
    float* xn_f  = (float*)base;                 // [0,32MiB); reused as x2_f later
    bf16*  xn_b  = (bf16*)(base + 32*MB);        // dead after kv-gemm -> h_b
    bf16*  Khm   = (bf16*)(base + 48*MB);
    bf16*  Vhm   = (bf16*)(base + 64*MB);
    bf16*  h_b   = (bf16*)(base + 32*MB);
    bf16*  h1_b  = (bf16*)(base + 48*MB);        // overwrites Khm/Vhm after attn
    float* x2_f  = xn_f;
    char* p = base + 112*MB;
    bf16*  kvw_b  = (bf16*)p;  p += (size_t)1024*DIM*2;        // in_w rows [512,1536) bf16
    bf16*  w1_b   = (bf16*)p;  p += (size_t)FFD*DIM*2;
    bf16*  w2_b   = (bf16*)p;  p += (size_t)DIM*FFD*2;
    double* xbpart= (double*)p; p += (size_t)BATCH*32*DIM*8;
    double* xbar_d= (double*)p; p += (size_t)BATCH*DIM*8;
    float* xbar_f = (float*)p;  p += (size_t)BATCH*DIM*4;
    double* diag  = (double*)p; p += (size_t)MROWS*8;
    double* spars = (double*)p; p += (size_t)MROWS*8;
    int*   topidx = (int*)p;    p += (size_t)BATCH*64*4;
    int*   selmap = (int*)p;    p += (size_t)MROWS*4;
    bf16*  Qhm    = (bf16*)p;   p += (size_t)BATCH*NH*QPAD*DHEAD*2;   // 384 KiB
    float* ctxb   = (float*)p;  p += (size_t)BATCH*TOPQ*DIM*4;
    float* sout   = (float*)p;  p += (size_t)BATCH*TOPQ*DIM*4;
    float* apart  = (float*)p;  p += (size_t)BATCH*NH*TOPQ*NKC*PSTR*4;  // 10.5 MB

    init_kernel<<<64, 256, 0, stream>>>(selmap);
    cvt_kernel<<<512,  256, 0, stream>>>(in_w + (size_t)DIM*DIM, kvw_b, 1024*DIM);
    cvt_kernel<<<1024, 256, 0, stream>>>(w1, w1_b, FFD*DIM);
    cvt_kernel<<<1024, 256, 0, stream>>>(w2, w2_b, DIM*FFD);
    ln1_kernel<<<MROWS, 256, 0, stream>>>(x, ln1_g, ln1_b, xn_f, xn_b, diag);
    xbar_part_kernel<<<dim3(32, BATCH), 512, 0, stream>>>(xn_f, xbpart);
    xbar_fin_kernel<<<BATCH, 512, 0, stream>>>(xbpart, xbar_d, xbar_f);
    sparsity_kernel<<<MROWS/4, 256, 0, stream>>>(xn_f, xbar_d, diag, spars);
    topk_kernel<<<BATCH, 256, 0, stream>>>(spars, topidx, selmap, out);
    // KV projection (M=16384, N=1024 -> head-major K/V): 256^2 8-phase, grid 64x4
    gemm256_kernel<3, bf16><<<256, 512, 131072, stream>>>(
        xn_b, kvw_b, in_b + DIM, Khm, Vhm, DIM, 0, 2);
    qproj_kernel<<<dim3(QPAD, BATCH), 256, 0, stream>>>(xn_f, in_w, in_b, topidx, Qhm);
    attn_mfma_kernel<<<dim3(NKC/4, NH, BATCH), 256, 0, stream>>>(Qhm, Khm, Vhm, apart);
    attn_reduce_kernel<<<dim3((TOPQ + 3)/4, NH, BATCH), 256, 0, stream>>>(apart, ctxb);
    outproj_kernel<<<dim3(TOPQ, BATCH), 256, 0, stream>>>(ctxb, out_w, out_b, sout);
    res_ln2_kernel<<<MROWS, 256, 0, stream>>>(x, xbar_f, sout, selmap, ln2_g, ln2_b, x2_f, h_b);
    // FFN1 (M=16384, N=2048): 256^2 8-phase, grid 64x8
    gemm256_kernel<1, bf16><<<512, 512, 131072, stream>>>(
        h_b, w1_b, b1, h1_b, nullptr, DIM, FFD, 3);
    // FFN2 (N=512): keep 128^2 (512 blocks; 256^2 would idle half the GPU)
    gemm128_kernel<2, float><<<512, 256, 0, stream>>>(
        h1_b, w2_b, b2, out, x2_f, nullptr, FFD, DIM, 2);
}

// Round 5
// 497.049 us; speedup vs baseline: 1.0043x; 1.0043x over previous
//
#include <hip/hip_runtime.h>
#include <hip/hip_bf16.h>
#include <math.h>

#define BATCH 8
#define SEQ   2048
#define DIM   512
#define NH    8
#define DHEAD 64
#define FFD   2048
#define TOPQ  39            // ceil(5*ln(2048)) with factor=5, min_k=5 (fixed harness inputs)
#define MROWS (BATCH*SEQ)   // 16384
#define KC    128           // keys per attention partial chunk (one wave)
#define NKC   (SEQ/KC)      // 16
#define PSTR  66            // partial stride: 64 ctx + m + l
#define QPAD  48            // TOPQ padded to 3 MFMA row-tiles

typedef __hip_bfloat16 bf16;
typedef __attribute__((ext_vector_type(8))) short short8;
typedef __attribute__((ext_vector_type(4))) short sh4;
typedef __attribute__((ext_vector_type(4))) float floatx4;

__device__ __forceinline__ float bf2f(short u){
    return __uint_as_float(((unsigned int)(unsigned short)u) << 16);
}
// RNE fp32->bf16 bits (matches hardware convert for finite values)
__device__ __forceinline__ unsigned int f2bf_bits(float f){
    unsigned int u = __float_as_uint(f);
    return (u + 0x7fffu + ((u >> 16) & 1u)) >> 16;
}
// fast gelu (tanh form): |err vs exact erf-gelu| < ~3e-3, << bf16 rounding here
__device__ __forceinline__ float gelu_f(float v){
    float u = v*(0.7978845608028654f + 0.0356774081363f*v*v);
    float e = __expf(2.f*u);
    return 0.5f*v*(2.f - 2.f/(e + 1.f));
}
__device__ __forceinline__ float wave_sum(float v){
    #pragma unroll
    for (int off = 32; off > 0; off >>= 1) v += __shfl_down(v, off);
    return v;
}
__device__ __forceinline__ double wave_sum_d(double v){
    #pragma unroll
    for (int off = 32; off > 0; off >>= 1) v += __shfl_down(v, off);
    return v;
}
// block = 256 threads (4 waves)
__device__ __forceinline__ float block_sum256(float v, float* sbuf){
    v = wave_sum(v);
    if ((threadIdx.x & 63) == 0) sbuf[threadIdx.x >> 6] = v;
    __syncthreads();
    float r = sbuf[0] + sbuf[1] + sbuf[2] + sbuf[3];
    __syncthreads();
    return r;
}
__device__ __forceinline__ double block_sum256d(double v, double* sbuf){
    v = wave_sum_d(v);
    if ((threadIdx.x & 63) == 0) sbuf[threadIdx.x >> 6] = v;
    __syncthreads();
    double r = sbuf[0] + sbuf[1] + sbuf[2] + sbuf[3];
    __syncthreads();
    return r;
}

// async global->LDS, 16 B per lane; LDS dest = wave-uniform base + lane*16
__device__ __forceinline__ void load_lds16(const void* g, void* l){
    auto gp = reinterpret_cast<const uint32_t __attribute__((address_space(1)))*>(
        reinterpret_cast<uintptr_t>(g));
    auto lp = reinterpret_cast<uint32_t __attribute__((address_space(3)))*>(
        reinterpret_cast<uintptr_t>(l));
    __builtin_amdgcn_global_load_lds(gp, lp, 16, 0, 0);
}

// 16x16x16 bf16 MFMA (K=16): A/B = 4 bf16/lane (k = (lane>>4)*4 + j), C/D std 16x16 map
__device__ __forceinline__ floatx4 mfma16(sh4 a, sh4 b, floatx4 c){
#if __has_builtin(__builtin_amdgcn_mfma_f32_16x16x16bf16_1k)
    return __builtin_amdgcn_mfma_f32_16x16x16bf16_1k(a, b, c, 0, 0, 0);
#elif __has_builtin(__builtin_amdgcn_mfma_f32_16x16x16_bf16)
    return __builtin_amdgcn_mfma_f32_16x16x16_bf16(a, b, c, 0, 0, 0);
#else
    asm volatile("v_mfma_f32_16x16x16_bf16 %0, %1, %2, %0\n\ts_nop 7\n\ts_nop 7"
                 : "+v"(c) : "v"(a), "v"(b));
    return c;
#endif
}

// transpose-read: 4 bf16 at elem strides {0,16,32,48} from per-lane LDS addr
__device__ __forceinline__ sh4 tr16_read(const short* p){
#if __has_builtin(__builtin_amdgcn_ds_read_tr16_b64_v4i16)
    auto lp = (__attribute__((address_space(3))) sh4*)(uintptr_t)p;
    return __builtin_amdgcn_ds_read_tr16_b64_v4i16(lp);
#elif __has_builtin(__builtin_amdgcn_ds_read_tr16_b64)
    auto lp = (__attribute__((address_space(3))) sh4*)(uintptr_t)p;
    return __builtin_amdgcn_ds_read_tr16_b64(lp);
#else
    sh4 r; r[0] = p[0]; r[1] = p[16]; r[2] = p[32]; r[3] = p[48]; return r;
#endif
}

__device__ __forceinline__ void store_out(bf16* p, float v){ *p = __float2bfloat16(v); }
__device__ __forceinline__ void store_out(float* p, float v){ *p = v; }

// ---------------------------------------------------------------------------
// Round-12: 256x256-tile GEMM, CORRECTED T3+T4 sync discipline:
//   per K-tile: { stage(buf^1, t+1) ; vmcnt(8) counted ; barrier ;
//                 read B ; 4x{ read A ; setprio(1) 16 MFMA setprio(0) } ;
//                 barrier }
// vs round-11 which drained vmcnt(0) every tile (load issued 1 phase earlier
// -> full latency exposed; the m97 disease) and paid 8 barriers/tile.
// Now: 2 barriers + 1 counted wait per tile; prefetched loads get a full
// tile (~4 phases) of cover; main loop NEVER drains vmcnt to 0. Compiler
// emits its own fine-grained lgkmcnt interleave over the unrolled tile.
// vmcnt(8) is per-wave; the following barrier makes ALL waves' tile-t glds
// visible before any ds_read. Tile-end barrier protects buf c from t+1's
// staging (t+1 writes buf c).
// LDS 128 KB = 2 dbuf x (A 32KB | B 32KB); row = 128 B = 8 16B-octets;
// phys octet = logical ^ (row&7); pre-swizzled global src, linear glds dest.
// EPI: 1 = gelu->bf16 (FFN1), 3 = KV head-major scatter.
// ---------------------------------------------------------------------------
template<int EPI, typename OUT_T>
__global__ __launch_bounds__(512, 1) void gemm256_kernel(const bf16* __restrict__ A,
                                                         const bf16* __restrict__ Bm,
                                                         const float* __restrict__ bias,
                                                         OUT_T* __restrict__ C,
                                                         bf16* __restrict__ Vhm,
                                                         int K, int ldc, int lgGX)
{
    extern __shared__ __align__(16) char smem[];     // 131072 B dynamic

    const int bid = blockIdx.x;
    const int per = gridDim.x >> 3;
    const int lid = (bid & 7)*per + (bid >> 3);      // XCD-contiguous (nwg%8==0)
    const int bx  = lid & ((1 << lgGX) - 1);
    const int by  = lid >> lgGX;

    const int t    = threadIdx.x;                    // 0..511
    const int lane = t & 63;
    const int wid  = t >> 6;                         // 0..7
    const int wm   = wid >> 2;                       // 0..1  (M half)
    const int wn   = wid & 3;                        // 0..3  (N quarter)
    const int lf   = lane & 15;
    const int g    = lane >> 4;

    // staging thread map: within an 8KB chunk (64 rows x 128B), thread t covers
    // row (t>>3), phys octet (t&7); fetches logical octet sl = (t&7)^((t>>3)&7)
    const int srow = t >> 3;
    const int sl   = (t & 7) ^ (srow & 7);
    const short* gAsrc = (const short*)A  + ((size_t)by*256 + srow)*K + sl*8;
    const short* gBsrc = (const short*)Bm + ((size_t)bx*256 + srow)*K + sl*8;

    auto stageA = [&](int buf, int tile, int q){
        load_lds16(gAsrc + (size_t)q*64*K + (size_t)tile*64,
                   smem + buf*65536 + q*8192 + wid*1024);
    };
    auto stageB = [&](int buf, int tile, int q){
        load_lds16(gBsrc + (size_t)q*64*K + (size_t)tile*64,
                   smem + buf*65536 + 32768 + q*8192 + wid*1024);
    };
    // fragment reads: row&7 == lf&7 for all frag rows (offsets are mult of 8)
    auto ldsA = [&](int buf, int i, int s) -> short8 {
        int row  = wm*128 + i*16 + lf;
        int phys = (s*4 + g) ^ (lf & 7);
        return *(const short8*)(smem + buf*65536 + row*128 + phys*16);
    };
    auto ldsB = [&](int buf, int j, int s) -> short8 {
        int row  = wn*64 + j*16 + lf;
        int phys = (s*4 + g) ^ (lf & 7);
        return *(const short8*)(smem + buf*65536 + 32768 + row*128 + phys*16);
    };

    floatx4 acc[8][4];
    floatx4 z = {0.f,0.f,0.f,0.f};
    #pragma unroll
    for (int i = 0; i < 8; ++i)
        #pragma unroll
        for (int j = 0; j < 4; ++j) acc[i][j] = z;

    const int T = K >> 6;                            // K-tiles (K=512 -> 8)
    // prologue: issue tile-0 loads only; the loop's vmcnt(8)+barrier covers them
    #pragma unroll
    for (int q = 0; q < 4; ++q) stageA(0, 0, q);
    #pragma unroll
    for (int q = 0; q < 4; ++q) stageB(0, 0, q);

    for (int tt = 0; tt < T; ++tt){
        const int c  = tt & 1, nc = c ^ 1;
        if (tt + 1 < T){
            #pragma unroll
            for (int q = 0; q < 4; ++q) stageA(nc, tt+1, q);
            #pragma unroll
            for (int q = 0; q < 4; ++q) stageB(nc, tt+1, q);
            asm volatile("s_waitcnt vmcnt(8)" ::: "memory");  // tile t landed; t+1 in flight
        } else {
            asm volatile("s_waitcnt vmcnt(0)" ::: "memory");  // last tile: nothing younger
        }
        __builtin_amdgcn_s_barrier();                // all waves' tile-t data visible

        short8 bF[4][2];
        #pragma unroll
        for (int j = 0; j < 4; ++j){
            bF[j][0] = ldsB(c, j, 0);
            bF[j][1] = ldsB(c, j, 1);
        }
        #pragma unroll
        for (int p = 0; p < 4; ++p){
            short8 aPh[2][2];
            aPh[0][0] = ldsA(c, 2*p,   0); aPh[0][1] = ldsA(c, 2*p,   1);
            aPh[1][0] = ldsA(c, 2*p+1, 0); aPh[1][1] = ldsA(c, 2*p+1, 1);
            __builtin_amdgcn_s_setprio(1);
            #pragma unroll
            for (int mm = 0; mm < 2; ++mm)
                #pragma unroll
                for (int j = 0; j < 4; ++j){
                    acc[2*p+mm][j] = __builtin_amdgcn_mfma_f32_16x16x32_bf16(aPh[mm][0], bF[j][0], acc[2*p+mm][j], 0, 0, 0);
                    acc[2*p+mm][j] = __builtin_amdgcn_mfma_f32_16x16x32_bf16(aPh[mm][1], bF[j][1], acc[2*p+mm][j], 0, 0, 0);
                }
            __builtin_amdgcn_s_setprio(0);
        }
        __builtin_amdgcn_s_barrier();                // buf c reads done -> t+1 may overwrite
    }
    __syncthreads();                                  // K-loop LDS dead -> overlay

    // epilogue: two 64x64 rounds per wave; same pack/LDS-stage/coalesced-store
    // pattern as the 128^2 kernel. cs = 64x72 shorts per wave (9 KB x8 = 72 KB).
    short* cs = (short*)smem + wid*(64*72);
    const int odd = lf & 1;
    const int rsel = odd*2;
    const int subrow = lane >> 3, cq = lane & 7;
    #pragma unroll
    for (int rr2 = 0; rr2 < 2; ++rr2){
        #pragma unroll
        for (int j = 0; j < 4; ++j){
            float bv = bias[bx*256 + wn*64 + j*16 + lf];
            #pragma unroll
            for (int i = 0; i < 4; ++i){
                int im = rr2*4 + i;
                unsigned long long self = 0;
                #pragma unroll
                for (int r = 0; r < 4; ++r){
                    float v = acc[im][j][r] + bv;
                    if constexpr (EPI == 1) v = gelu_f(v);
                    self |= ((unsigned long long)f2bf_bits(v)) << (16*r);
                }
                unsigned long long nbr = __shfl_xor(self, 1);
                unsigned long long lo = odd ? nbr : self;
                unsigned long long hi = odd ? self : nbr;
                int colb = 16*j + (lf & ~1);
                unsigned int w0 = (unsigned int)((lo >> (16*rsel)) & 0xffffu)
                                | ((unsigned int)((hi >> (16*rsel)) & 0xffffu) << 16);
                unsigned int w1 = (unsigned int)((lo >> (16*(rsel+1))) & 0xffffu)
                                | ((unsigned int)((hi >> (16*(rsel+1))) & 0xffffu) << 16);
                *(unsigned int*)(cs + (16*i + 4*g + rsel    )*72 + colb) = w0;
                *(unsigned int*)(cs + (16*i + 4*g + rsel + 1)*72 + colb) = w1;
            }
        }
        // same-wave read-back + coalesced stores (8 rows x 128 B per instr)
        #pragma unroll
        for (int rr = 0; rr < 8; ++rr){
            int rl = rr*8 + subrow;
            short8 vv = *(const short8*)(cs + rl*72 + cq*8);
            int grow = by*256 + wm*128 + rr2*64 + rl;
            int gc   = bx*256 + wn*64 + cq*8;
            if constexpr (EPI == 3){
                int b = grow >> 11, s = grow & 2047;
                int h = (gc >> 6) & 7, d = gc & 63;
                bf16* dst = (gc < 512) ? (bf16*)C : Vhm;
                *(short8*)((short*)dst + (((size_t)(b*NH + h))*SEQ + s)*DHEAD + d) = vv;
            } else {
                *(short8*)((short*)C + (size_t)grow*ldc + gc) = vv;
            }
        }
    }
}

// ---------------------------------------------------------------------------
// 128x128-tile GEMM (round-10 structure) — retained for FFN2 (N=512: only
// 128 blocks at 256^2 would idle half the GPU; 512 blocks here).
// ---------------------------------------------------------------------------
template<int EPI, typename OUT_T>
__global__ __launch_bounds__(256, 3) void gemm128_kernel(const bf16* __restrict__ A,
                                                         const bf16* __restrict__ Bm,
                                                         const float* __restrict__ bias,
                                                         OUT_T* __restrict__ C,
                                                         const float* __restrict__ x2,
                                                         bf16* __restrict__ Vhm,
                                                         int K, int ldc, int lgGX)
{
    __shared__ __align__(16) char smem[49152];   // 3 x (As 8KB | Bs 8KB)
    short* CsBase = (short*)smem;

    const int bid = blockIdx.x;
    const int per = gridDim.x >> 3;
    const int lid = (bid & 7)*per + (bid >> 3);
    const int bx  = lid & ((1 << lgGX) - 1);
    const int by  = lid >> lgGX;

    const int t    = threadIdx.x;
    const int lane = t & 63;
    const int w    = t >> 6;
    const int lf   = lane & 15;
    const int ko   = lane >> 4;
    const int slot = ko ^ ((lf >> 1) & 3);
    const int mrow = (w >> 1)*64, ncol = (w & 1)*64;

    floatx4 acc[4][4];
    floatx4 z = {0.f,0.f,0.f,0.f};
    #pragma unroll
    for (int i = 0; i < 4; ++i)
        #pragma unroll
        for (int j = 0; j < 4; ++j) acc[i][j] = z;

    const int srow = w*16 + (lane >> 2);
    const int sq   = lane & 3;
    const int r0 = srow,      kq0 = sq ^ ((r0 >> 1) & 3);
    const int r1 = 64 + srow, kq1 = sq ^ ((r1 >> 1) & 3);
    const short* ga0 = (const short*)A  + ((size_t)by*128 + r0)*K + kq0*8;
    const short* ga1 = (const short*)A  + ((size_t)by*128 + r1)*K + kq1*8;
    const short* gb0 = (const short*)Bm + ((size_t)bx*128 + r0)*K + kq0*8;
    const short* gb1 = (const short*)Bm + ((size_t)bx*128 + r1)*K + kq1*8;
    char* la0 = smem + w*1024;
    char* la1 = smem + 4096 + w*1024;
    char* lb0 = smem + 8192 + w*1024;
    char* lb1 = smem + 12288 + w*1024;

    auto stage = [&](int off){
        load_lds16(ga0, la0 + off); load_lds16(ga1, la1 + off);
        load_lds16(gb0, lb0 + off); load_lds16(gb1, lb1 + off);
        ga0 += 32; ga1 += 32; gb0 += 32; gb1 += 32;
    };
    auto compute = [&](int off){
        const short* As = (const short*)(smem + off);
        const short* Bs = (const short*)(smem + off + 8192);
        short8 af[4], bfr[4];
        #pragma unroll
        for (int i = 0; i < 4; ++i){
            af[i]  = *(const short8*)(As + (mrow + i*16 + lf)*32 + slot*8);
            bfr[i] = *(const short8*)(Bs + (ncol + i*16 + lf)*32 + slot*8);
        }
        #pragma unroll
        for (int i = 0; i < 4; ++i)
            #pragma unroll
            for (int j = 0; j < 4; ++j)
                acc[i][j] = __builtin_amdgcn_mfma_f32_16x16x32_bf16(af[i], bfr[j], acc[i][j], 0, 0, 0);
    };

    const int T = K >> 5;
    stage(0);
    stage(16384);
    int oc = 0, on = 16384, on2 = 32768;
    for (int kt = 0; kt < T - 2; ++kt){
        asm volatile("s_waitcnt vmcnt(4)" ::: "memory");
        __builtin_amdgcn_s_barrier();
        asm volatile("" ::: "memory");
        stage(on2);
        compute(oc);
        int tmp = oc; oc = on; on = on2; on2 = tmp;
    }
    asm volatile("s_waitcnt vmcnt(4)" ::: "memory");
    __builtin_amdgcn_s_barrier();
    asm volatile("" ::: "memory");
    compute(oc);
    { int tmp = oc; oc = on; on = on2; on2 = tmp; }
    asm volatile("s_waitcnt vmcnt(0)" ::: "memory");
    __builtin_amdgcn_s_barrier();
    asm volatile("" ::: "memory");
    compute(oc);
    __syncthreads();

    if constexpr (EPI == 2){
        const int lr = ko*4;
        #pragma unroll
        for (int j = 0; j < 4; ++j){
            int gcol = bx*128 + ncol + j*16 + lf;
            float bv = bias[gcol];
            #pragma unroll
            for (int i = 0; i < 4; ++i){
                #pragma unroll
                for (int r = 0; r < 4; ++r){
                    size_t grow = (size_t)by*128 + mrow + i*16 + lr + r;
                    float v = acc[i][j][r] + bv + x2[grow*ldc + gcol];
                    store_out(&C[grow*ldc + gcol], v);
                }
            }
        }
    } else {
        short* cs = CsBase + w*(64*72);
        const int odd = lf & 1;
        const int rsel = odd*2;
        #pragma unroll
        for (int j = 0; j < 4; ++j){
            float bv = bias[bx*128 + ncol + j*16 + lf];
            #pragma unroll
            for (int i = 0; i < 4; ++i){
                unsigned long long self = 0;
                #pragma unroll
                for (int r = 0; r < 4; ++r){
                    float v = acc[i][j][r] + bv;
                    if constexpr (EPI == 1) v = gelu_f(v);
                    self |= ((unsigned long long)f2bf_bits(v)) << (16*r);
                }
                unsigned long long nbr = __shfl_xor(self, 1);
                unsigned long long lo = odd ? nbr : self;
                unsigned long long hi = odd ? self : nbr;
                int colb = 16*j + (lf & ~1);
                unsigned int w0 = (unsigned int)((lo >> (16*rsel)) & 0xffffu)
                                | ((unsigned int)((hi >> (16*rsel)) & 0xffffu) << 16);
                unsigned int w1 = (unsigned int)((lo >> (16*(rsel+1))) & 0xffffu)
                                | ((unsigned int)((hi >> (16*(rsel+1))) & 0xffffu) << 16);
                *(unsigned int*)(cs + (16*i + 4*ko + rsel    )*72 + colb) = w0;
                *(unsigned int*)(cs + (16*i + 4*ko + rsel + 1)*72 + colb) = w1;
            }
        }
        const int subrow = lane >> 3, cq = lane & 7;
        #pragma unroll
        for (int rr = 0; rr < 8; ++rr){
            int rl = rr*8 + subrow;
            short8 vv = *(const short8*)(cs + rl*72 + cq*8);
            if constexpr (EPI == 3){
                int grow = by*128 + mrow + rl;
                int b = grow >> 11, s = grow & 2047;
                int gc = bx*128 + ncol + cq*8;
                int h = (gc >> 6) & 7, d = gc & 63;
                bf16* dst = (gc < 512) ? (bf16*)C : Vhm;
                *(short8*)((short*)dst + (((size_t)(b*NH + h))*SEQ + s)*DHEAD + d) = vv;
            } else {
                size_t grow = (size_t)by*128 + mrow + rl;
                int gcol = bx*128 + ncol + cq*8;
                *(short8*)((short*)C + grow*ldc + gcol) = vv;
            }
        }
    }
}

// ---------------------------------------------------------------------------
__global__ void init_kernel(int* selmap){
    int i = blockIdx.x*256 + threadIdx.x;
    if (i < MROWS) selmap[i] = -1;
}

// fp32 -> bf16 weight convert (n multiple of 4)
__global__ __launch_bounds__(256) void cvt_kernel(const float* __restrict__ src,
                                                  bf16* __restrict__ dst, int n){
    int i = (blockIdx.x*256 + threadIdx.x)*4;
    if (i < n){
        float4 v = *(const float4*)(src + i);
        dst[i+0] = __float2bfloat16(v.x);
        dst[i+1] = __float2bfloat16(v.y);
        dst[i+2] = __float2bfloat16(v.z);
        dst[i+3] = __float2bfloat16(v.w);
    }
}

// ---------------------------------------------------------------------------
// LN1 (fp32 in): x -> xn (f32), xnb (bf16), diag[row]=|xn|^2 in fp64 (ranking)
// ---------------------------------------------------------------------------
__global__ __launch_bounds__(256) void ln1_kernel(const float* __restrict__ x,
                                                  const float* __restrict__ g,
                                                  const float* __restrict__ bt,
                                                  float* __restrict__ xn,
                                                  bf16* __restrict__ xnb,
                                                  double* __restrict__ diag)
{
    __shared__ double sbuf[4];
    int row = blockIdx.x;
    int t = threadIdx.x;
    size_t base = (size_t)row*DIM;
    double x0 = (double)x[base + t];
    double x1 = (double)x[base + t + 256];
    double m  = block_sum256d(x0 + x1, sbuf) * (1.0/DIM);
    double d0 = x0 - m, d1 = x1 - m;
    double var = block_sum256d(d0*d0 + d1*d1, sbuf) * (1.0/DIM);
    double r = 1.0/sqrt(var + 1e-5);
    double y0 = d0*r*(double)g[t]     + (double)bt[t];
    double y1 = d1*r*(double)g[t+256] + (double)bt[t+256];
    xn[base+t] = (float)y0;       xn[base+t+256] = (float)y1;
    xnb[base+t] = __float2bfloat16((float)y0);
    xnb[base+t+256] = __float2bfloat16((float)y1);
    double dd = block_sum256d(y0*y0 + y1*y1, sbuf);
    if (t == 0) diag[row] = dd;
}

// column-mean of xn per batch, fp64 two-stage
__global__ __launch_bounds__(512) void xbar_part_kernel(const float* __restrict__ xn, double* __restrict__ part){
    int b = blockIdx.y, c = blockIdx.x, d = threadIdx.x;
    const float* p = xn + ((size_t)b*SEQ + c*64)*DIM + d;
    double s = 0.0;
    for (int i = 0; i < 64; ++i) s += (double)p[(size_t)i*DIM];
    part[((size_t)(b*32 + c))*DIM + d] = s;
}
__global__ __launch_bounds__(512) void xbar_fin_kernel(const double* __restrict__ part,
                                                       double* __restrict__ xbar_d,
                                                       float* __restrict__ xbar_f){
    int b = blockIdx.x, d = threadIdx.x;
    double s = 0.0;
    for (int c = 0; c < 32; ++c) s += part[((size_t)(b*32 + c))*DIM + d];
    s *= (1.0/SEQ);
    xbar_d[(size_t)b*DIM + d] = s;
    xbar_f[(size_t)b*DIM + d] = (float)s;
}

// sparsity*sqrt(D) = diag - dot(xn_row, xbar); fp64 so ranking error << ref fp32 noise
__global__ __launch_bounds__(256) void sparsity_kernel(const float* __restrict__ xn,
                                                       const double* __restrict__ xbar,
                                                       const double* __restrict__ diag,
                                                       double* __restrict__ sp)
{
    int row  = blockIdx.x*4 + (threadIdx.x >> 6);
    int lane = threadIdx.x & 63;
    int b    = row >> 11;
    const float* xr = xn + (size_t)row*DIM;
    const double* xb = xbar + (size_t)b*DIM;
    double s = 0.0;
    for (int e = lane; e < DIM; e += 64) s += (double)xr[e]*xb[e];
    s = wave_sum_d(s);
    if (lane == 0) sp[row] = diag[row] - s;
}

// top-39 per batch (iterative argmax; ties -> lowest index, matching jax top_k)
__global__ __launch_bounds__(256) void topk_kernel(const double* __restrict__ sp,
                                                   int* __restrict__ topidx,
                                                   int* __restrict__ selmap,
                                                   float* __restrict__ dout)
{
    __shared__ double vals[SEQ];
    __shared__ double rv[256];
    __shared__ int    ri[256];
    int b = blockIdx.x, t = threadIdx.x;
    for (int i = t; i < SEQ; i += 256) vals[i] = sp[(size_t)b*SEQ + i];
    __syncthreads();
    for (int it = 0; it < TOPQ; ++it){
        double bv = -1.0e300; int bi = 0;
        for (int i = t; i < SEQ; i += 256){
            double v = vals[i];
            if (v > bv){ bv = v; bi = i; }
        }
        rv[t] = bv; ri[t] = bi;
        __syncthreads();
        for (int stride = 128; stride > 0; stride >>= 1){
            if (t < stride){
                double ov = rv[t+stride]; int oi = ri[t+stride];
                if (ov > rv[t] || (ov == rv[t] && oi < ri[t])){ rv[t] = ov; ri[t] = oi; }
            }
            __syncthreads();
        }
        if (t == 0){
            int idx = ri[0];
            topidx[b*64 + it] = idx;
            selmap[(size_t)b*SEQ + idx] = it;
            vals[idx] = -1.0e300;
        }
        __syncthreads();
    }
    if (b == 0 && t == 0) dout[(size_t)MROWS*DIM] = (float)TOPQ/(float)SEQ;
}

// Q projection for the selected rows -> bf16 head-major Qhm[b][h][48][64]
// (rows TOPQ..47 zero-padded so the MFMA attention can use 3 full 16-row tiles)
__global__ __launch_bounds__(256) void qproj_kernel(const float* __restrict__ xn,
                                                    const float* __restrict__ in_w,
                                                    const float* __restrict__ in_b,
                                                    const int* __restrict__ topidx,
                                                    bf16* __restrict__ Qhm)
{
    int j = blockIdx.x, b = blockIdx.y, t = threadIdx.x;
    __shared__ float qr[DIM];
    if (j >= TOPQ){
        for (int d0 = t; d0 < DIM; d0 += 256){
            int h = d0 >> 6, d = d0 & 63;
            Qhm[((size_t)(b*NH + h)*QPAD + j)*DHEAD + d] = __float2bfloat16(0.f);
        }
        return;
    }
    int srow = topidx[b*64 + j];
    const float* xr = xn + ((size_t)(b*SEQ + srow))*DIM;
    for (int i = t; i < DIM; i += 256) qr[i] = xr[i];
    __syncthreads();
    for (int d0 = t; d0 < DIM; d0 += 256){
        const float* wr = in_w + (size_t)d0*DIM;   // Wq row d0
        float s = 0.f;
        for (int e = 0; e < DIM; e += 4){
            float4 wv = *(const float4*)(wr + e);
            s += qr[e]*wv.x + qr[e+1]*wv.y + qr[e+2]*wv.z + qr[e+3]*wv.w;
        }
        int h = d0 >> 6, d = d0 & 63;
        Qhm[((size_t)(b*NH + h)*QPAD + j)*DHEAD + d] = __float2bfloat16(s + in_b[d0]);
    }
}

// ---------------------------------------------------------------------------
// MFMA split-K attention partial (round-8 structure, unchanged).
// ---------------------------------------------------------------------------
__global__ __launch_bounds__(256, 1) void attn_mfma_kernel(const bf16* __restrict__ Qhm,
                                                           const bf16* __restrict__ Khm,
                                                           const bf16* __restrict__ Vhm,
                                                           float* __restrict__ part)
{
    __shared__ __align__(16) short vsm[4*8192];   // 64 KB: 4 waves x (128k x 64d)
    const int bh   = blockIdx.z*NH + blockIdx.y;
    const int w    = threadIdx.x >> 6;
    const int lane = threadIdx.x & 63;
    const int ch   = blockIdx.x*4 + w;           // chunk 0..15
    const int kb   = ch*KC;                      // first key of chunk
    const int lf   = lane & 15;
    const int g    = lane >> 4;

    short* vbase = vsm + w*8192;
    const short* vg = (const short*)Vhm + ((size_t)bh*SEQ + kb)*DHEAD;
    {
        const int kh = lane >> 1, dh = (lane & 1)*8;
        #pragma unroll
        for (int L = 0; L < 16; ++L){
            int k = (L & 3)*32 + kh;
            int d = (L >> 2)*16 + dh;
            load_lds16(vg + (size_t)k*DHEAD + d, vbase + L*512);
        }
    }

    short8 qf[3][2];
    const short* qp = (const short*)Qhm + (size_t)bh*QPAD*DHEAD;
    #pragma unroll
    for (int nt = 0; nt < 3; ++nt)
        #pragma unroll
        for (int s = 0; s < 2; ++s)
            qf[nt][s] = *(const short8*)(qp + (nt*16 + lf)*DHEAD + s*32 + g*8);

    floatx4 sa[8][3];
    floatx4 z = {0.f,0.f,0.f,0.f};
    #pragma unroll
    for (int mt = 0; mt < 8; ++mt)
        #pragma unroll
        for (int nt = 0; nt < 3; ++nt) sa[mt][nt] = z;

    const short* kp = (const short*)Khm + ((size_t)bh*SEQ + kb)*DHEAD;
    #pragma unroll
    for (int mt = 0; mt < 8; ++mt){
        const short* kr = kp + (size_t)(mt*16 + lf)*DHEAD + g*8;
        short8 kf0 = *(const short8*)(kr);
        short8 kf1 = *(const short8*)(kr + 32);
        #pragma unroll
        for (int nt = 0; nt < 3; ++nt){
            sa[mt][nt] = __builtin_amdgcn_mfma_f32_16x16x32_bf16(kf0, qf[nt][0], sa[mt][nt], 0, 0, 0);
            sa[mt][nt] = __builtin_amdgcn_mfma_f32_16x16x32_bf16(kf1, qf[nt][1], sa[mt][nt], 0, 0, 0);
        }
    }

    float mx[3], ls[3];
    #pragma unroll
    for (int nt = 0; nt < 3; ++nt){
        float m = sa[0][nt][0];
        #pragma unroll
        for (int mt = 0; mt < 8; ++mt)
            #pragma unroll
            for (int r = 0; r < 4; ++r) m = fmaxf(m, sa[mt][nt][r]);
        m = fmaxf(m, __shfl_xor(m, 16));
        m = fmaxf(m, __shfl_xor(m, 32));
        float l = 0.f;
        #pragma unroll
        for (int mt = 0; mt < 8; ++mt){
            #pragma unroll
            for (int r = 0; r < 4; ++r){
                float p = __expf((sa[mt][nt][r] - m)*0.125f);   // 1/sqrt(64)
                sa[mt][nt][r] = p;
                l += p;
            }
        }
        l += __shfl_xor(l, 16);
        l += __shfl_xor(l, 32);
        mx[nt] = m; ls[nt] = l;
    }

    asm volatile("s_waitcnt vmcnt(0)" ::: "memory");   // V staging landed
    floatx4 oacc[3][4];
    #pragma unroll
    for (int mi = 0; mi < 3; ++mi)
        #pragma unroll
        for (int dt = 0; dt < 4; ++dt) oacc[mi][dt] = z;

    #pragma unroll
    for (int t = 0; t < 8; ++t){
        sh4 pa[3];
        #pragma unroll
        for (int mi = 0; mi < 3; ++mi){
            union { sh4 v; unsigned u[2]; } pk;
            pk.u[0] = f2bf_bits(sa[t][mi][0]) | (f2bf_bits(sa[t][mi][1]) << 16);
            pk.u[1] = f2bf_bits(sa[t][mi][2]) | (f2bf_bits(sa[t][mi][3]) << 16);
            pa[mi] = pk.v;
        }
        #pragma unroll
        for (int dt = 0; dt < 4; ++dt){
            sh4 vf = tr16_read(vbase + dt*2048 + (t*16 + 4*g)*16 + lf);
            #pragma unroll
            for (int mi = 0; mi < 3; ++mi)
                oacc[mi][dt] = mfma16(pa[mi], vf, oacc[mi][dt]);
        }
    }

    float* pbase = part + ((size_t)bh*TOPQ*NKC + ch)*PSTR;
    #pragma unroll
    for (int mi = 0; mi < 3; ++mi){
        #pragma unroll
        for (int r = 0; r < 4; ++r){
            int q = mi*16 + 4*g + r;
            if (q < TOPQ){
                float* pp = pbase + (size_t)q*NKC*PSTR;
                #pragma unroll
                for (int dt = 0; dt < 4; ++dt)
                    pp[dt*16 + lf] = oacc[mi][dt][r];
            }
        }
    }
    #pragma unroll
    for (int nt = 0; nt < 3; ++nt){
        int q = nt*16 + lf;
        if (g == 3 && q < TOPQ){
            float* pp = pbase + (size_t)q*NKC*PSTR;
            pp[64] = mx[nt]*0.125f;
            pp[65] = ls[nt];
        }
    }
}

// pass 2: merge 16 partials per (b,h,q); wave per q (4 q per block)  (unchanged)
__global__ __launch_bounds__(256) void attn_reduce_kernel(const float* __restrict__ part,
                                                          float* __restrict__ ctx)
{
    int qc = blockIdx.x, h = blockIdx.y, b = blockIdx.z;
    int w = threadIdx.x >> 6, lane = threadIdx.x & 63;
    int q = qc*4 + w;
    if (q >= TOPQ) return;
    const float* pb = part + (((size_t)(b*NH + h))*TOPQ + q)*NKC*PSTR;
    float M = -3.402823466e38f;
    #pragma unroll
    for (int i = 0; i < NKC; ++i) M = fmaxf(M, pb[i*PSTR + 64]);
    float L = 0.f, a = 0.f;
    #pragma unroll
    for (int i = 0; i < NKC; ++i){
        float sc = __expf(pb[i*PSTR + 64] - M);
        L += pb[i*PSTR + 65]*sc;
        a += pb[i*PSTR + lane]*sc;
    }
    ctx[((size_t)(b*TOPQ + q))*DIM + h*DHEAD + lane] = a/L;
}

// output projection of the 39 ctx rows (fp32 weights)
__global__ __launch_bounds__(256) void outproj_kernel(const float* __restrict__ ctx,
                                                      const float* __restrict__ ow,
                                                      const float* __restrict__ ob,
                                                      float* __restrict__ sout)
{
    int j = blockIdx.x, b = blockIdx.y, t = threadIdx.x;
    __shared__ float cr[DIM];
    const float* xr = ctx + ((size_t)(b*TOPQ + j))*DIM;
    for (int i = t; i < DIM; i += 256) cr[i] = xr[i];
    __syncthreads();
    for (int d0 = t; d0 < DIM; d0 += 256){
        const float* wr = ow + (size_t)d0*DIM;
        float s = 0.f;
        for (int e = 0; e < DIM; e += 4){
            float4 wv = *(const float4*)(wr + e);
            s += cr[e]*wv.x + cr[e+1]*wv.y + cr[e+2]*wv.z + cr[e+3]*wv.w;
        }
        sout[((size_t)(b*TOPQ + j))*DIM + d0] = s + ob[d0];
    }
}

// residual (+ scatter sparse rows / broadcast xbar) then LN2 -> h (bf16), x2 (f32)
__global__ __launch_bounds__(256) void res_ln2_kernel(const float* __restrict__ x,
                                                      const float* __restrict__ xbar,
                                                      const float* __restrict__ sout,
                                                      const int* __restrict__ selmap,
                                                      const float* __restrict__ g2,
                                                      const float* __restrict__ bt2,
                                                      float* __restrict__ x2,
                                                      bf16* __restrict__ hb)
{
    __shared__ float sbuf[4];
    int row = blockIdx.x;
    int b = row >> 11;
    int t = threadIdx.x;
    int slot = selmap[row];
    const float* ar = (slot >= 0) ? (sout + ((size_t)(b*TOPQ + slot))*DIM)
                                  : (xbar + (size_t)b*DIM);
    size_t base = (size_t)row*DIM;
    float v0 = x[base + t]       + ar[t];
    float v1 = x[base + t + 256] + ar[t + 256];
    x2[base + t] = v0; x2[base + t + 256] = v1;
    float m = block_sum256(v0 + v1, sbuf) * (1.f/DIM);
    float d0 = v0 - m, d1 = v1 - m;
    float var = block_sum256(d0*d0 + d1*d1, sbuf) * (1.f/DIM);
    float r = 1.f/sqrtf(var + 1e-5f);
    hb[base + t]       = __float2bfloat16(d0*r*g2[t]     + bt2[t]);
    hb[base + t + 256] = __float2bfloat16(d1*r*g2[t+256] + bt2[t+256]);
}

// ---------------------------------------------------------------------------
extern "C" void kernel_launch(void* const* d_in, const int* in_sizes, int n_in,
                              void* d_out, int out_size, void* d_ws, size_t ws_size,
                              hipStream_t stream)
{
    (void)in_sizes; (void)n_in; (void)out_size; (void)ws_size;
    const float* x     = (const float*)d_in[0];
    const float* ln1_g = (const float*)d_in[1];
    const float* ln1_b = (const float*)d_in[2];
    const float* in_w  = (const float*)d_in[3];
    const float* in_b  = (const float*)d_in[4];
    const float* out_w = (const float*)d_in[5];
    const float* out_b = (const float*)d_in[6];
    const float* ln2_g = (const float*)d_in[7];
    const float* ln2_b = (const float*)d_in[8];
    const float* w1    = (const float*)d_in[9];
    const float* b1    = (const float*)d_in[10];
    const float* w2    = (const float*)d_in[11];
    const float* b2    = (const float*)d_in[12];
    float* out = (float*)d_out;

    const size_t MB = 1024*1024;
    char* base = (char*)d_ws;
    float* xn_f  = (float*)base;                 // [0,32MiB); reused as x2_f later
    bf16*  xn_b  = (bf16*)(base + 32*MB);        // dead after kv-gemm -> h_b
    bf16*  Khm   = (bf16*)(base + 48*MB);
    bf16*  Vhm   = (bf16*)(base + 64*MB);
    bf16*  h_b   = (bf16*)(base + 32*MB);
    bf16*  h1_b  = (bf16*)(base + 48*MB);        // overwrites Khm/Vhm after attn
    float* x2_f  = xn_f;
    char* p = base + 112*MB;
    bf16*  kvw_b  = (bf16*)p;  p += (size_t)1024*DIM*2;        // in_w rows [512,1536) bf16
    bf16*  w1_b   = (bf16*)p;  p += (size_t)FFD*DIM*2;
    bf16*  w2_b   = (bf16*)p;  p += (size_t)DIM*FFD*2;
    double* xbpart= (double*)p; p += (size_t)BATCH*32*DIM*8;
    double* xbar_d= (double*)p; p += (size_t)BATCH*DIM*8;
    float* xbar_f = (float*)p;  p += (size_t)BATCH*DIM*4;
    double* diag  = (double*)p; p += (size_t)MROWS*8;
    double* spars = (double*)p; p += (size_t)MROWS*8;
    int*   topidx = (int*)p;    p += (size_t)BATCH*64*4;
    int*   selmap = (int*)p;    p += (size_t)MROWS*4;
    bf16*  Qhm    = (bf16*)p;   p += (size_t)BATCH*NH*QPAD*DHEAD*2;   // 384 KiB
    float* ctxb   = (float*)p;  p += (size_t)BATCH*TOPQ*DIM*4;
    float* sout   = (float*)p;  p += (size_t)BATCH*TOPQ*DIM*4;
    float* apart  = (float*)p;  p += (size_t)BATCH*NH*TOPQ*NKC*PSTR*4;  // 10.5 MB

    init_kernel<<<64, 256, 0, stream>>>(selmap);
    cvt_kernel<<<512,  256, 0, stream>>>(in_w + (size_t)DIM*DIM, kvw_b, 1024*DIM);
    cvt_kernel<<<1024, 256, 0, stream>>>(w1, w1_b, FFD*DIM);
    cvt_kernel<<<1024, 256, 0, stream>>>(w2, w2_b, DIM*FFD);
    ln1_kernel<<<MROWS, 256, 0, stream>>>(x, ln1_g, ln1_b, xn_f, xn_b, diag);
    xbar_part_kernel<<<dim3(32, BATCH), 512, 0, stream>>>(xn_f, xbpart);
    xbar_fin_kernel<<<BATCH, 512, 0, stream>>>(xbpart, xbar_d, xbar_f);
    sparsity_kernel<<<MROWS/4, 256, 0, stream>>>(xn_f, xbar_d, diag, spars);
    topk_kernel<<<BATCH, 256, 0, stream>>>(spars, topidx, selmap, out);
    // KV projection (M=16384, N=1024 -> head-major K/V): 256^2, grid 64x4
    gemm256_kernel<3, bf16><<<256, 512, 131072, stream>>>(
        xn_b, kvw_b, in_b + DIM, Khm, Vhm, DIM, 0, 2);
    qproj_kernel<<<dim3(QPAD, BATCH), 256, 0, stream>>>(xn_f, in_w, in_b, topidx, Qhm);
    attn_mfma_kernel<<<dim3(NKC/4, NH, BATCH), 256, 0, stream>>>(Qhm, Khm, Vhm, apart);
    attn_reduce_kernel<<<dim3((TOPQ + 3)/4, NH, BATCH), 256, 0, stream>>>(apart, ctxb);
    outproj_kernel<<<dim3(TOPQ, BATCH), 256, 0, stream>>>(ctxb, out_w, out_b, sout);
    res_ln2_kernel<<<MROWS, 256, 0, stream>>>(x, xbar_f, sout, selmap, ln2_g, ln2_b, x2_f, h_b);
    // FFN1 (M=16384, N=2048): 256^2, grid 64x8
    gemm256_kernel<1, bf16><<<512, 512, 131072, stream>>>(
        h_b, w1_b, b1, h1_b, nullptr, DIM, FFD, 3);
    // FFN2 (N=512): keep 128^2 (512 blocks; 256^2 would idle half the GPU)
    gemm128_kernel<2, float><<<512, 256, 0, stream>>>(
        h1_b, w2_b, b2, out, x2_f, nullptr, FFD, DIM, 2);
}

// Round 6
// 466.255 us; speedup vs baseline: 1.0706x; 1.0660x over previous
//
#include <hip/hip_runtime.h>
#include <hip/hip_bf16.h>
#include <math.h>

#define BATCH 8
#define SEQ   2048
#define DIM   512
#define NH    8
#define DHEAD 64
#define FFD   2048
#define TOPQ  39            // ceil(5*ln(2048)) with factor=5, min_k=5 (fixed harness inputs)
#define MROWS (BATCH*SEQ)   // 16384
#define KC    128           // keys per attention partial chunk (one wave)
#define NKC   (SEQ/KC)      // 16
#define PSTR  66            // partial stride: 64 ctx + m + l
#define QPAD  48            // TOPQ padded to 3 MFMA row-tiles

typedef __hip_bfloat16 bf16;
typedef __attribute__((ext_vector_type(8))) short short8;
typedef __attribute__((ext_vector_type(4))) short sh4;
typedef __attribute__((ext_vector_type(4))) float floatx4;

__device__ __forceinline__ float bf2f(short u){
    return __uint_as_float(((unsigned int)(unsigned short)u) << 16);
}
// RNE fp32->bf16 bits (matches hardware convert for finite values)
__device__ __forceinline__ unsigned int f2bf_bits(float f){
    unsigned int u = __float_as_uint(f);
    return (u + 0x7fffu + ((u >> 16) & 1u)) >> 16;
}
// fast gelu (tanh form): |err vs exact erf-gelu| < ~3e-3, << bf16 rounding here
__device__ __forceinline__ float gelu_f(float v){
    float u = v*(0.7978845608028654f + 0.0356774081363f*v*v);
    float e = __expf(2.f*u);
    return 0.5f*v*(2.f - 2.f/(e + 1.f));
}
__device__ __forceinline__ float wave_sum(float v){
    #pragma unroll
    for (int off = 32; off > 0; off >>= 1) v += __shfl_down(v, off);
    return v;
}
__device__ __forceinline__ double wave_sum_d(double v){
    #pragma unroll
    for (int off = 32; off > 0; off >>= 1) v += __shfl_down(v, off);
    return v;
}
// block = 256 threads (4 waves)
__device__ __forceinline__ float block_sum256(float v, float* sbuf){
    v = wave_sum(v);
    if ((threadIdx.x & 63) == 0) sbuf[threadIdx.x >> 6] = v;
    __syncthreads();
    float r = sbuf[0] + sbuf[1] + sbuf[2] + sbuf[3];
    __syncthreads();
    return r;
}
__device__ __forceinline__ double block_sum256d(double v, double* sbuf){
    v = wave_sum_d(v);
    if ((threadIdx.x & 63) == 0) sbuf[threadIdx.x >> 6] = v;
    __syncthreads();
    double r = sbuf[0] + sbuf[1] + sbuf[2] + sbuf[3];
    __syncthreads();
    return r;
}

// async global->LDS, 16 B per lane; LDS dest = wave-uniform base + lane*16
__device__ __forceinline__ void load_lds16(const void* g, void* l){
    auto gp = reinterpret_cast<const uint32_t __attribute__((address_space(1)))*>(
        reinterpret_cast<uintptr_t>(g));
    auto lp = reinterpret_cast<uint32_t __attribute__((address_space(3)))*>(
        reinterpret_cast<uintptr_t>(l));
    __builtin_amdgcn_global_load_lds(gp, lp, 16, 0, 0);
}

// 16x16x16 bf16 MFMA (K=16): A/B = 4 bf16/lane (k = (lane>>4)*4 + j), C/D std 16x16 map
__device__ __forceinline__ floatx4 mfma16(sh4 a, sh4 b, floatx4 c){
#if __has_builtin(__builtin_amdgcn_mfma_f32_16x16x16bf16_1k)
    return __builtin_amdgcn_mfma_f32_16x16x16bf16_1k(a, b, c, 0, 0, 0);
#elif __has_builtin(__builtin_amdgcn_mfma_f32_16x16x16_bf16)
    return __builtin_amdgcn_mfma_f32_16x16x16_bf16(a, b, c, 0, 0, 0);
#else
    asm volatile("v_mfma_f32_16x16x16_bf16 %0, %1, %2, %0\n\ts_nop 7\n\ts_nop 7"
                 : "+v"(c) : "v"(a), "v"(b));
    return c;
#endif
}

// transpose-read: 4 bf16 at elem strides {0,16,32,48} from per-lane LDS addr
__device__ __forceinline__ sh4 tr16_read(const short* p){
#if __has_builtin(__builtin_amdgcn_ds_read_tr16_b64_v4i16)
    auto lp = (__attribute__((address_space(3))) sh4*)(uintptr_t)p;
    return __builtin_amdgcn_ds_read_tr16_b64_v4i16(lp);
#elif __has_builtin(__builtin_amdgcn_ds_read_tr16_b64)
    auto lp = (__attribute__((address_space(3))) sh4*)(uintptr_t)p;
    return __builtin_amdgcn_ds_read_tr16_b64(lp);
#else
    sh4 r; r[0] = p[0]; r[1] = p[16]; r[2] = p[32]; r[3] = p[48]; return r;
#endif
}

__device__ __forceinline__ void store_out(bf16* p, float v){ *p = __float2bfloat16(v); }
__device__ __forceinline__ void store_out(float* p, float v){ *p = v; }

// ---------------------------------------------------------------------------
// 128x128-tile GEMM (round-10 proven structure): C = A(MxK)·B(NxK)^T + bias.
// Depth-2 pipeline, counted vmcnt (T4). 3 x 16 KB LDS buffers:
//   prologue: stage(b0); stage(b1)                    // 8 loads in flight
//   loop kt : vmcnt(4) ; s_barrier ; stage(b[kt+2]) ; compute(b[kt])
//   tail    : vmcnt(4)/bar/compute ; vmcnt(0)/bar/compute
// (Round-11/12 256^2 experiments regressed: shallow-K shapes at 1 block/CU
// are prologue/epilogue/tail-bound, not sync-structure-bound. Reverted.)
// EPI: 1 = gelu->bf16, 2 = +x2 -> fp32 (direct stores), 3 = KV head-major.
// ---------------------------------------------------------------------------
template<int EPI, typename OUT_T>
__global__ __launch_bounds__(256, 3) void gemm128_kernel(const bf16* __restrict__ A,
                                                         const bf16* __restrict__ Bm,
                                                         const float* __restrict__ bias,
                                                         OUT_T* __restrict__ C,
                                                         const float* __restrict__ x2,
                                                         bf16* __restrict__ Vhm,
                                                         int K, int ldc, int lgGX)
{
    __shared__ __align__(16) char smem[49152];   // 3 x (As 8KB | Bs 8KB)
    short* CsBase = (short*)smem;

    const int bid = blockIdx.x;
    const int per = gridDim.x >> 3;
    const int lid = (bid & 7)*per + (bid >> 3);
    const int bx  = lid & ((1 << lgGX) - 1);
    const int by  = lid >> lgGX;

    const int t    = threadIdx.x;
    const int lane = t & 63;
    const int w    = t >> 6;
    const int lf   = lane & 15;
    const int ko   = lane >> 4;
    const int slot = ko ^ ((lf >> 1) & 3);
    const int mrow = (w >> 1)*64, ncol = (w & 1)*64;

    floatx4 acc[4][4];
    floatx4 z = {0.f,0.f,0.f,0.f};
    #pragma unroll
    for (int i = 0; i < 4; ++i)
        #pragma unroll
        for (int j = 0; j < 4; ++j) acc[i][j] = z;

    const int srow = w*16 + (lane >> 2);
    const int sq   = lane & 3;
    const int r0 = srow,      kq0 = sq ^ ((r0 >> 1) & 3);
    const int r1 = 64 + srow, kq1 = sq ^ ((r1 >> 1) & 3);
    const short* ga0 = (const short*)A  + ((size_t)by*128 + r0)*K + kq0*8;
    const short* ga1 = (const short*)A  + ((size_t)by*128 + r1)*K + kq1*8;
    const short* gb0 = (const short*)Bm + ((size_t)bx*128 + r0)*K + kq0*8;
    const short* gb1 = (const short*)Bm + ((size_t)bx*128 + r1)*K + kq1*8;
    char* la0 = smem + w*1024;
    char* la1 = smem + 4096 + w*1024;
    char* lb0 = smem + 8192 + w*1024;
    char* lb1 = smem + 12288 + w*1024;

    auto stage = [&](int off){
        load_lds16(ga0, la0 + off); load_lds16(ga1, la1 + off);
        load_lds16(gb0, lb0 + off); load_lds16(gb1, lb1 + off);
        ga0 += 32; ga1 += 32; gb0 += 32; gb1 += 32;
    };
    auto compute = [&](int off){
        const short* As = (const short*)(smem + off);
        const short* Bs = (const short*)(smem + off + 8192);
        short8 af[4], bfr[4];
        #pragma unroll
        for (int i = 0; i < 4; ++i){
            af[i]  = *(const short8*)(As + (mrow + i*16 + lf)*32 + slot*8);
            bfr[i] = *(const short8*)(Bs + (ncol + i*16 + lf)*32 + slot*8);
        }
        #pragma unroll
        for (int i = 0; i < 4; ++i)
            #pragma unroll
            for (int j = 0; j < 4; ++j)
                acc[i][j] = __builtin_amdgcn_mfma_f32_16x16x32_bf16(af[i], bfr[j], acc[i][j], 0, 0, 0);
    };

    const int T = K >> 5;
    stage(0);
    stage(16384);
    int oc = 0, on = 16384, on2 = 32768;
    for (int kt = 0; kt < T - 2; ++kt){
        asm volatile("s_waitcnt vmcnt(4)" ::: "memory");
        __builtin_amdgcn_s_barrier();
        asm volatile("" ::: "memory");
        stage(on2);
        compute(oc);
        int tmp = oc; oc = on; on = on2; on2 = tmp;
    }
    asm volatile("s_waitcnt vmcnt(4)" ::: "memory");
    __builtin_amdgcn_s_barrier();
    asm volatile("" ::: "memory");
    compute(oc);
    { int tmp = oc; oc = on; on = on2; on2 = tmp; }
    asm volatile("s_waitcnt vmcnt(0)" ::: "memory");
    __builtin_amdgcn_s_barrier();
    asm volatile("" ::: "memory");
    compute(oc);
    __syncthreads();

    if constexpr (EPI == 2){
        const int lr = ko*4;
        #pragma unroll
        for (int j = 0; j < 4; ++j){
            int gcol = bx*128 + ncol + j*16 + lf;
            float bv = bias[gcol];
            #pragma unroll
            for (int i = 0; i < 4; ++i){
                #pragma unroll
                for (int r = 0; r < 4; ++r){
                    size_t grow = (size_t)by*128 + mrow + i*16 + lr + r;
                    float v = acc[i][j][r] + bv + x2[grow*ldc + gcol];
                    store_out(&C[grow*ldc + gcol], v);
                }
            }
        }
    } else {
        short* cs = CsBase + w*(64*72);
        const int odd = lf & 1;
        const int rsel = odd*2;
        #pragma unroll
        for (int j = 0; j < 4; ++j){
            float bv = bias[bx*128 + ncol + j*16 + lf];
            #pragma unroll
            for (int i = 0; i < 4; ++i){
                unsigned long long self = 0;
                #pragma unroll
                for (int r = 0; r < 4; ++r){
                    float v = acc[i][j][r] + bv;
                    if constexpr (EPI == 1) v = gelu_f(v);
                    self |= ((unsigned long long)f2bf_bits(v)) << (16*r);
                }
                unsigned long long nbr = __shfl_xor(self, 1);
                unsigned long long lo = odd ? nbr : self;
                unsigned long long hi = odd ? self : nbr;
                int colb = 16*j + (lf & ~1);
                unsigned int w0 = (unsigned int)((lo >> (16*rsel)) & 0xffffu)
                                | ((unsigned int)((hi >> (16*rsel)) & 0xffffu) << 16);
                unsigned int w1 = (unsigned int)((lo >> (16*(rsel+1))) & 0xffffu)
                                | ((unsigned int)((hi >> (16*(rsel+1))) & 0xffffu) << 16);
                *(unsigned int*)(cs + (16*i + 4*ko + rsel    )*72 + colb) = w0;
                *(unsigned int*)(cs + (16*i + 4*ko + rsel + 1)*72 + colb) = w1;
            }
        }
        const int subrow = lane >> 3, cq = lane & 7;
        #pragma unroll
        for (int rr = 0; rr < 8; ++rr){
            int rl = rr*8 + subrow;
            short8 vv = *(const short8*)(cs + rl*72 + cq*8);
            if constexpr (EPI == 3){
                int grow = by*128 + mrow + rl;
                int b = grow >> 11, s = grow & 2047;
                int gc = bx*128 + ncol + cq*8;
                int h = (gc >> 6) & 7, d = gc & 63;
                bf16* dst = (gc < 512) ? (bf16*)C : Vhm;
                *(short8*)((short*)dst + (((size_t)(b*NH + h))*SEQ + s)*DHEAD + d) = vv;
            } else {
                size_t grow = (size_t)by*128 + mrow + rl;
                int gcol = bx*128 + ncol + cq*8;
                *(short8*)((short*)C + grow*ldc + gcol) = vv;
            }
        }
    }
}

// ---------------------------------------------------------------------------
__global__ void init_kernel(int* selmap){
    int i = blockIdx.x*256 + threadIdx.x;
    if (i < MROWS) selmap[i] = -1;
}

// fp32 -> bf16 weight convert (n multiple of 4)
__global__ __launch_bounds__(256) void cvt_kernel(const float* __restrict__ src,
                                                  bf16* __restrict__ dst, int n){
    int i = (blockIdx.x*256 + threadIdx.x)*4;
    if (i < n){
        float4 v = *(const float4*)(src + i);
        dst[i+0] = __float2bfloat16(v.x);
        dst[i+1] = __float2bfloat16(v.y);
        dst[i+2] = __float2bfloat16(v.z);
        dst[i+3] = __float2bfloat16(v.w);
    }
}

// ---------------------------------------------------------------------------
// LN1 (fp32 in): x -> xn (f32), xnb (bf16), diag[row]=|xn|^2 in fp64 (ranking)
// ---------------------------------------------------------------------------
__global__ __launch_bounds__(256) void ln1_kernel(const float* __restrict__ x,
                                                  const float* __restrict__ g,
                                                  const float* __restrict__ bt,
                                                  float* __restrict__ xn,
                                                  bf16* __restrict__ xnb,
                                                  double* __restrict__ diag)
{
    __shared__ double sbuf[4];
    int row = blockIdx.x;
    int t = threadIdx.x;
    size_t base = (size_t)row*DIM;
    double x0 = (double)x[base + t];
    double x1 = (double)x[base + t + 256];
    double m  = block_sum256d(x0 + x1, sbuf) * (1.0/DIM);
    double d0 = x0 - m, d1 = x1 - m;
    double var = block_sum256d(d0*d0 + d1*d1, sbuf) * (1.0/DIM);
    double r = 1.0/sqrt(var + 1e-5);
    double y0 = d0*r*(double)g[t]     + (double)bt[t];
    double y1 = d1*r*(double)g[t+256] + (double)bt[t+256];
    xn[base+t] = (float)y0;       xn[base+t+256] = (float)y1;
    xnb[base+t] = __float2bfloat16((float)y0);
    xnb[base+t+256] = __float2bfloat16((float)y1);
    double dd = block_sum256d(y0*y0 + y1*y1, sbuf);
    if (t == 0) diag[row] = dd;
}

// column-mean of xn per batch, fp64 two-stage
__global__ __launch_bounds__(512) void xbar_part_kernel(const float* __restrict__ xn, double* __restrict__ part){
    int b = blockIdx.y, c = blockIdx.x, d = threadIdx.x;
    const float* p = xn + ((size_t)b*SEQ + c*64)*DIM + d;
    double s = 0.0;
    for (int i = 0; i < 64; ++i) s += (double)p[(size_t)i*DIM];
    part[((size_t)(b*32 + c))*DIM + d] = s;
}
__global__ __launch_bounds__(512) void xbar_fin_kernel(const double* __restrict__ part,
                                                       double* __restrict__ xbar_d,
                                                       float* __restrict__ xbar_f){
    int b = blockIdx.x, d = threadIdx.x;
    double s = 0.0;
    for (int c = 0; c < 32; ++c) s += part[((size_t)(b*32 + c))*DIM + d];
    s *= (1.0/SEQ);
    xbar_d[(size_t)b*DIM + d] = s;
    xbar_f[(size_t)b*DIM + d] = (float)s;
}

// sparsity*sqrt(D) = diag - dot(xn_row, xbar); fp64 so ranking error << ref fp32 noise
__global__ __launch_bounds__(256) void sparsity_kernel(const float* __restrict__ xn,
                                                       const double* __restrict__ xbar,
                                                       const double* __restrict__ diag,
                                                       double* __restrict__ sp)
{
    int row  = blockIdx.x*4 + (threadIdx.x >> 6);
    int lane = threadIdx.x & 63;
    int b    = row >> 11;
    const float* xr = xn + (size_t)row*DIM;
    const double* xb = xbar + (size_t)b*DIM;
    double s = 0.0;
    for (int e = lane; e < DIM; e += 64) s += (double)xr[e]*xb[e];
    s = wave_sum_d(s);
    if (lane == 0) sp[row] = diag[row] - s;
}

// ---------------------------------------------------------------------------
// Round-13: register-resident top-39. Old version: 39 serial full-LDS rescans
// + 8-step tree with 8 __syncthreads each, on an 8-block grid (3% occupancy)
// -> ~25-30us of pure latency. New: each thread holds its 8 candidates packed
// as monotone u64 (order_bits(sp) & ~2047) | (2047 - idx):
//   * integer max == (value desc, then LOWEST index wins tie) in one op
//   * truncating fp64 below bit 41 only merges pairs that are exact ties in
//     the reference's fp32 scores, where jax top_k takes the lower index --
//     exactly what the packed order yields (>= old code's fidelity).
// Per iteration: 6 u64 shfl_xor wave-max + 4-entry LDS combine + owner clears
// its slot (compile-time indexing, no scratch). 2 barriers/iter. ~5us.
// ---------------------------------------------------------------------------
__global__ __launch_bounds__(256) void topk_kernel(const double* __restrict__ sp,
                                                   int* __restrict__ topidx,
                                                   int* __restrict__ selmap,
                                                   float* __restrict__ dout)
{
    __shared__ unsigned long long wmax[4];
    int b = blockIdx.x, t = threadIdx.x;
    int lane = t & 63, w = t >> 6;

    unsigned long long pk[8];
    #pragma unroll
    for (int i = 0; i < 8; ++i){
        int idx = i*256 + t;                          // coalesced
        unsigned long long bits =
            (unsigned long long)__double_as_longlong(sp[(size_t)b*SEQ + idx]);
        unsigned long long m = (bits & 0x8000000000000000ull)
                             ? ~bits : (bits | 0x8000000000000000ull);
        pk[i] = (m & ~2047ull) | (unsigned long long)(2047 - idx);
    }
    unsigned long long lm = pk[0];
    #pragma unroll
    for (int i = 1; i < 8; ++i) lm = (pk[i] > lm) ? pk[i] : lm;

    for (int it = 0; it < TOPQ; ++it){
        unsigned long long m = lm;
        #pragma unroll
        for (int off = 32; off > 0; off >>= 1){
            unsigned long long o = __shfl_xor(m, off);
            m = (o > m) ? o : m;
        }
        if (lane == 0) wmax[w] = m;
        __syncthreads();
        unsigned long long g01 = (wmax[0] > wmax[1]) ? wmax[0] : wmax[1];
        unsigned long long g23 = (wmax[2] > wmax[3]) ? wmax[2] : wmax[3];
        unsigned long long g = (g01 > g23) ? g01 : g23;
        int idx = 2047 - (int)(g & 2047ull);
        if (t == 0){
            topidx[b*64 + it] = idx;
            selmap[(size_t)b*SEQ + idx] = it;
        }
        if ((idx & 255) == t){                        // owner removes + recompute
            int slot = idx >> 8;
            #pragma unroll
            for (int i = 0; i < 8; ++i) if (i == slot) pk[i] = 0;
            lm = pk[0];
            #pragma unroll
            for (int i = 1; i < 8; ++i) lm = (pk[i] > lm) ? pk[i] : lm;
        }
        __syncthreads();                              // wmax reuse safety
    }
    if (b == 0 && t == 0) dout[(size_t)MROWS*DIM] = (float)TOPQ/(float)SEQ;
}

// Q projection for the selected rows -> bf16 head-major Qhm[b][h][48][64]
// (rows TOPQ..47 zero-padded so the MFMA attention can use 3 full 16-row tiles)
__global__ __launch_bounds__(256) void qproj_kernel(const float* __restrict__ xn,
                                                    const float* __restrict__ in_w,
                                                    const float* __restrict__ in_b,
                                                    const int* __restrict__ topidx,
                                                    bf16* __restrict__ Qhm)
{
    int j = blockIdx.x, b = blockIdx.y, t = threadIdx.x;
    __shared__ float qr[DIM];
    if (j >= TOPQ){
        for (int d0 = t; d0 < DIM; d0 += 256){
            int h = d0 >> 6, d = d0 & 63;
            Qhm[((size_t)(b*NH + h)*QPAD + j)*DHEAD + d] = __float2bfloat16(0.f);
        }
        return;
    }
    int srow = topidx[b*64 + j];
    const float* xr = xn + ((size_t)(b*SEQ + srow))*DIM;
    for (int i = t; i < DIM; i += 256) qr[i] = xr[i];
    __syncthreads();
    for (int d0 = t; d0 < DIM; d0 += 256){
        const float* wr = in_w + (size_t)d0*DIM;   // Wq row d0
        float s = 0.f;
        for (int e = 0; e < DIM; e += 4){
            float4 wv = *(const float4*)(wr + e);
            s += qr[e]*wv.x + qr[e+1]*wv.y + qr[e+2]*wv.z + qr[e+3]*wv.w;
        }
        int h = d0 >> 6, d = d0 & 63;
        Qhm[((size_t)(b*NH + h)*QPAD + j)*DHEAD + d] = __float2bfloat16(s + in_b[d0]);
    }
}

// ---------------------------------------------------------------------------
// MFMA split-K attention partial (round-8 structure, unchanged).
// ---------------------------------------------------------------------------
__global__ __launch_bounds__(256, 1) void attn_mfma_kernel(const bf16* __restrict__ Qhm,
                                                           const bf16* __restrict__ Khm,
                                                           const bf16* __restrict__ Vhm,
                                                           float* __restrict__ part)
{
    __shared__ __align__(16) short vsm[4*8192];   // 64 KB: 4 waves x (128k x 64d)
    const int bh   = blockIdx.z*NH + blockIdx.y;
    const int w    = threadIdx.x >> 6;
    const int lane = threadIdx.x & 63;
    const int ch   = blockIdx.x*4 + w;           // chunk 0..15
    const int kb   = ch*KC;                      // first key of chunk
    const int lf   = lane & 15;
    const int g    = lane >> 4;

    short* vbase = vsm + w*8192;
    const short* vg = (const short*)Vhm + ((size_t)bh*SEQ + kb)*DHEAD;
    {
        const int kh = lane >> 1, dh = (lane & 1)*8;
        #pragma unroll
        for (int L = 0; L < 16; ++L){
            int k = (L & 3)*32 + kh;
            int d = (L >> 2)*16 + dh;
            load_lds16(vg + (size_t)k*DHEAD + d, vbase + L*512);
        }
    }

    short8 qf[3][2];
    const short* qp = (const short*)Qhm + (size_t)bh*QPAD*DHEAD;
    #pragma unroll
    for (int nt = 0; nt < 3; ++nt)
        #pragma unroll
        for (int s = 0; s < 2; ++s)
            qf[nt][s] = *(const short8*)(qp + (nt*16 + lf)*DHEAD + s*32 + g*8);

    floatx4 sa[8][3];
    floatx4 z = {0.f,0.f,0.f,0.f};
    #pragma unroll
    for (int mt = 0; mt < 8; ++mt)
        #pragma unroll
        for (int nt = 0; nt < 3; ++nt) sa[mt][nt] = z;

    const short* kp = (const short*)Khm + ((size_t)bh*SEQ + kb)*DHEAD;
    #pragma unroll
    for (int mt = 0; mt < 8; ++mt){
        const short* kr = kp + (size_t)(mt*16 + lf)*DHEAD + g*8;
        short8 kf0 = *(const short8*)(kr);
        short8 kf1 = *(const short8*)(kr + 32);
        #pragma unroll
        for (int nt = 0; nt < 3; ++nt){
            sa[mt][nt] = __builtin_amdgcn_mfma_f32_16x16x32_bf16(kf0, qf[nt][0], sa[mt][nt], 0, 0, 0);
            sa[mt][nt] = __builtin_amdgcn_mfma_f32_16x16x32_bf16(kf1, qf[nt][1], sa[mt][nt], 0, 0, 0);
        }
    }

    float mx[3], ls[3];
    #pragma unroll
    for (int nt = 0; nt < 3; ++nt){
        float m = sa[0][nt][0];
        #pragma unroll
        for (int mt = 0; mt < 8; ++mt)
            #pragma unroll
            for (int r = 0; r < 4; ++r) m = fmaxf(m, sa[mt][nt][r]);
        m = fmaxf(m, __shfl_xor(m, 16));
        m = fmaxf(m, __shfl_xor(m, 32));
        float l = 0.f;
        #pragma unroll
        for (int mt = 0; mt < 8; ++mt){
            #pragma unroll
            for (int r = 0; r < 4; ++r){
                float p = __expf((sa[mt][nt][r] - m)*0.125f);   // 1/sqrt(64)
                sa[mt][nt][r] = p;
                l += p;
            }
        }
        l += __shfl_xor(l, 16);
        l += __shfl_xor(l, 32);
        mx[nt] = m; ls[nt] = l;
    }

    asm volatile("s_waitcnt vmcnt(0)" ::: "memory");   // V staging landed
    floatx4 oacc[3][4];
    #pragma unroll
    for (int mi = 0; mi < 3; ++mi)
        #pragma unroll
        for (int dt = 0; dt < 4; ++dt) oacc[mi][dt] = z;

    #pragma unroll
    for (int t = 0; t < 8; ++t){
        sh4 pa[3];
        #pragma unroll
        for (int mi = 0; mi < 3; ++mi){
            union { sh4 v; unsigned u[2]; } pk;
            pk.u[0] = f2bf_bits(sa[t][mi][0]) | (f2bf_bits(sa[t][mi][1]) << 16);
            pk.u[1] = f2bf_bits(sa[t][mi][2]) | (f2bf_bits(sa[t][mi][3]) << 16);
            pa[mi] = pk.v;
        }
        #pragma unroll
        for (int dt = 0; dt < 4; ++dt){
            sh4 vf = tr16_read(vbase + dt*2048 + (t*16 + 4*g)*16 + lf);
            #pragma unroll
            for (int mi = 0; mi < 3; ++mi)
                oacc[mi][dt] = mfma16(pa[mi], vf, oacc[mi][dt]);
        }
    }

    float* pbase = part + ((size_t)bh*TOPQ*NKC + ch)*PSTR;
    #pragma unroll
    for (int mi = 0; mi < 3; ++mi){
        #pragma unroll
        for (int r = 0; r < 4; ++r){
            int q = mi*16 + 4*g + r;
            if (q < TOPQ){
                float* pp = pbase + (size_t)q*NKC*PSTR;
                #pragma unroll
                for (int dt = 0; dt < 4; ++dt)
                    pp[dt*16 + lf] = oacc[mi][dt][r];
            }
        }
    }
    #pragma unroll
    for (int nt = 0; nt < 3; ++nt){
        int q = nt*16 + lf;
        if (g == 3 && q < TOPQ){
            float* pp = pbase + (size_t)q*NKC*PSTR;
            pp[64] = mx[nt]*0.125f;
            pp[65] = ls[nt];
        }
    }
}

// pass 2: merge 16 partials per (b,h,q); wave per q (4 q per block)  (unchanged)
__global__ __launch_bounds__(256) void attn_reduce_kernel(const float* __restrict__ part,
                                                          float* __restrict__ ctx)
{
    int qc = blockIdx.x, h = blockIdx.y, b = blockIdx.z;
    int w = threadIdx.x >> 6, lane = threadIdx.x & 63;
    int q = qc*4 + w;
    if (q >= TOPQ) return;
    const float* pb = part + (((size_t)(b*NH + h))*TOPQ + q)*NKC*PSTR;
    float M = -3.402823466e38f;
    #pragma unroll
    for (int i = 0; i < NKC; ++i) M = fmaxf(M, pb[i*PSTR + 64]);
    float L = 0.f, a = 0.f;
    #pragma unroll
    for (int i = 0; i < NKC; ++i){
        float sc = __expf(pb[i*PSTR + 64] - M);
        L += pb[i*PSTR + 65]*sc;
        a += pb[i*PSTR + lane]*sc;
    }
    ctx[((size_t)(b*TOPQ + q))*DIM + h*DHEAD + lane] = a/L;
}

// output projection of the 39 ctx rows (fp32 weights)
__global__ __launch_bounds__(256) void outproj_kernel(const float* __restrict__ ctx,
                                                      const float* __restrict__ ow,
                                                      const float* __restrict__ ob,
                                                      float* __restrict__ sout)
{
    int j = blockIdx.x, b = blockIdx.y, t = threadIdx.x;
    __shared__ float cr[DIM];
    const float* xr = ctx + ((size_t)(b*TOPQ + j))*DIM;
    for (int i = t; i < DIM; i += 256) cr[i] = xr[i];
    __syncthreads();
    for (int d0 = t; d0 < DIM; d0 += 256){
        const float* wr = ow + (size_t)d0*DIM;
        float s = 0.f;
        for (int e = 0; e < DIM; e += 4){
            float4 wv = *(const float4*)(wr + e);
            s += cr[e]*wv.x + cr[e+1]*wv.y + cr[e+2]*wv.z + cr[e+3]*wv.w;
        }
        sout[((size_t)(b*TOPQ + j))*DIM + d0] = s + ob[d0];
    }
}

// residual (+ scatter sparse rows / broadcast xbar) then LN2 -> h (bf16), x2 (f32)
__global__ __launch_bounds__(256) void res_ln2_kernel(const float* __restrict__ x,
                                                      const float* __restrict__ xbar,
                                                      const float* __restrict__ sout,
                                                      const int* __restrict__ selmap,
                                                      const float* __restrict__ g2,
                                                      const float* __restrict__ bt2,
                                                      float* __restrict__ x2,
                                                      bf16* __restrict__ hb)
{
    __shared__ float sbuf[4];
    int row = blockIdx.x;
    int b = row >> 11;
    int t = threadIdx.x;
    int slot = selmap[row];
    const float* ar = (slot >= 0) ? (sout + ((size_t)(b*TOPQ + slot))*DIM)
                                  : (xbar + (size_t)b*DIM);
    size_t base = (size_t)row*DIM;
    float v0 = x[base + t]       + ar[t];
    float v1 = x[base + t + 256] + ar[t + 256];
    x2[base + t] = v0; x2[base + t + 256] = v1;
    float m = block_sum256(v0 + v1, sbuf) * (1.f/DIM);
    float d0 = v0 - m, d1 = v1 - m;
    float var = block_sum256(d0*d0 + d1*d1, sbuf) * (1.f/DIM);
    float r = 1.f/sqrtf(var + 1e-5f);
    hb[base + t]       = __float2bfloat16(d0*r*g2[t]     + bt2[t]);
    hb[base + t + 256] = __float2bfloat16(d1*r*g2[t+256] + bt2[t+256]);
}

// ---------------------------------------------------------------------------
extern "C" void kernel_launch(void* const* d_in, const int* in_sizes, int n_in,
                              void* d_out, int out_size, void* d_ws, size_t ws_size,
                              hipStream_t stream)
{
    (void)in_sizes; (void)n_in; (void)out_size; (void)ws_size;
    const float* x     = (const float*)d_in[0];
    const float* ln1_g = (const float*)d_in[1];
    const float* ln1_b = (const float*)d_in[2];
    const float* in_w  = (const float*)d_in[3];
    const float* in_b  = (const float*)d_in[4];
    const float* out_w = (const float*)d_in[5];
    const float* out_b = (const float*)d_in[6];
    const float* ln2_g = (const float*)d_in[7];
    const float* ln2_b = (const float*)d_in[8];
    const float* w1    = (const float*)d_in[9];
    const float* b1    = (const float*)d_in[10];
    const float* w2    = (const float*)d_in[11];
    const float* b2    = (const float*)d_in[12];
    float* out = (float*)d_out;

    const size_t MB = 1024*1024;
    char* base = (char*)d_ws;
    float* xn_f  = (float*)base;                 // [0,32MiB); reused as x2_f later
    bf16*  xn_b  = (bf16*)(base + 32*MB);        // dead after kv-gemm -> h_b
    bf16*  Khm   = (bf16*)(base + 48*MB);
    bf16*  Vhm   = (bf16*)(base + 64*MB);
    bf16*  h_b   = (bf16*)(base + 32*MB);
    bf16*  h1_b  = (bf16*)(base + 48*MB);        // overwrites Khm/Vhm after attn
    float* x2_f  = xn_f;
    char* p = base + 112*MB;
    bf16*  kvw_b  = (bf16*)p;  p += (size_t)1024*DIM*2;        // in_w rows [512,1536) bf16
    bf16*  w1_b   = (bf16*)p;  p += (size_t)FFD*DIM*2;
    bf16*  w2_b   = (bf16*)p;  p += (size_t)DIM*FFD*2;
    double* xbpart= (double*)p; p += (size_t)BATCH*32*DIM*8;
    double* xbar_d= (double*)p; p += (size_t)BATCH*DIM*8;
    float* xbar_f = (float*)p;  p += (size_t)BATCH*DIM*4;
    double* diag  = (double*)p; p += (size_t)MROWS*8;
    double* spars = (double*)p; p += (size_t)MROWS*8;
    int*   topidx = (int*)p;    p += (size_t)BATCH*64*4;
    int*   selmap = (int*)p;    p += (size_t)MROWS*4;
    bf16*  Qhm    = (bf16*)p;   p += (size_t)BATCH*NH*QPAD*DHEAD*2;   // 384 KiB
    float* ctxb   = (float*)p;  p += (size_t)BATCH*TOPQ*DIM*4;
    float* sout   = (float*)p;  p += (size_t)BATCH*TOPQ*DIM*4;
    float* apart  = (float*)p;  p += (size_t)BATCH*NH*TOPQ*NKC*PSTR*4;  // 10.5 MB

    init_kernel<<<64, 256, 0, stream>>>(selmap);
    cvt_kernel<<<512,  256, 0, stream>>>(in_w + (size_t)DIM*DIM, kvw_b, 1024*DIM);
    cvt_kernel<<<1024, 256, 0, stream>>>(w1, w1_b, FFD*DIM);
    cvt_kernel<<<1024, 256, 0, stream>>>(w2, w2_b, DIM*FFD);
    ln1_kernel<<<MROWS, 256, 0, stream>>>(x, ln1_g, ln1_b, xn_f, xn_b, diag);
    xbar_part_kernel<<<dim3(32, BATCH), 512, 0, stream>>>(xn_f, xbpart);
    xbar_fin_kernel<<<BATCH, 512, 0, stream>>>(xbpart, xbar_d, xbar_f);
    sparsity_kernel<<<MROWS/4, 256, 0, stream>>>(xn_f, xbar_d, diag, spars);
    topk_kernel<<<BATCH, 256, 0, stream>>>(spars, topidx, selmap, out);
    // KV projection (N=1024 -> head-major K/V): grid 8x128 -> 1024 blocks, lgGX=3
    gemm128_kernel<3, bf16><<<1024, 256, 0, stream>>>(
        xn_b, kvw_b, in_b + DIM, Khm, nullptr, Vhm, DIM, 0, 3);
    qproj_kernel<<<dim3(QPAD, BATCH), 256, 0, stream>>>(xn_f, in_w, in_b, topidx, Qhm);
    attn_mfma_kernel<<<dim3(NKC/4, NH, BATCH), 256, 0, stream>>>(Qhm, Khm, Vhm, apart);
    attn_reduce_kernel<<<dim3((TOPQ + 3)/4, NH, BATCH), 256, 0, stream>>>(apart, ctxb);
    outproj_kernel<<<dim3(TOPQ, BATCH), 256, 0, stream>>>(ctxb, out_w, out_b, sout);
    res_ln2_kernel<<<MROWS, 256, 0, stream>>>(x, xbar_f, sout, selmap, ln2_g, ln2_b, x2_f, h_b);
    // FFN1: grid 16x128 -> 2048 blocks, lgGX=4
    gemm128_kernel<1, bf16><<<2048, 256, 0, stream>>>(
        h_b, w1_b, b1, h1_b, nullptr, nullptr, DIM, FFD, 4);
    // FFN2: grid 4x128 -> 512 blocks, lgGX=2
    gemm128_kernel<2, float><<<512, 256, 0, stream>>>(
        h1_b, w2_b, b2, out, x2_f, nullptr, FFD, DIM, 2);
}

// Round 7
// 463.808 us; speedup vs baseline: 1.0762x; 1.0053x over previous
//
#include <hip/hip_runtime.h>
#include <hip/hip_bf16.h>
#include <math.h>

#define BATCH 8
#define SEQ   2048
#define DIM   512
#define NH    8
#define DHEAD 64
#define FFD   2048
#define TOPQ  39            // ceil(5*ln(2048)) with factor=5, min_k=5 (fixed harness inputs)
#define MROWS (BATCH*SEQ)   // 16384
#define KC    64            // keys per attention partial chunk (one wave)
#define NKC   (SEQ/KC)      // 32
#define PSTR  66            // partial stride: 64 ctx + m + l
#define QPAD  48            // TOPQ padded to 3 MFMA row-tiles

typedef __hip_bfloat16 bf16;
typedef __attribute__((ext_vector_type(8))) short short8;
typedef __attribute__((ext_vector_type(4))) short sh4;
typedef __attribute__((ext_vector_type(4))) float floatx4;

__device__ __forceinline__ float bf2f(short u){
    return __uint_as_float(((unsigned int)(unsigned short)u) << 16);
}
// RNE fp32->bf16 bits (matches hardware convert for finite values)
__device__ __forceinline__ unsigned int f2bf_bits(float f){
    unsigned int u = __float_as_uint(f);
    return (u + 0x7fffu + ((u >> 16) & 1u)) >> 16;
}
// fast gelu (tanh form): |err vs exact erf-gelu| < ~3e-3, << bf16 rounding here
__device__ __forceinline__ float gelu_f(float v){
    float u = v*(0.7978845608028654f + 0.0356774081363f*v*v);
    float e = __expf(2.f*u);
    return 0.5f*v*(2.f - 2.f/(e + 1.f));
}
__device__ __forceinline__ float wave_sum(float v){
    #pragma unroll
    for (int off = 32; off > 0; off >>= 1) v += __shfl_down(v, off);
    return v;
}
__device__ __forceinline__ double wave_sum_d(double v){
    #pragma unroll
    for (int off = 32; off > 0; off >>= 1) v += __shfl_down(v, off);
    return v;
}
// block = 256 threads (4 waves)
__device__ __forceinline__ float block_sum256(float v, float* sbuf){
    v = wave_sum(v);
    if ((threadIdx.x & 63) == 0) sbuf[threadIdx.x >> 6] = v;
    __syncthreads();
    float r = sbuf[0] + sbuf[1] + sbuf[2] + sbuf[3];
    __syncthreads();
    return r;
}
__device__ __forceinline__ double block_sum256d(double v, double* sbuf){
    v = wave_sum_d(v);
    if ((threadIdx.x & 63) == 0) sbuf[threadIdx.x >> 6] = v;
    __syncthreads();
    double r = sbuf[0] + sbuf[1] + sbuf[2] + sbuf[3];
    __syncthreads();
    return r;
}

// async global->LDS, 16 B per lane; LDS dest = wave-uniform base + lane*16
__device__ __forceinline__ void load_lds16(const void* g, void* l){
    auto gp = reinterpret_cast<const uint32_t __attribute__((address_space(1)))*>(
        reinterpret_cast<uintptr_t>(g));
    auto lp = reinterpret_cast<uint32_t __attribute__((address_space(3)))*>(
        reinterpret_cast<uintptr_t>(l));
    __builtin_amdgcn_global_load_lds(gp, lp, 16, 0, 0);
}

// 16x16x16 bf16 MFMA (K=16): A/B = 4 bf16/lane (k = (lane>>4)*4 + j), C/D std 16x16 map
__device__ __forceinline__ floatx4 mfma16(sh4 a, sh4 b, floatx4 c){
#if __has_builtin(__builtin_amdgcn_mfma_f32_16x16x16bf16_1k)
    return __builtin_amdgcn_mfma_f32_16x16x16bf16_1k(a, b, c, 0, 0, 0);
#elif __has_builtin(__builtin_amdgcn_mfma_f32_16x16x16_bf16)
    return __builtin_amdgcn_mfma_f32_16x16x16_bf16(a, b, c, 0, 0, 0);
#else
    asm volatile("v_mfma_f32_16x16x16_bf16 %0, %1, %2, %0\n\ts_nop 7\n\ts_nop 7"
                 : "+v"(c) : "v"(a), "v"(b));
    return c;
#endif
}

// transpose-read: 4 bf16 at elem strides {0,16,32,48} from per-lane LDS addr
__device__ __forceinline__ sh4 tr16_read(const short* p){
#if __has_builtin(__builtin_amdgcn_ds_read_tr16_b64_v4i16)
    auto lp = (__attribute__((address_space(3))) sh4*)(uintptr_t)p;
    return __builtin_amdgcn_ds_read_tr16_b64_v4i16(lp);
#elif __has_builtin(__builtin_amdgcn_ds_read_tr16_b64)
    auto lp = (__attribute__((address_space(3))) sh4*)(uintptr_t)p;
    return __builtin_amdgcn_ds_read_tr16_b64(lp);
#else
    sh4 r; r[0] = p[0]; r[1] = p[16]; r[2] = p[32]; r[3] = p[48]; return r;
#endif
}

__device__ __forceinline__ void store_out(bf16* p, float v){ *p = __float2bfloat16(v); }
__device__ __forceinline__ void store_out(float* p, float v){ *p = v; }

// ---------------------------------------------------------------------------
// 128x128-tile GEMM (round-10 proven structure): C = A(MxK)·B(NxK)^T + bias.
// Depth-2 pipeline, counted vmcnt (T4). 3 x 16 KB LDS buffers:
//   prologue: stage(b0); stage(b1)                    // 8 loads in flight
//   loop kt : vmcnt(4) ; s_barrier ; stage(b[kt+2]) ; compute(b[kt])
//   tail    : vmcnt(4)/bar/compute ; vmcnt(0)/bar/compute
// EPI: 1 = gelu->bf16, 2 = +x2 -> fp32 (direct stores), 3 = KV head-major.
// ---------------------------------------------------------------------------
template<int EPI, typename OUT_T>
__global__ __launch_bounds__(256, 3) void gemm128_kernel(const bf16* __restrict__ A,
                                                         const bf16* __restrict__ Bm,
                                                         const float* __restrict__ bias,
                                                         OUT_T* __restrict__ C,
                                                         const float* __restrict__ x2,
                                                         bf16* __restrict__ Vhm,
                                                         int K, int ldc, int lgGX)
{
    __shared__ __align__(16) char smem[49152];   // 3 x (As 8KB | Bs 8KB)
    short* CsBase = (short*)smem;

    const int bid = blockIdx.x;
    const int per = gridDim.x >> 3;
    const int lid = (bid & 7)*per + (bid >> 3);
    const int bx  = lid & ((1 << lgGX) - 1);
    const int by  = lid >> lgGX;

    const int t    = threadIdx.x;
    const int lane = t & 63;
    const int w    = t >> 6;
    const int lf   = lane & 15;
    const int ko   = lane >> 4;
    const int slot = ko ^ ((lf >> 1) & 3);
    const int mrow = (w >> 1)*64, ncol = (w & 1)*64;

    floatx4 acc[4][4];
    floatx4 z = {0.f,0.f,0.f,0.f};
    #pragma unroll
    for (int i = 0; i < 4; ++i)
        #pragma unroll
        for (int j = 0; j < 4; ++j) acc[i][j] = z;

    const int srow = w*16 + (lane >> 2);
    const int sq   = lane & 3;
    const int r0 = srow,      kq0 = sq ^ ((r0 >> 1) & 3);
    const int r1 = 64 + srow, kq1 = sq ^ ((r1 >> 1) & 3);
    const short* ga0 = (const short*)A  + ((size_t)by*128 + r0)*K + kq0*8;
    const short* ga1 = (const short*)A  + ((size_t)by*128 + r1)*K + kq1*8;
    const short* gb0 = (const short*)Bm + ((size_t)bx*128 + r0)*K + kq0*8;
    const short* gb1 = (const short*)Bm + ((size_t)bx*128 + r1)*K + kq1*8;
    char* la0 = smem + w*1024;
    char* la1 = smem + 4096 + w*1024;
    char* lb0 = smem + 8192 + w*1024;
    char* lb1 = smem + 12288 + w*1024;

    auto stage = [&](int off){
        load_lds16(ga0, la0 + off); load_lds16(ga1, la1 + off);
        load_lds16(gb0, lb0 + off); load_lds16(gb1, lb1 + off);
        ga0 += 32; ga1 += 32; gb0 += 32; gb1 += 32;
    };
    auto compute = [&](int off){
        const short* As = (const short*)(smem + off);
        const short* Bs = (const short*)(smem + off + 8192);
        short8 af[4], bfr[4];
        #pragma unroll
        for (int i = 0; i < 4; ++i){
            af[i]  = *(const short8*)(As + (mrow + i*16 + lf)*32 + slot*8);
            bfr[i] = *(const short8*)(Bs + (ncol + i*16 + lf)*32 + slot*8);
        }
        #pragma unroll
        for (int i = 0; i < 4; ++i)
            #pragma unroll
            for (int j = 0; j < 4; ++j)
                acc[i][j] = __builtin_amdgcn_mfma_f32_16x16x32_bf16(af[i], bfr[j], acc[i][j], 0, 0, 0);
    };

    const int T = K >> 5;
    stage(0);
    stage(16384);
    int oc = 0, on = 16384, on2 = 32768;
    for (int kt = 0; kt < T - 2; ++kt){
        asm volatile("s_waitcnt vmcnt(4)" ::: "memory");
        __builtin_amdgcn_s_barrier();
        asm volatile("" ::: "memory");
        stage(on2);
        compute(oc);
        int tmp = oc; oc = on; on = on2; on2 = tmp;
    }
    asm volatile("s_waitcnt vmcnt(4)" ::: "memory");
    __builtin_amdgcn_s_barrier();
    asm volatile("" ::: "memory");
    compute(oc);
    { int tmp = oc; oc = on; on = on2; on2 = tmp; }
    asm volatile("s_waitcnt vmcnt(0)" ::: "memory");
    __builtin_amdgcn_s_barrier();
    asm volatile("" ::: "memory");
    compute(oc);
    __syncthreads();

    if constexpr (EPI == 2){
        const int lr = ko*4;
        #pragma unroll
        for (int j = 0; j < 4; ++j){
            int gcol = bx*128 + ncol + j*16 + lf;
            float bv = bias[gcol];
            #pragma unroll
            for (int i = 0; i < 4; ++i){
                #pragma unroll
                for (int r = 0; r < 4; ++r){
                    size_t grow = (size_t)by*128 + mrow + i*16 + lr + r;
                    float v = acc[i][j][r] + bv + x2[grow*ldc + gcol];
                    store_out(&C[grow*ldc + gcol], v);
                }
            }
        }
    } else {
        short* cs = CsBase + w*(64*72);
        const int odd = lf & 1;
        const int rsel = odd*2;
        #pragma unroll
        for (int j = 0; j < 4; ++j){
            float bv = bias[bx*128 + ncol + j*16 + lf];
            #pragma unroll
            for (int i = 0; i < 4; ++i){
                unsigned long long self = 0;
                #pragma unroll
                for (int r = 0; r < 4; ++r){
                    float v = acc[i][j][r] + bv;
                    if constexpr (EPI == 1) v = gelu_f(v);
                    self |= ((unsigned long long)f2bf_bits(v)) << (16*r);
                }
                unsigned long long nbr = __shfl_xor(self, 1);
                unsigned long long lo = odd ? nbr : self;
                unsigned long long hi = odd ? self : nbr;
                int colb = 16*j + (lf & ~1);
                unsigned int w0 = (unsigned int)((lo >> (16*rsel)) & 0xffffu)
                                | ((unsigned int)((hi >> (16*rsel)) & 0xffffu) << 16);
                unsigned int w1 = (unsigned int)((lo >> (16*(rsel+1))) & 0xffffu)
                                | ((unsigned int)((hi >> (16*(rsel+1))) & 0xffffu) << 16);
                *(unsigned int*)(cs + (16*i + 4*ko + rsel    )*72 + colb) = w0;
                *(unsigned int*)(cs + (16*i + 4*ko + rsel + 1)*72 + colb) = w1;
            }
        }
        const int subrow = lane >> 3, cq = lane & 7;
        #pragma unroll
        for (int rr = 0; rr < 8; ++rr){
            int rl = rr*8 + subrow;
            short8 vv = *(const short8*)(cs + rl*72 + cq*8);
            if constexpr (EPI == 3){
                int grow = by*128 + mrow + rl;
                int b = grow >> 11, s = grow & 2047;
                int gc = bx*128 + ncol + cq*8;
                int h = (gc >> 6) & 7, d = gc & 63;
                bf16* dst = (gc < 512) ? (bf16*)C : Vhm;
                *(short8*)((short*)dst + (((size_t)(b*NH + h))*SEQ + s)*DHEAD + d) = vv;
            } else {
                size_t grow = (size_t)by*128 + mrow + rl;
                int gcol = bx*128 + ncol + cq*8;
                *(short8*)((short*)C + grow*ldc + gcol) = vv;
            }
        }
    }
}

// ---------------------------------------------------------------------------
// Round-14: merged prep — selmap init + 3 fp32->bf16 weight converts in ONE
// launch (was 4 launches). Block ranges: [0,64) init, [64,576) kvw,
// [576,1600) w1, [1600,2624) w2.
// ---------------------------------------------------------------------------
__global__ __launch_bounds__(256) void prep_kernel(const float* __restrict__ in_w,
                                                   const float* __restrict__ w1,
                                                   const float* __restrict__ w2,
                                                   bf16* __restrict__ kvw_b,
                                                   bf16* __restrict__ w1_b,
                                                   bf16* __restrict__ w2_b,
                                                   int* __restrict__ selmap)
{
    int bid = blockIdx.x, t = threadIdx.x;
    if (bid < 64){
        selmap[bid*256 + t] = -1;
        return;
    }
    const float* src; bf16* dst; int i;
    if (bid < 576){      src = in_w + (size_t)DIM*DIM; dst = kvw_b; i = ((bid - 64)*256 + t)*4; }
    else if (bid < 1600){ src = w1;  dst = w1_b; i = ((bid - 576)*256 + t)*4; }
    else {               src = w2;  dst = w2_b; i = ((bid - 1600)*256 + t)*4; }
    float4 v = *(const float4*)(src + i);
    dst[i+0] = __float2bfloat16(v.x);
    dst[i+1] = __float2bfloat16(v.y);
    dst[i+2] = __float2bfloat16(v.z);
    dst[i+3] = __float2bfloat16(v.w);
}

// ---------------------------------------------------------------------------
// LN1 (fp32 in): x -> xn (f32), xnb (bf16), diag[row]=|xn|^2 in fp64 (ranking)
// ---------------------------------------------------------------------------
__global__ __launch_bounds__(256) void ln1_kernel(const float* __restrict__ x,
                                                  const float* __restrict__ g,
                                                  const float* __restrict__ bt,
                                                  float* __restrict__ xn,
                                                  bf16* __restrict__ xnb,
                                                  double* __restrict__ diag)
{
    __shared__ double sbuf[4];
    int row = blockIdx.x;
    int t = threadIdx.x;
    size_t base = (size_t)row*DIM;
    double x0 = (double)x[base + t];
    double x1 = (double)x[base + t + 256];
    double m  = block_sum256d(x0 + x1, sbuf) * (1.0/DIM);
    double d0 = x0 - m, d1 = x1 - m;
    double var = block_sum256d(d0*d0 + d1*d1, sbuf) * (1.0/DIM);
    double r = 1.0/sqrt(var + 1e-5);
    double y0 = d0*r*(double)g[t]     + (double)bt[t];
    double y1 = d1*r*(double)g[t+256] + (double)bt[t+256];
    xn[base+t] = (float)y0;       xn[base+t+256] = (float)y1;
    xnb[base+t] = __float2bfloat16((float)y0);
    xnb[base+t+256] = __float2bfloat16((float)y1);
    double dd = block_sum256d(y0*y0 + y1*y1, sbuf);
    if (t == 0) diag[row] = dd;
}

// column-mean of xn per batch, fp64 two-stage
__global__ __launch_bounds__(512) void xbar_part_kernel(const float* __restrict__ xn, double* __restrict__ part){
    int b = blockIdx.y, c = blockIdx.x, d = threadIdx.x;
    const float* p = xn + ((size_t)b*SEQ + c*64)*DIM + d;
    double s = 0.0;
    for (int i = 0; i < 64; ++i) s += (double)p[(size_t)i*DIM];
    part[((size_t)(b*32 + c))*DIM + d] = s;
}
__global__ __launch_bounds__(512) void xbar_fin_kernel(const double* __restrict__ part,
                                                       double* __restrict__ xbar_d,
                                                       float* __restrict__ xbar_f){
    int b = blockIdx.x, d = threadIdx.x;
    double s = 0.0;
    for (int c = 0; c < 32; ++c) s += part[((size_t)(b*32 + c))*DIM + d];
    s *= (1.0/SEQ);
    xbar_d[(size_t)b*DIM + d] = s;
    xbar_f[(size_t)b*DIM + d] = (float)s;
}

// sparsity*sqrt(D) = diag - dot(xn_row, xbar); fp64 so ranking error << ref fp32 noise
__global__ __launch_bounds__(256) void sparsity_kernel(const float* __restrict__ xn,
                                                       const double* __restrict__ xbar,
                                                       const double* __restrict__ diag,
                                                       double* __restrict__ sp)
{
    int row  = blockIdx.x*4 + (threadIdx.x >> 6);
    int lane = threadIdx.x & 63;
    int b    = row >> 11;
    const float* xr = xn + (size_t)row*DIM;
    const double* xb = xbar + (size_t)b*DIM;
    double s = 0.0;
    for (int e = lane; e < DIM; e += 64) s += (double)xr[e]*xb[e];
    s = wave_sum_d(s);
    if (lane == 0) sp[row] = diag[row] - s;
}

// ---------------------------------------------------------------------------
// register-resident top-39 (round-13, proven): packed monotone u64 order keys,
// 6 shfl_xor wave-max + 4-entry LDS combine per iteration.
// ---------------------------------------------------------------------------
__global__ __launch_bounds__(256) void topk_kernel(const double* __restrict__ sp,
                                                   int* __restrict__ topidx,
                                                   int* __restrict__ selmap,
                                                   float* __restrict__ dout)
{
    __shared__ unsigned long long wmax[4];
    int b = blockIdx.x, t = threadIdx.x;
    int lane = t & 63, w = t >> 6;

    unsigned long long pk[8];
    #pragma unroll
    for (int i = 0; i < 8; ++i){
        int idx = i*256 + t;                          // coalesced
        unsigned long long bits =
            (unsigned long long)__double_as_longlong(sp[(size_t)b*SEQ + idx]);
        unsigned long long m = (bits & 0x8000000000000000ull)
                             ? ~bits : (bits | 0x8000000000000000ull);
        pk[i] = (m & ~2047ull) | (unsigned long long)(2047 - idx);
    }
    unsigned long long lm = pk[0];
    #pragma unroll
    for (int i = 1; i < 8; ++i) lm = (pk[i] > lm) ? pk[i] : lm;

    for (int it = 0; it < TOPQ; ++it){
        unsigned long long m = lm;
        #pragma unroll
        for (int off = 32; off > 0; off >>= 1){
            unsigned long long o = __shfl_xor(m, off);
            m = (o > m) ? o : m;
        }
        if (lane == 0) wmax[w] = m;
        __syncthreads();
        unsigned long long g01 = (wmax[0] > wmax[1]) ? wmax[0] : wmax[1];
        unsigned long long g23 = (wmax[2] > wmax[3]) ? wmax[2] : wmax[3];
        unsigned long long g = (g01 > g23) ? g01 : g23;
        int idx = 2047 - (int)(g & 2047ull);
        if (t == 0){
            topidx[b*64 + it] = idx;
            selmap[(size_t)b*SEQ + idx] = it;
        }
        if ((idx & 255) == t){                        // owner removes + recompute
            int slot = idx >> 8;
            #pragma unroll
            for (int i = 0; i < 8; ++i) if (i == slot) pk[i] = 0;
            lm = pk[0];
            #pragma unroll
            for (int i = 1; i < 8; ++i) lm = (pk[i] > lm) ? pk[i] : lm;
        }
        __syncthreads();                              // wmax reuse safety
    }
    if (b == 0 && t == 0) dout[(size_t)MROWS*DIM] = (float)TOPQ/(float)SEQ;
}

// Q projection for the selected rows -> bf16 head-major Qhm[b][h][48][64]
// (rows TOPQ..47 zero-padded so the MFMA attention can use 3 full 16-row tiles)
__global__ __launch_bounds__(256) void qproj_kernel(const float* __restrict__ xn,
                                                    const float* __restrict__ in_w,
                                                    const float* __restrict__ in_b,
                                                    const int* __restrict__ topidx,
                                                    bf16* __restrict__ Qhm)
{
    int j = blockIdx.x, b = blockIdx.y, t = threadIdx.x;
    __shared__ float qr[DIM];
    if (j >= TOPQ){
        for (int d0 = t; d0 < DIM; d0 += 256){
            int h = d0 >> 6, d = d0 & 63;
            Qhm[((size_t)(b*NH + h)*QPAD + j)*DHEAD + d] = __float2bfloat16(0.f);
        }
        return;
    }
    int srow = topidx[b*64 + j];
    const float* xr = xn + ((size_t)(b*SEQ + srow))*DIM;
    for (int i = t; i < DIM; i += 256) qr[i] = xr[i];
    __syncthreads();
    for (int d0 = t; d0 < DIM; d0 += 256){
        const float* wr = in_w + (size_t)d0*DIM;   // Wq row d0
        float s = 0.f;
        for (int e = 0; e < DIM; e += 4){
            float4 wv = *(const float4*)(wr + e);
            s += qr[e]*wv.x + qr[e+1]*wv.y + qr[e+2]*wv.z + qr[e+3]*wv.w;
        }
        int h = d0 >> 6, d = d0 & 63;
        Qhm[((size_t)(b*NH + h)*QPAD + j)*DHEAD + d] = __float2bfloat16(s + in_b[d0]);
    }
}

// ---------------------------------------------------------------------------
// Round-14: MFMA split-K attention partial, KC 128 -> 64.
// Old: 64 KB LDS -> 1 block/CU = 4 waves/CU (12.5% occ); each wave a serial
// dependent chain (K-loads -> QK MFMA -> softmax -> PV) with ~900cy HBM loads
// covered by only 3 peer waves -> latency-bound.
// New: V-chunk 8 KB/wave, block LDS 32 KB, grid (8,8,8)=512 blocks
// = 2 blocks/CU = 8 waves/CU -> 2x latency overlap; sa halves (4 mt tiles).
// Partial format: NKC=32 chunks of 64 keys, PSTR unchanged.
// ---------------------------------------------------------------------------
__global__ __launch_bounds__(256, 1) void attn_mfma_kernel(const bf16* __restrict__ Qhm,
                                                           const bf16* __restrict__ Khm,
                                                           const bf16* __restrict__ Vhm,
                                                           float* __restrict__ part)
{
    __shared__ __align__(16) short vsm[4*4096];   // 32 KB: 4 waves x (64k x 64d)
    const int bh   = blockIdx.z*NH + blockIdx.y;
    const int w    = threadIdx.x >> 6;
    const int lane = threadIdx.x & 63;
    const int ch   = blockIdx.x*4 + w;           // chunk 0..31
    const int kb   = ch*KC;                      // first key of chunk
    const int lf   = lane & 15;
    const int g    = lane >> 4;

    // ---- stage V chunk into per-wave LDS, subtiled elem = (d>>4)*1024 + k*16 + (d&15)
    short* vbase = vsm + w*4096;
    const short* vg = (const short*)Vhm + ((size_t)bh*SEQ + kb)*DHEAD;
    {
        const int kh = lane >> 1, dh = (lane & 1)*8;
        #pragma unroll
        for (int L = 0; L < 8; ++L){
            int k = (L & 1)*32 + kh;
            int d = (L >> 1)*16 + dh;
            load_lds16(vg + (size_t)k*DHEAD + d, vbase + L*512);
        }
    }

    // ---- Q B-fragments (col = q = lf, k-octet = g), direct from global
    short8 qf[3][2];
    const short* qp = (const short*)Qhm + (size_t)bh*QPAD*DHEAD;
    #pragma unroll
    for (int nt = 0; nt < 3; ++nt)
        #pragma unroll
        for (int s = 0; s < 2; ++s)
            qf[nt][s] = *(const short8*)(qp + (nt*16 + lf)*DHEAD + s*32 + g*8);

    // ---- S^T = K·Q^T : M = 64 keys (4 tiles), N = 48 q (3 tiles), K = 64 (2 steps)
    floatx4 sa[4][3];
    floatx4 z = {0.f,0.f,0.f,0.f};
    #pragma unroll
    for (int mt = 0; mt < 4; ++mt)
        #pragma unroll
        for (int nt = 0; nt < 3; ++nt) sa[mt][nt] = z;

    const short* kp = (const short*)Khm + ((size_t)bh*SEQ + kb)*DHEAD;
    #pragma unroll
    for (int mt = 0; mt < 4; ++mt){
        const short* kr = kp + (size_t)(mt*16 + lf)*DHEAD + g*8;
        short8 kf0 = *(const short8*)(kr);
        short8 kf1 = *(const short8*)(kr + 32);
        #pragma unroll
        for (int nt = 0; nt < 3; ++nt){
            sa[mt][nt] = __builtin_amdgcn_mfma_f32_16x16x32_bf16(kf0, qf[nt][0], sa[mt][nt], 0, 0, 0);
            sa[mt][nt] = __builtin_amdgcn_mfma_f32_16x16x32_bf16(kf1, qf[nt][1], sa[mt][nt], 0, 0, 0);
        }
    }

    // ---- in-register partial softmax per q (raw-score max; scale folded into exp)
    float mx[3], ls[3];
    #pragma unroll
    for (int nt = 0; nt < 3; ++nt){
        float m = sa[0][nt][0];
        #pragma unroll
        for (int mt = 0; mt < 4; ++mt)
            #pragma unroll
            for (int r = 0; r < 4; ++r) m = fmaxf(m, sa[mt][nt][r]);
        m = fmaxf(m, __shfl_xor(m, 16));
        m = fmaxf(m, __shfl_xor(m, 32));
        float l = 0.f;
        #pragma unroll
        for (int mt = 0; mt < 4; ++mt){
            #pragma unroll
            for (int r = 0; r < 4; ++r){
                float p = __expf((sa[mt][nt][r] - m)*0.125f);   // 1/sqrt(64)
                sa[mt][nt][r] = p;
                l += p;
            }
        }
        l += __shfl_xor(l, 16);
        l += __shfl_xor(l, 32);
        mx[nt] = m; ls[nt] = l;
    }

    // ---- PV: ctx = P(48x64)·V(64x64), mfma 16x16x16, K-steps t = 0..3
    asm volatile("s_waitcnt vmcnt(0)" ::: "memory");   // V staging landed
    floatx4 oacc[3][4];
    #pragma unroll
    for (int mi = 0; mi < 3; ++mi)
        #pragma unroll
        for (int dt = 0; dt < 4; ++dt) oacc[mi][dt] = z;

    #pragma unroll
    for (int t = 0; t < 4; ++t){
        sh4 pa[3];
        #pragma unroll
        for (int mi = 0; mi < 3; ++mi){
            union { sh4 v; unsigned u[2]; } pk;
            pk.u[0] = f2bf_bits(sa[t][mi][0]) | (f2bf_bits(sa[t][mi][1]) << 16);
            pk.u[1] = f2bf_bits(sa[t][mi][2]) | (f2bf_bits(sa[t][mi][3]) << 16);
            pa[mi] = pk.v;
        }
        #pragma unroll
        for (int dt = 0; dt < 4; ++dt){
            sh4 vf = tr16_read(vbase + dt*1024 + (t*16 + 4*g)*16 + lf);
            #pragma unroll
            for (int mi = 0; mi < 3; ++mi)
                oacc[mi][dt] = mfma16(pa[mi], vf, oacc[mi][dt]);
        }
    }

    // ---- store partial: ctx rows (q = mi*16 + 4g + r, d = dt*16 + lf), plus m,l
    float* pbase = part + ((size_t)bh*TOPQ*NKC + ch)*PSTR;
    #pragma unroll
    for (int mi = 0; mi < 3; ++mi){
        #pragma unroll
        for (int r = 0; r < 4; ++r){
            int q = mi*16 + 4*g + r;
            if (q < TOPQ){
                float* pp = pbase + (size_t)q*NKC*PSTR;
                #pragma unroll
                for (int dt = 0; dt < 4; ++dt)
                    pp[dt*16 + lf] = oacc[mi][dt][r];
            }
        }
    }
    #pragma unroll
    for (int nt = 0; nt < 3; ++nt){
        int q = nt*16 + lf;
        if (g == 3 && q < TOPQ){
            float* pp = pbase + (size_t)q*NKC*PSTR;
            pp[64] = mx[nt]*0.125f;
            pp[65] = ls[nt];
        }
    }
}

// pass 2: merge 32 partials per (b,h,q); wave per q (4 q per block)
__global__ __launch_bounds__(256) void attn_reduce_kernel(const float* __restrict__ part,
                                                          float* __restrict__ ctx)
{
    int qc = blockIdx.x, h = blockIdx.y, b = blockIdx.z;
    int w = threadIdx.x >> 6, lane = threadIdx.x & 63;
    int q = qc*4 + w;
    if (q >= TOPQ) return;
    const float* pb = part + (((size_t)(b*NH + h))*TOPQ + q)*NKC*PSTR;
    float M = -3.402823466e38f;
    #pragma unroll
    for (int i = 0; i < NKC; ++i) M = fmaxf(M, pb[i*PSTR + 64]);
    float L = 0.f, a = 0.f;
    #pragma unroll
    for (int i = 0; i < NKC; ++i){
        float sc = __expf(pb[i*PSTR + 64] - M);
        L += pb[i*PSTR + 65]*sc;
        a += pb[i*PSTR + lane]*sc;
    }
    ctx[((size_t)(b*TOPQ + q))*DIM + h*DHEAD + lane] = a/L;
}

// output projection of the 39 ctx rows (fp32 weights)
__global__ __launch_bounds__(256) void outproj_kernel(const float* __restrict__ ctx,
                                                      const float* __restrict__ ow,
                                                      const float* __restrict__ ob,
                                                      float* __restrict__ sout)
{
    int j = blockIdx.x, b = blockIdx.y, t = threadIdx.x;
    __shared__ float cr[DIM];
    const float* xr = ctx + ((size_t)(b*TOPQ + j))*DIM;
    for (int i = t; i < DIM; i += 256) cr[i] = xr[i];
    __syncthreads();
    for (int d0 = t; d0 < DIM; d0 += 256){
        const float* wr = ow + (size_t)d0*DIM;
        float s = 0.f;
        for (int e = 0; e < DIM; e += 4){
            float4 wv = *(const float4*)(wr + e);
            s += cr[e]*wv.x + cr[e+1]*wv.y + cr[e+2]*wv.z + cr[e+3]*wv.w;
        }
        sout[((size_t)(b*TOPQ + j))*DIM + d0] = s + ob[d0];
    }
}

// residual (+ scatter sparse rows / broadcast xbar) then LN2 -> h (bf16), x2 (f32)
__global__ __launch_bounds__(256) void res_ln2_kernel(const float* __restrict__ x,
                                                      const float* __restrict__ xbar,
                                                      const float* __restrict__ sout,
                                                      const int* __restrict__ selmap,
                                                      const float* __restrict__ g2,
                                                      const float* __restrict__ bt2,
                                                      float* __restrict__ x2,
                                                      bf16* __restrict__ hb)
{
    __shared__ float sbuf[4];
    int row = blockIdx.x;
    int b = row >> 11;
    int t = threadIdx.x;
    int slot = selmap[row];
    const float* ar = (slot >= 0) ? (sout + ((size_t)(b*TOPQ + slot))*DIM)
                                  : (xbar + (size_t)b*DIM);
    size_t base = (size_t)row*DIM;
    float v0 = x[base + t]       + ar[t];
    float v1 = x[base + t + 256] + ar[t + 256];
    x2[base + t] = v0; x2[base + t + 256] = v1;
    float m = block_sum256(v0 + v1, sbuf) * (1.f/DIM);
    float d0 = v0 - m, d1 = v1 - m;
    float var = block_sum256(d0*d0 + d1*d1, sbuf) * (1.f/DIM);
    float r = 1.f/sqrtf(var + 1e-5f);
    hb[base + t]       = __float2bfloat16(d0*r*g2[t]     + bt2[t]);
    hb[base + t + 256] = __float2bfloat16(d1*r*g2[t+256] + bt2[t+256]);
}

// ---------------------------------------------------------------------------
extern "C" void kernel_launch(void* const* d_in, const int* in_sizes, int n_in,
                              void* d_out, int out_size, void* d_ws, size_t ws_size,
                              hipStream_t stream)
{
    (void)in_sizes; (void)n_in; (void)out_size; (void)ws_size;
    const float* x     = (const float*)d_in[0];
    const float* ln1_g = (const float*)d_in[1];
    const float* ln1_b = (const float*)d_in[2];
    const float* in_w  = (const float*)d_in[3];
    const float* in_b  = (const float*)d_in[4];
    const float* out_w = (const float*)d_in[5];
    const float* out_b = (const float*)d_in[6];
    const float* ln2_g = (const float*)d_in[7];
    const float* ln2_b = (const float*)d_in[8];
    const float* w1    = (const float*)d_in[9];
    const float* b1    = (const float*)d_in[10];
    const float* w2    = (const float*)d_in[11];
    const float* b2    = (const float*)d_in[12];
    float* out = (float*)d_out;

    const size_t MB = 1024*1024;
    char* base = (char*)d_ws;
    float* xn_f  = (float*)base;                 // [0,32MiB); reused as x2_f later
    bf16*  xn_b  = (bf16*)(base + 32*MB);        // dead after kv-gemm -> h_b
    bf16*  Khm   = (bf16*)(base + 48*MB);
    bf16*  Vhm   = (bf16*)(base + 64*MB);
    bf16*  h_b   = (bf16*)(base + 32*MB);
    bf16*  h1_b  = (bf16*)(base + 48*MB);        // overwrites Khm/Vhm after attn
    float* x2_f  = xn_f;
    // apart (21 MiB) lives at [80,101) MiB: free during attention (h1_b rows
    // covering it are written only by FFN1, after attn_reduce consumed apart).
    float* apart = (float*)(base + 80*MB);
    char* p = base + 112*MB;
    bf16*  kvw_b  = (bf16*)p;  p += (size_t)1024*DIM*2;        // in_w rows [512,1536) bf16
    bf16*  w1_b   = (bf16*)p;  p += (size_t)FFD*DIM*2;
    bf16*  w2_b   = (bf16*)p;  p += (size_t)DIM*FFD*2;
    double* xbpart= (double*)p; p += (size_t)BATCH*32*DIM*8;
    double* xbar_d= (double*)p; p += (size_t)BATCH*DIM*8;
    float* xbar_f = (float*)p;  p += (size_t)BATCH*DIM*4;
    double* diag  = (double*)p; p += (size_t)MROWS*8;
    double* spars = (double*)p; p += (size_t)MROWS*8;
    int*   topidx = (int*)p;    p += (size_t)BATCH*64*4;
    int*   selmap = (int*)p;    p += (size_t)MROWS*4;
    bf16*  Qhm    = (bf16*)p;   p += (size_t)BATCH*NH*QPAD*DHEAD*2;   // 384 KiB
    float* ctxb   = (float*)p;  p += (size_t)BATCH*TOPQ*DIM*4;
    float* sout   = (float*)p;  p += (size_t)BATCH*TOPQ*DIM*4;

    prep_kernel<<<2624, 256, 0, stream>>>(in_w, w1, w2, kvw_b, w1_b, w2_b, selmap);
    ln1_kernel<<<MROWS, 256, 0, stream>>>(x, ln1_g, ln1_b, xn_f, xn_b, diag);
    xbar_part_kernel<<<dim3(32, BATCH), 512, 0, stream>>>(xn_f, xbpart);
    xbar_fin_kernel<<<BATCH, 512, 0, stream>>>(xbpart, xbar_d, xbar_f);
    sparsity_kernel<<<MROWS/4, 256, 0, stream>>>(xn_f, xbar_d, diag, spars);
    topk_kernel<<<BATCH, 256, 0, stream>>>(spars, topidx, selmap, out);
    // KV projection (N=1024 -> head-major K/V): grid 8x128 -> 1024 blocks, lgGX=3
    gemm128_kernel<3, bf16><<<1024, 256, 0, stream>>>(
        xn_b, kvw_b, in_b + DIM, Khm, nullptr, Vhm, DIM, 0, 3);
    qproj_kernel<<<dim3(QPAD, BATCH), 256, 0, stream>>>(xn_f, in_w, in_b, topidx, Qhm);
    attn_mfma_kernel<<<dim3(NKC/4, NH, BATCH), 256, 0, stream>>>(Qhm, Khm, Vhm, apart);
    attn_reduce_kernel<<<dim3((TOPQ + 3)/4, NH, BATCH), 256, 0, stream>>>(apart, ctxb);
    outproj_kernel<<<dim3(TOPQ, BATCH), 256, 0, stream>>>(ctxb, out_w, out_b, sout);
    res_ln2_kernel<<<MROWS, 256, 0, stream>>>(x, xbar_f, sout, selmap, ln2_g, ln2_b, x2_f, h_b);
    // FFN1: grid 16x128 -> 2048 blocks, lgGX=4
    gemm128_kernel<1, bf16><<<2048, 256, 0, stream>>>(
        h_b, w1_b, b1, h1_b, nullptr, nullptr, DIM, FFD, 4);
    // FFN2: grid 4x128 -> 512 blocks, lgGX=2
    gemm128_kernel<2, float><<<512, 256, 0, stream>>>(
        h1_b, w2_b, b2, out, x2_f, nullptr, FFD, DIM, 2);
}

// Round 8
// 451.859 us; speedup vs baseline: 1.1047x; 1.0264x over previous
//
#include <hip/hip_runtime.h>
#include <hip/hip_bf16.h>
#include <math.h>

#define BATCH 8
#define SEQ   2048
#define DIM   512
#define NH    8
#define DHEAD 64
#define FFD   2048
#define TOPQ  39            // ceil(5*ln(2048)) with factor=5, min_k=5 (fixed harness inputs)
#define MROWS (BATCH*SEQ)   // 16384
#define KC    64            // keys per attention partial chunk (one wave)
#define NKC   (SEQ/KC)      // 32
#define PSTR  66            // partial stride: 64 ctx + m + l
#define QPAD  48            // TOPQ padded to 3 MFMA row-tiles

typedef __hip_bfloat16 bf16;
typedef __attribute__((ext_vector_type(8))) short short8;
typedef __attribute__((ext_vector_type(4))) short sh4;
typedef __attribute__((ext_vector_type(4))) float floatx4;

__device__ __forceinline__ float bf2f(short u){
    return __uint_as_float(((unsigned int)(unsigned short)u) << 16);
}
// RNE fp32->bf16 bits (matches hardware convert for finite values)
__device__ __forceinline__ unsigned int f2bf_bits(float f){
    unsigned int u = __float_as_uint(f);
    return (u + 0x7fffu + ((u >> 16) & 1u)) >> 16;
}
// fast gelu (tanh form): |err vs exact erf-gelu| < ~3e-3, << bf16 rounding here
__device__ __forceinline__ float gelu_f(float v){
    float u = v*(0.7978845608028654f + 0.0356774081363f*v*v);
    float e = __expf(2.f*u);
    return 0.5f*v*(2.f - 2.f/(e + 1.f));
}
__device__ __forceinline__ float wave_sum(float v){
    #pragma unroll
    for (int off = 32; off > 0; off >>= 1) v += __shfl_down(v, off);
    return v;
}
__device__ __forceinline__ double wave_sum_d(double v){
    #pragma unroll
    for (int off = 32; off > 0; off >>= 1) v += __shfl_down(v, off);
    return v;
}

// async global->LDS, 16 B per lane; LDS dest = wave-uniform base + lane*16
__device__ __forceinline__ void load_lds16(const void* g, void* l){
    auto gp = reinterpret_cast<const uint32_t __attribute__((address_space(1)))*>(
        reinterpret_cast<uintptr_t>(g));
    auto lp = reinterpret_cast<uint32_t __attribute__((address_space(3)))*>(
        reinterpret_cast<uintptr_t>(l));
    __builtin_amdgcn_global_load_lds(gp, lp, 16, 0, 0);
}

// 16x16x16 bf16 MFMA (K=16): A/B = 4 bf16/lane (k = (lane>>4)*4 + j), C/D std 16x16 map
__device__ __forceinline__ floatx4 mfma16(sh4 a, sh4 b, floatx4 c){
#if __has_builtin(__builtin_amdgcn_mfma_f32_16x16x16bf16_1k)
    return __builtin_amdgcn_mfma_f32_16x16x16bf16_1k(a, b, c, 0, 0, 0);
#elif __has_builtin(__builtin_amdgcn_mfma_f32_16x16x16_bf16)
    return __builtin_amdgcn_mfma_f32_16x16x16_bf16(a, b, c, 0, 0, 0);
#else
    asm volatile("v_mfma_f32_16x16x16_bf16 %0, %1, %2, %0\n\ts_nop 7\n\ts_nop 7"
                 : "+v"(c) : "v"(a), "v"(b));
    return c;
#endif
}

// transpose-read: 4 bf16 at elem strides {0,16,32,48} from per-lane LDS addr
__device__ __forceinline__ sh4 tr16_read(const short* p){
#if __has_builtin(__builtin_amdgcn_ds_read_tr16_b64_v4i16)
    auto lp = (__attribute__((address_space(3))) sh4*)(uintptr_t)p;
    return __builtin_amdgcn_ds_read_tr16_b64_v4i16(lp);
#elif __has_builtin(__builtin_amdgcn_ds_read_tr16_b64)
    auto lp = (__attribute__((address_space(3))) sh4*)(uintptr_t)p;
    return __builtin_amdgcn_ds_read_tr16_b64(lp);
#else
    sh4 r; r[0] = p[0]; r[1] = p[16]; r[2] = p[32]; r[3] = p[48]; return r;
#endif
}

__device__ __forceinline__ void store_out(bf16* p, float v){ *p = __float2bfloat16(v); }
__device__ __forceinline__ void store_out(float* p, float v){ *p = v; }

// ---------------------------------------------------------------------------
// 128x128-tile GEMM (round-10 proven structure): C = A(MxK)·B(NxK)^T + bias.
// Depth-2 pipeline, counted vmcnt (T4). 3 x 16 KB LDS buffers:
//   prologue: stage(b0); stage(b1)                    // 8 loads in flight
//   loop kt : vmcnt(4) ; s_barrier ; stage(b[kt+2]) ; compute(b[kt])
//   tail    : vmcnt(4)/bar/compute ; vmcnt(0)/bar/compute
// EPI: 1 = gelu->bf16, 2 = +x2 -> fp32 (direct stores), 3 = KV head-major.
// ---------------------------------------------------------------------------
template<int EPI, typename OUT_T>
__global__ __launch_bounds__(256, 3) void gemm128_kernel(const bf16* __restrict__ A,
                                                         const bf16* __restrict__ Bm,
                                                         const float* __restrict__ bias,
                                                         OUT_T* __restrict__ C,
                                                         const float* __restrict__ x2,
                                                         bf16* __restrict__ Vhm,
                                                         int K, int ldc, int lgGX)
{
    __shared__ __align__(16) char smem[49152];   // 3 x (As 8KB | Bs 8KB)
    short* CsBase = (short*)smem;

    const int bid = blockIdx.x;
    const int per = gridDim.x >> 3;
    const int lid = (bid & 7)*per + (bid >> 3);
    const int bx  = lid & ((1 << lgGX) - 1);
    const int by  = lid >> lgGX;

    const int t    = threadIdx.x;
    const int lane = t & 63;
    const int w    = t >> 6;
    const int lf   = lane & 15;
    const int ko   = lane >> 4;
    const int slot = ko ^ ((lf >> 1) & 3);
    const int mrow = (w >> 1)*64, ncol = (w & 1)*64;

    floatx4 acc[4][4];
    floatx4 z = {0.f,0.f,0.f,0.f};
    #pragma unroll
    for (int i = 0; i < 4; ++i)
        #pragma unroll
        for (int j = 0; j < 4; ++j) acc[i][j] = z;

    const int srow = w*16 + (lane >> 2);
    const int sq   = lane & 3;
    const int r0 = srow,      kq0 = sq ^ ((r0 >> 1) & 3);
    const int r1 = 64 + srow, kq1 = sq ^ ((r1 >> 1) & 3);
    const short* ga0 = (const short*)A  + ((size_t)by*128 + r0)*K + kq0*8;
    const short* ga1 = (const short*)A  + ((size_t)by*128 + r1)*K + kq1*8;
    const short* gb0 = (const short*)Bm + ((size_t)bx*128 + r0)*K + kq0*8;
    const short* gb1 = (const short*)Bm + ((size_t)bx*128 + r1)*K + kq1*8;
    char* la0 = smem + w*1024;
    char* la1 = smem + 4096 + w*1024;
    char* lb0 = smem + 8192 + w*1024;
    char* lb1 = smem + 12288 + w*1024;

    auto stage = [&](int off){
        load_lds16(ga0, la0 + off); load_lds16(ga1, la1 + off);
        load_lds16(gb0, lb0 + off); load_lds16(gb1, lb1 + off);
        ga0 += 32; ga1 += 32; gb0 += 32; gb1 += 32;
    };
    auto compute = [&](int off){
        const short* As = (const short*)(smem + off);
        const short* Bs = (const short*)(smem + off + 8192);
        short8 af[4], bfr[4];
        #pragma unroll
        for (int i = 0; i < 4; ++i){
            af[i]  = *(const short8*)(As + (mrow + i*16 + lf)*32 + slot*8);
            bfr[i] = *(const short8*)(Bs + (ncol + i*16 + lf)*32 + slot*8);
        }
        #pragma unroll
        for (int i = 0; i < 4; ++i)
            #pragma unroll
            for (int j = 0; j < 4; ++j)
                acc[i][j] = __builtin_amdgcn_mfma_f32_16x16x32_bf16(af[i], bfr[j], acc[i][j], 0, 0, 0);
    };

    const int T = K >> 5;
    stage(0);
    stage(16384);
    int oc = 0, on = 16384, on2 = 32768;
    for (int kt = 0; kt < T - 2; ++kt){
        asm volatile("s_waitcnt vmcnt(4)" ::: "memory");
        __builtin_amdgcn_s_barrier();
        asm volatile("" ::: "memory");
        stage(on2);
        compute(oc);
        int tmp = oc; oc = on; on = on2; on2 = tmp;
    }
    asm volatile("s_waitcnt vmcnt(4)" ::: "memory");
    __builtin_amdgcn_s_barrier();
    asm volatile("" ::: "memory");
    compute(oc);
    { int tmp = oc; oc = on; on = on2; on2 = tmp; }
    asm volatile("s_waitcnt vmcnt(0)" ::: "memory");
    __builtin_amdgcn_s_barrier();
    asm volatile("" ::: "memory");
    compute(oc);
    __syncthreads();

    if constexpr (EPI == 2){
        const int lr = ko*4;
        #pragma unroll
        for (int j = 0; j < 4; ++j){
            int gcol = bx*128 + ncol + j*16 + lf;
            float bv = bias[gcol];
            #pragma unroll
            for (int i = 0; i < 4; ++i){
                #pragma unroll
                for (int r = 0; r < 4; ++r){
                    size_t grow = (size_t)by*128 + mrow + i*16 + lr + r;
                    float v = acc[i][j][r] + bv + x2[grow*ldc + gcol];
                    store_out(&C[grow*ldc + gcol], v);
                }
            }
        }
    } else {
        short* cs = CsBase + w*(64*72);
        const int odd = lf & 1;
        const int rsel = odd*2;
        #pragma unroll
        for (int j = 0; j < 4; ++j){
            float bv = bias[bx*128 + ncol + j*16 + lf];
            #pragma unroll
            for (int i = 0; i < 4; ++i){
                unsigned long long self = 0;
                #pragma unroll
                for (int r = 0; r < 4; ++r){
                    float v = acc[i][j][r] + bv;
                    if constexpr (EPI == 1) v = gelu_f(v);
                    self |= ((unsigned long long)f2bf_bits(v)) << (16*r);
                }
                unsigned long long nbr = __shfl_xor(self, 1);
                unsigned long long lo = odd ? nbr : self;
                unsigned long long hi = odd ? self : nbr;
                int colb = 16*j + (lf & ~1);
                unsigned int w0 = (unsigned int)((lo >> (16*rsel)) & 0xffffu)
                                | ((unsigned int)((hi >> (16*rsel)) & 0xffffu) << 16);
                unsigned int w1 = (unsigned int)((lo >> (16*(rsel+1))) & 0xffffu)
                                | ((unsigned int)((hi >> (16*(rsel+1))) & 0xffffu) << 16);
                *(unsigned int*)(cs + (16*i + 4*ko + rsel    )*72 + colb) = w0;
                *(unsigned int*)(cs + (16*i + 4*ko + rsel + 1)*72 + colb) = w1;
            }
        }
        const int subrow = lane >> 3, cq = lane & 7;
        #pragma unroll
        for (int rr = 0; rr < 8; ++rr){
            int rl = rr*8 + subrow;
            short8 vv = *(const short8*)(cs + rl*72 + cq*8);
            if constexpr (EPI == 3){
                int grow = by*128 + mrow + rl;
                int b = grow >> 11, s = grow & 2047;
                int gc = bx*128 + ncol + cq*8;
                int h = (gc >> 6) & 7, d = gc & 63;
                bf16* dst = (gc < 512) ? (bf16*)C : Vhm;
                *(short8*)((short*)dst + (((size_t)(b*NH + h))*SEQ + s)*DHEAD + d) = vv;
            } else {
                size_t grow = (size_t)by*128 + mrow + rl;
                int gcol = bx*128 + ncol + cq*8;
                *(short8*)((short*)C + grow*ldc + gcol) = vv;
            }
        }
    }
}

// ---------------------------------------------------------------------------
// merged prep — selmap init + 3 fp32->bf16 weight converts in ONE launch.
// Block ranges: [0,64) init, [64,576) kvw, [576,1600) w1, [1600,2624) w2.
// ---------------------------------------------------------------------------
__global__ __launch_bounds__(256) void prep_kernel(const float* __restrict__ in_w,
                                                   const float* __restrict__ w1,
                                                   const float* __restrict__ w2,
                                                   bf16* __restrict__ kvw_b,
                                                   bf16* __restrict__ w1_b,
                                                   bf16* __restrict__ w2_b,
                                                   int* __restrict__ selmap)
{
    int bid = blockIdx.x, t = threadIdx.x;
    if (bid < 64){
        selmap[bid*256 + t] = -1;
        return;
    }
    const float* src; bf16* dst; int i;
    if (bid < 576){      src = in_w + (size_t)DIM*DIM; dst = kvw_b; i = ((bid - 64)*256 + t)*4; }
    else if (bid < 1600){ src = w1;  dst = w1_b; i = ((bid - 576)*256 + t)*4; }
    else {               src = w2;  dst = w2_b; i = ((bid - 1600)*256 + t)*4; }
    float4 v = *(const float4*)(src + i);
    dst[i+0] = __float2bfloat16(v.x);
    dst[i+1] = __float2bfloat16(v.y);
    dst[i+2] = __float2bfloat16(v.z);
    dst[i+3] = __float2bfloat16(v.w);
}

// ---------------------------------------------------------------------------
// Round-15 LN1: ONE-PASS paired fp64 reduction (Σx, Σx²) -> var = E[x²]-m².
// Old: 3 sequential block-reductions (6 barriers); new: 1 barrier total.
// diag (Σxn²) moved into sparsity_kernel (which streams the row anyway).
// ---------------------------------------------------------------------------
__global__ __launch_bounds__(256) void ln1_kernel(const float* __restrict__ x,
                                                  const float* __restrict__ g,
                                                  const float* __restrict__ bt,
                                                  float* __restrict__ xn,
                                                  bf16* __restrict__ xnb)
{
    __shared__ double sbuf[8];
    int row = blockIdx.x;
    int t = threadIdx.x;
    size_t base = (size_t)row*DIM;
    double x0 = (double)x[base + t];
    double x1 = (double)x[base + t + 256];
    double a = x0 + x1, q = x0*x0 + x1*x1;
    #pragma unroll
    for (int off = 32; off > 0; off >>= 1){
        a += __shfl_down(a, off);
        q += __shfl_down(q, off);
    }
    if ((t & 63) == 0){ sbuf[t >> 6] = a; sbuf[4 + (t >> 6)] = q; }
    __syncthreads();
    double sx  = sbuf[0] + sbuf[1] + sbuf[2] + sbuf[3];
    double sxx = sbuf[4] + sbuf[5] + sbuf[6] + sbuf[7];
    double m   = sx*(1.0/DIM);
    double var = sxx*(1.0/DIM) - m*m;
    double r = 1.0/sqrt(var + 1e-5);
    double y0 = (x0 - m)*r*(double)g[t]     + (double)bt[t];
    double y1 = (x1 - m)*r*(double)g[t+256] + (double)bt[t+256];
    xn[base+t] = (float)y0;       xn[base+t+256] = (float)y1;
    xnb[base+t] = __float2bfloat16((float)y0);
    xnb[base+t+256] = __float2bfloat16((float)y1);
}

// column-mean of xn per batch, fp64 two-stage
__global__ __launch_bounds__(512) void xbar_part_kernel(const float* __restrict__ xn, double* __restrict__ part){
    int b = blockIdx.y, c = blockIdx.x, d = threadIdx.x;
    const float* p = xn + ((size_t)b*SEQ + c*64)*DIM + d;
    double s = 0.0;
    for (int i = 0; i < 64; ++i) s += (double)p[(size_t)i*DIM];
    part[((size_t)(b*32 + c))*DIM + d] = s;
}
__global__ __launch_bounds__(512) void xbar_fin_kernel(const double* __restrict__ part,
                                                       double* __restrict__ xbar_d,
                                                       float* __restrict__ xbar_f){
    int b = blockIdx.x, d = threadIdx.x;
    double s = 0.0;
    for (int c = 0; c < 32; ++c) s += part[((size_t)(b*32 + c))*DIM + d];
    s *= (1.0/SEQ);
    xbar_d[(size_t)b*DIM + d] = s;
    xbar_f[(size_t)b*DIM + d] = (float)s;
}

// sparsity*sqrt(D) = Σxn² - dot(xn_row, xbar); fp64 over the SAME fp32 xn
// values ref uses -> ranking margin >> ref's own fp32 noise. (diag folded in.)
__global__ __launch_bounds__(256) void sparsity_kernel(const float* __restrict__ xn,
                                                       const double* __restrict__ xbar,
                                                       double* __restrict__ sp)
{
    int row  = blockIdx.x*4 + (threadIdx.x >> 6);
    int lane = threadIdx.x & 63;
    int b    = row >> 11;
    const float* xr = xn + (size_t)row*DIM;
    const double* xb = xbar + (size_t)b*DIM;
    double s = 0.0, d2 = 0.0;
    for (int e = lane; e < DIM; e += 64){
        double xv = (double)xr[e];
        s  += xv*xb[e];
        d2 += xv*xv;
    }
    #pragma unroll
    for (int off = 32; off > 0; off >>= 1){
        s  += __shfl_down(s, off);
        d2 += __shfl_down(d2, off);
    }
    if (lane == 0) sp[row] = d2 - s;
}

// ---------------------------------------------------------------------------
// register-resident top-39 (round-13, proven): packed monotone u64 order keys,
// 6 shfl_xor wave-max + 4-entry LDS combine per iteration.
// ---------------------------------------------------------------------------
__global__ __launch_bounds__(256) void topk_kernel(const double* __restrict__ sp,
                                                   int* __restrict__ topidx,
                                                   int* __restrict__ selmap,
                                                   float* __restrict__ dout)
{
    __shared__ unsigned long long wmax[4];
    int b = blockIdx.x, t = threadIdx.x;
    int lane = t & 63, w = t >> 6;

    unsigned long long pk[8];
    #pragma unroll
    for (int i = 0; i < 8; ++i){
        int idx = i*256 + t;                          // coalesced
        unsigned long long bits =
            (unsigned long long)__double_as_longlong(sp[(size_t)b*SEQ + idx]);
        unsigned long long m = (bits & 0x8000000000000000ull)
                             ? ~bits : (bits | 0x8000000000000000ull);
        pk[i] = (m & ~2047ull) | (unsigned long long)(2047 - idx);
    }
    unsigned long long lm = pk[0];
    #pragma unroll
    for (int i = 1; i < 8; ++i) lm = (pk[i] > lm) ? pk[i] : lm;

    for (int it = 0; it < TOPQ; ++it){
        unsigned long long m = lm;
        #pragma unroll
        for (int off = 32; off > 0; off >>= 1){
            unsigned long long o = __shfl_xor(m, off);
            m = (o > m) ? o : m;
        }
        if (lane == 0) wmax[w] = m;
        __syncthreads();
        unsigned long long g01 = (wmax[0] > wmax[1]) ? wmax[0] : wmax[1];
        unsigned long long g23 = (wmax[2] > wmax[3]) ? wmax[2] : wmax[3];
        unsigned long long g = (g01 > g23) ? g01 : g23;
        int idx = 2047 - (int)(g & 2047ull);
        if (t == 0){
            topidx[b*64 + it] = idx;
            selmap[(size_t)b*SEQ + idx] = it;
        }
        if ((idx & 255) == t){                        // owner removes + recompute
            int slot = idx >> 8;
            #pragma unroll
            for (int i = 0; i < 8; ++i) if (i == slot) pk[i] = 0;
            lm = pk[0];
            #pragma unroll
            for (int i = 1; i < 8; ++i) lm = (pk[i] > lm) ? pk[i] : lm;
        }
        __syncthreads();                              // wmax reuse safety
    }
    if (b == 0 && t == 0) dout[(size_t)MROWS*DIM] = (float)TOPQ/(float)SEQ;
}

// Q projection for the selected rows -> bf16 head-major Qhm[b][h][48][64]
// (rows TOPQ..47 zero-padded so the MFMA attention can use 3 full 16-row tiles)
__global__ __launch_bounds__(256) void qproj_kernel(const float* __restrict__ xn,
                                                    const float* __restrict__ in_w,
                                                    const float* __restrict__ in_b,
                                                    const int* __restrict__ topidx,
                                                    bf16* __restrict__ Qhm)
{
    int j = blockIdx.x, b = blockIdx.y, t = threadIdx.x;
    __shared__ float qr[DIM];
    if (j >= TOPQ){
        for (int d0 = t; d0 < DIM; d0 += 256){
            int h = d0 >> 6, d = d0 & 63;
            Qhm[((size_t)(b*NH + h)*QPAD + j)*DHEAD + d] = __float2bfloat16(0.f);
        }
        return;
    }
    int srow = topidx[b*64 + j];
    const float* xr = xn + ((size_t)(b*SEQ + srow))*DIM;
    for (int i = t; i < DIM; i += 256) qr[i] = xr[i];
    __syncthreads();
    for (int d0 = t; d0 < DIM; d0 += 256){
        const float* wr = in_w + (size_t)d0*DIM;   // Wq row d0
        float s = 0.f;
        for (int e = 0; e < DIM; e += 4){
            float4 wv = *(const float4*)(wr + e);
            s += qr[e]*wv.x + qr[e+1]*wv.y + qr[e+2]*wv.z + qr[e+3]*wv.w;
        }
        int h = d0 >> 6, d = d0 & 63;
        Qhm[((size_t)(b*NH + h)*QPAD + j)*DHEAD + d] = __float2bfloat16(s + in_b[d0]);
    }
}

// ---------------------------------------------------------------------------
// MFMA split-K attention partial (round-14 structure: KC=64, 2 blocks/CU).
// ---------------------------------------------------------------------------
__global__ __launch_bounds__(256, 1) void attn_mfma_kernel(const bf16* __restrict__ Qhm,
                                                           const bf16* __restrict__ Khm,
                                                           const bf16* __restrict__ Vhm,
                                                           float* __restrict__ part)
{
    __shared__ __align__(16) short vsm[4*4096];   // 32 KB: 4 waves x (64k x 64d)
    const int bh   = blockIdx.z*NH + blockIdx.y;
    const int w    = threadIdx.x >> 6;
    const int lane = threadIdx.x & 63;
    const int ch   = blockIdx.x*4 + w;           // chunk 0..31
    const int kb   = ch*KC;                      // first key of chunk
    const int lf   = lane & 15;
    const int g    = lane >> 4;

    // ---- stage V chunk into per-wave LDS, subtiled elem = (d>>4)*1024 + k*16 + (d&15)
    short* vbase = vsm + w*4096;
    const short* vg = (const short*)Vhm + ((size_t)bh*SEQ + kb)*DHEAD;
    {
        const int kh = lane >> 1, dh = (lane & 1)*8;
        #pragma unroll
        for (int L = 0; L < 8; ++L){
            int k = (L & 1)*32 + kh;
            int d = (L >> 1)*16 + dh;
            load_lds16(vg + (size_t)k*DHEAD + d, vbase + L*512);
        }
    }

    // ---- Q B-fragments (col = q = lf, k-octet = g), direct from global
    short8 qf[3][2];
    const short* qp = (const short*)Qhm + (size_t)bh*QPAD*DHEAD;
    #pragma unroll
    for (int nt = 0; nt < 3; ++nt)
        #pragma unroll
        for (int s = 0; s < 2; ++s)
            qf[nt][s] = *(const short8*)(qp + (nt*16 + lf)*DHEAD + s*32 + g*8);

    // ---- S^T = K·Q^T : M = 64 keys (4 tiles), N = 48 q (3 tiles), K = 64 (2 steps)
    floatx4 sa[4][3];
    floatx4 z = {0.f,0.f,0.f,0.f};
    #pragma unroll
    for (int mt = 0; mt < 4; ++mt)
        #pragma unroll
        for (int nt = 0; nt < 3; ++nt) sa[mt][nt] = z;

    const short* kp = (const short*)Khm + ((size_t)bh*SEQ + kb)*DHEAD;
    #pragma unroll
    for (int mt = 0; mt < 4; ++mt){
        const short* kr = kp + (size_t)(mt*16 + lf)*DHEAD + g*8;
        short8 kf0 = *(const short8*)(kr);
        short8 kf1 = *(const short8*)(kr + 32);
        #pragma unroll
        for (int nt = 0; nt < 3; ++nt){
            sa[mt][nt] = __builtin_amdgcn_mfma_f32_16x16x32_bf16(kf0, qf[nt][0], sa[mt][nt], 0, 0, 0);
            sa[mt][nt] = __builtin_amdgcn_mfma_f32_16x16x32_bf16(kf1, qf[nt][1], sa[mt][nt], 0, 0, 0);
        }
    }

    // ---- in-register partial softmax per q (raw-score max; scale folded into exp)
    float mx[3], ls[3];
    #pragma unroll
    for (int nt = 0; nt < 3; ++nt){
        float m = sa[0][nt][0];
        #pragma unroll
        for (int mt = 0; mt < 4; ++mt)
            #pragma unroll
            for (int r = 0; r < 4; ++r) m = fmaxf(m, sa[mt][nt][r]);
        m = fmaxf(m, __shfl_xor(m, 16));
        m = fmaxf(m, __shfl_xor(m, 32));
        float l = 0.f;
        #pragma unroll
        for (int mt = 0; mt < 4; ++mt){
            #pragma unroll
            for (int r = 0; r < 4; ++r){
                float p = __expf((sa[mt][nt][r] - m)*0.125f);   // 1/sqrt(64)
                sa[mt][nt][r] = p;
                l += p;
            }
        }
        l += __shfl_xor(l, 16);
        l += __shfl_xor(l, 32);
        mx[nt] = m; ls[nt] = l;
    }

    // ---- PV: ctx = P(48x64)·V(64x64), mfma 16x16x16, K-steps t = 0..3
    asm volatile("s_waitcnt vmcnt(0)" ::: "memory");   // V staging landed
    floatx4 oacc[3][4];
    #pragma unroll
    for (int mi = 0; mi < 3; ++mi)
        #pragma unroll
        for (int dt = 0; dt < 4; ++dt) oacc[mi][dt] = z;

    #pragma unroll
    for (int t = 0; t < 4; ++t){
        sh4 pa[3];
        #pragma unroll
        for (int mi = 0; mi < 3; ++mi){
            union { sh4 v; unsigned u[2]; } pk;
            pk.u[0] = f2bf_bits(sa[t][mi][0]) | (f2bf_bits(sa[t][mi][1]) << 16);
            pk.u[1] = f2bf_bits(sa[t][mi][2]) | (f2bf_bits(sa[t][mi][3]) << 16);
            pa[mi] = pk.v;
        }
        #pragma unroll
        for (int dt = 0; dt < 4; ++dt){
            sh4 vf = tr16_read(vbase + dt*1024 + (t*16 + 4*g)*16 + lf);
            #pragma unroll
            for (int mi = 0; mi < 3; ++mi)
                oacc[mi][dt] = mfma16(pa[mi], vf, oacc[mi][dt]);
        }
    }

    // ---- store partial: ctx rows (q = mi*16 + 4g + r, d = dt*16 + lf), plus m,l
    float* pbase = part + ((size_t)bh*TOPQ*NKC + ch)*PSTR;
    #pragma unroll
    for (int mi = 0; mi < 3; ++mi){
        #pragma unroll
        for (int r = 0; r < 4; ++r){
            int q = mi*16 + 4*g + r;
            if (q < TOPQ){
                float* pp = pbase + (size_t)q*NKC*PSTR;
                #pragma unroll
                for (int dt = 0; dt < 4; ++dt)
                    pp[dt*16 + lf] = oacc[mi][dt][r];
            }
        }
    }
    #pragma unroll
    for (int nt = 0; nt < 3; ++nt){
        int q = nt*16 + lf;
        if (g == 3 && q < TOPQ){
            float* pp = pbase + (size_t)q*NKC*PSTR;
            pp[64] = mx[nt]*0.125f;
            pp[65] = ls[nt];
        }
    }
}

// ---------------------------------------------------------------------------
// Round-15: merged attn partial-merge + output projection. grid (TOPQ, BATCH).
// Phase 1: each wave merges 2 heads' 32 partials -> ctx row in LDS.
// Phase 2: 512-dot out-projection from LDS. Kills one dispatch + ctxb trip.
// ---------------------------------------------------------------------------
__global__ __launch_bounds__(256) void attn_out_kernel(const float* __restrict__ part,
                                                       const float* __restrict__ ow,
                                                       const float* __restrict__ ob,
                                                       float* __restrict__ sout)
{
    __shared__ float cr[DIM];
    int q = blockIdx.x, b = blockIdx.y;
    int t = threadIdx.x, w = t >> 6, lane = t & 63;
    for (int h = w; h < NH; h += 4){
        const float* pb = part + (((size_t)(b*NH + h))*TOPQ + q)*NKC*PSTR;
        float M = -3.402823466e38f;
        #pragma unroll
        for (int i = 0; i < NKC; ++i) M = fmaxf(M, pb[i*PSTR + 64]);
        float L = 0.f, a = 0.f;
        #pragma unroll
        for (int i = 0; i < NKC; ++i){
            float sc = __expf(pb[i*PSTR + 64] - M);
            L += pb[i*PSTR + 65]*sc;
            a += pb[i*PSTR + lane]*sc;
        }
        cr[h*64 + lane] = a/L;
    }
    __syncthreads();
    for (int d0 = t; d0 < DIM; d0 += 256){
        const float* wr = ow + (size_t)d0*DIM;
        float s = 0.f;
        for (int e = 0; e < DIM; e += 4){
            float4 wv = *(const float4*)(wr + e);
            s += cr[e]*wv.x + cr[e+1]*wv.y + cr[e+2]*wv.z + cr[e+3]*wv.w;
        }
        sout[((size_t)(b*TOPQ + q))*DIM + d0] = s + ob[d0];
    }
}

// ---------------------------------------------------------------------------
// Round-15 res+LN2: ONE-PASS paired fp32 reduction (Σv, Σv²); 4 -> 1 barrier.
// One-pass var deviation from ref's two-pass ~1e-6 rel << bf16 rounding.
// ---------------------------------------------------------------------------
__global__ __launch_bounds__(256) void res_ln2_kernel(const float* __restrict__ x,
                                                      const float* __restrict__ xbar,
                                                      const float* __restrict__ sout,
                                                      const int* __restrict__ selmap,
                                                      const float* __restrict__ g2,
                                                      const float* __restrict__ bt2,
                                                      float* __restrict__ x2,
                                                      bf16* __restrict__ hb)
{
    __shared__ float sbuf[8];
    int row = blockIdx.x;
    int b = row >> 11;
    int t = threadIdx.x;
    int slot = selmap[row];
    const float* ar = (slot >= 0) ? (sout + ((size_t)(b*TOPQ + slot))*DIM)
                                  : (xbar + (size_t)b*DIM);
    size_t base = (size_t)row*DIM;
    float v0 = x[base + t]       + ar[t];
    float v1 = x[base + t + 256] + ar[t + 256];
    x2[base + t] = v0; x2[base + t + 256] = v1;
    float a = v0 + v1, q = v0*v0 + v1*v1;
    #pragma unroll
    for (int off = 32; off > 0; off >>= 1){
        a += __shfl_down(a, off);
        q += __shfl_down(q, off);
    }
    if ((t & 63) == 0){ sbuf[t >> 6] = a; sbuf[4 + (t >> 6)] = q; }
    __syncthreads();
    float sv  = sbuf[0] + sbuf[1] + sbuf[2] + sbuf[3];
    float svv = sbuf[4] + sbuf[5] + sbuf[6] + sbuf[7];
    float m   = sv*(1.f/DIM);
    float var = svv*(1.f/DIM) - m*m;
    float r = 1.f/sqrtf(var + 1e-5f);
    hb[base + t]       = __float2bfloat16((v0 - m)*r*g2[t]     + bt2[t]);
    hb[base + t + 256] = __float2bfloat16((v1 - m)*r*g2[t+256] + bt2[t+256]);
}

// ---------------------------------------------------------------------------
extern "C" void kernel_launch(void* const* d_in, const int* in_sizes, int n_in,
                              void* d_out, int out_size, void* d_ws, size_t ws_size,
                              hipStream_t stream)
{
    (void)in_sizes; (void)n_in; (void)out_size; (void)ws_size;
    const float* x     = (const float*)d_in[0];
    const float* ln1_g = (const float*)d_in[1];
    const float* ln1_b = (const float*)d_in[2];
    const float* in_w  = (const float*)d_in[3];
    const float* in_b  = (const float*)d_in[4];
    const float* out_w = (const float*)d_in[5];
    const float* out_b = (const float*)d_in[6];
    const float* ln2_g = (const float*)d_in[7];
    const float* ln2_b = (const float*)d_in[8];
    const float* w1    = (const float*)d_in[9];
    const float* b1    = (const float*)d_in[10];
    const float* w2    = (const float*)d_in[11];
    const float* b2    = (const float*)d_in[12];
    float* out = (float*)d_out;

    const size_t MB = 1024*1024;
    char* base = (char*)d_ws;
    float* xn_f  = (float*)base;                 // [0,32MiB); reused as x2_f later
    bf16*  xn_b  = (bf16*)(base + 32*MB);        // dead after kv-gemm -> h_b
    bf16*  Khm   = (bf16*)(base + 48*MB);
    bf16*  Vhm   = (bf16*)(base + 64*MB);
    bf16*  h_b   = (bf16*)(base + 32*MB);
    bf16*  h1_b  = (bf16*)(base + 48*MB);        // overwrites Khm/Vhm after attn
    float* x2_f  = xn_f;
    // apart (21 MiB) lives at [80,101) MiB: free during attention (h1_b rows
    // covering it are written only by FFN1, after attn_out consumed apart).
    float* apart = (float*)(base + 80*MB);
    char* p = base + 112*MB;
    bf16*  kvw_b  = (bf16*)p;  p += (size_t)1024*DIM*2;        // in_w rows [512,1536) bf16
    bf16*  w1_b   = (bf16*)p;  p += (size_t)FFD*DIM*2;
    bf16*  w2_b   = (bf16*)p;  p += (size_t)DIM*FFD*2;
    double* xbpart= (double*)p; p += (size_t)BATCH*32*DIM*8;
    double* xbar_d= (double*)p; p += (size_t)BATCH*DIM*8;
    float* xbar_f = (float*)p;  p += (size_t)BATCH*DIM*4;
    double* spars = (double*)p; p += (size_t)MROWS*8;
    int*   topidx = (int*)p;    p += (size_t)BATCH*64*4;
    int*   selmap = (int*)p;    p += (size_t)MROWS*4;
    bf16*  Qhm    = (bf16*)p;   p += (size_t)BATCH*NH*QPAD*DHEAD*2;   // 384 KiB
    float* sout   = (float*)p;  p += (size_t)BATCH*TOPQ*DIM*4;

    prep_kernel<<<2624, 256, 0, stream>>>(in_w, w1, w2, kvw_b, w1_b, w2_b, selmap);
    ln1_kernel<<<MROWS, 256, 0, stream>>>(x, ln1_g, ln1_b, xn_f, xn_b);
    xbar_part_kernel<<<dim3(32, BATCH), 512, 0, stream>>>(xn_f, xbpart);
    xbar_fin_kernel<<<BATCH, 512, 0, stream>>>(xbpart, xbar_d, xbar_f);
    sparsity_kernel<<<MROWS/4, 256, 0, stream>>>(xn_f, xbar_d, spars);
    topk_kernel<<<BATCH, 256, 0, stream>>>(spars, topidx, selmap, out);
    // KV projection (N=1024 -> head-major K/V): grid 8x128 -> 1024 blocks, lgGX=3
    gemm128_kernel<3, bf16><<<1024, 256, 0, stream>>>(
        xn_b, kvw_b, in_b + DIM, Khm, nullptr, Vhm, DIM, 0, 3);
    qproj_kernel<<<dim3(QPAD, BATCH), 256, 0, stream>>>(xn_f, in_w, in_b, topidx, Qhm);
    attn_mfma_kernel<<<dim3(NKC/4, NH, BATCH), 256, 0, stream>>>(Qhm, Khm, Vhm, apart);
    attn_out_kernel<<<dim3(TOPQ, BATCH), 256, 0, stream>>>(apart, out_w, out_b, sout);
    res_ln2_kernel<<<MROWS, 256, 0, stream>>>(x, xbar_f, sout, selmap, ln2_g, ln2_b, x2_f, h_b);
    // FFN1: grid 16x128 -> 2048 blocks, lgGX=4
    gemm128_kernel<1, bf16><<<2048, 256, 0, stream>>>(
        h_b, w1_b, b1, h1_b, nullptr, nullptr, DIM, FFD, 4);
    // FFN2: grid 4x128 -> 512 blocks, lgGX=2
    gemm128_kernel<2, float><<<512, 256, 0, stream>>>(
        h1_b, w2_b, b2, out, x2_f, nullptr, FFD, DIM, 2);
}

// Round 9
// 365.211 us; speedup vs baseline: 1.3668x; 1.2373x over previous
//
#include <hip/hip_runtime.h>
#include <hip/hip_bf16.h>
#include <math.h>

#define BATCH 8
#define SEQ   2048
#define DIM   512
#define NH    8
#define DHEAD 64
#define FFD   2048
#define TOPQ  39            // ceil(5*ln(2048)) with factor=5, min_k=5 (fixed harness inputs)
#define MROWS (BATCH*SEQ)   // 16384
#define KC    64            // keys per attention partial chunk (one wave)
#define NKC   (SEQ/KC)      // 32
#define PSTR  66            // partial stride: 64 ctx + m + l
#define QPAD  48            // TOPQ padded to 3 MFMA row-tiles

typedef __hip_bfloat16 bf16;
typedef __attribute__((ext_vector_type(8))) short short8;
typedef __attribute__((ext_vector_type(4))) short sh4;
typedef __attribute__((ext_vector_type(4))) float floatx4;

__device__ __forceinline__ float bf2f(short u){
    return __uint_as_float(((unsigned int)(unsigned short)u) << 16);
}
// RNE fp32->bf16 bits (matches hardware convert for finite values)
__device__ __forceinline__ unsigned int f2bf_bits(float f){
    unsigned int u = __float_as_uint(f);
    return (u + 0x7fffu + ((u >> 16) & 1u)) >> 16;
}
// fast gelu (tanh form): |err vs exact erf-gelu| < ~3e-3, << bf16 rounding here
__device__ __forceinline__ float gelu_f(float v){
    float u = v*(0.7978845608028654f + 0.0356774081363f*v*v);
    float e = __expf(2.f*u);
    return 0.5f*v*(2.f - 2.f/(e + 1.f));
}

// async global->LDS, 16 B per lane; LDS dest = wave-uniform base + lane*16
__device__ __forceinline__ void load_lds16(const void* g, void* l){
    auto gp = reinterpret_cast<const uint32_t __attribute__((address_space(1)))*>(
        reinterpret_cast<uintptr_t>(g));
    auto lp = reinterpret_cast<uint32_t __attribute__((address_space(3)))*>(
        reinterpret_cast<uintptr_t>(l));
    __builtin_amdgcn_global_load_lds(gp, lp, 16, 0, 0);
}

// 16x16x16 bf16 MFMA (K=16): A/B = 4 bf16/lane (k = (lane>>4)*4 + j), C/D std 16x16 map
__device__ __forceinline__ floatx4 mfma16(sh4 a, sh4 b, floatx4 c){
#if __has_builtin(__builtin_amdgcn_mfma_f32_16x16x16bf16_1k)
    return __builtin_amdgcn_mfma_f32_16x16x16bf16_1k(a, b, c, 0, 0, 0);
#elif __has_builtin(__builtin_amdgcn_mfma_f32_16x16x16_bf16)
    return __builtin_amdgcn_mfma_f32_16x16x16_bf16(a, b, c, 0, 0, 0);
#else
    asm volatile("v_mfma_f32_16x16x16_bf16 %0, %1, %2, %0\n\ts_nop 7\n\ts_nop 7"
                 : "+v"(c) : "v"(a), "v"(b));
    return c;
#endif
}

// transpose-read: 4 bf16 at elem strides {0,16,32,48} from per-lane LDS addr
__device__ __forceinline__ sh4 tr16_read(const short* p){
#if __has_builtin(__builtin_amdgcn_ds_read_tr16_b64_v4i16)
    auto lp = (__attribute__((address_space(3))) sh4*)(uintptr_t)p;
    return __builtin_amdgcn_ds_read_tr16_b64_v4i16(lp);
#elif __has_builtin(__builtin_amdgcn_ds_read_tr16_b64)
    auto lp = (__attribute__((address_space(3))) sh4*)(uintptr_t)p;
    return __builtin_amdgcn_ds_read_tr16_b64(lp);
#else
    sh4 r; r[0] = p[0]; r[1] = p[16]; r[2] = p[32]; r[3] = p[48]; return r;
#endif
}

__device__ __forceinline__ void store_out(bf16* p, float v){ *p = __float2bfloat16(v); }
__device__ __forceinline__ void store_out(float* p, float v){ *p = v; }

// ---------------------------------------------------------------------------
// 128x128-tile GEMM (round-10 proven structure): C = A(MxK)·B(NxK)^T + bias.
// Depth-2 pipeline, counted vmcnt (T4). 3 x 16 KB LDS buffers.
// EPI: 1 = gelu->bf16, 2 = +x2 -> fp32 (direct stores), 3 = KV head-major.
// ---------------------------------------------------------------------------
template<int EPI, typename OUT_T>
__global__ __launch_bounds__(256, 3) void gemm128_kernel(const bf16* __restrict__ A,
                                                         const bf16* __restrict__ Bm,
                                                         const float* __restrict__ bias,
                                                         OUT_T* __restrict__ C,
                                                         const float* __restrict__ x2,
                                                         bf16* __restrict__ Vhm,
                                                         int K, int ldc, int lgGX)
{
    __shared__ __align__(16) char smem[49152];   // 3 x (As 8KB | Bs 8KB)
    short* CsBase = (short*)smem;

    const int bid = blockIdx.x;
    const int per = gridDim.x >> 3;
    const int lid = (bid & 7)*per + (bid >> 3);
    const int bx  = lid & ((1 << lgGX) - 1);
    const int by  = lid >> lgGX;

    const int t    = threadIdx.x;
    const int lane = t & 63;
    const int w    = t >> 6;
    const int lf   = lane & 15;
    const int ko   = lane >> 4;
    const int slot = ko ^ ((lf >> 1) & 3);
    const int mrow = (w >> 1)*64, ncol = (w & 1)*64;

    floatx4 acc[4][4];
    floatx4 z = {0.f,0.f,0.f,0.f};
    #pragma unroll
    for (int i = 0; i < 4; ++i)
        #pragma unroll
        for (int j = 0; j < 4; ++j) acc[i][j] = z;

    const int srow = w*16 + (lane >> 2);
    const int sq   = lane & 3;
    const int r0 = srow,      kq0 = sq ^ ((r0 >> 1) & 3);
    const int r1 = 64 + srow, kq1 = sq ^ ((r1 >> 1) & 3);
    const short* ga0 = (const short*)A  + ((size_t)by*128 + r0)*K + kq0*8;
    const short* ga1 = (const short*)A  + ((size_t)by*128 + r1)*K + kq1*8;
    const short* gb0 = (const short*)Bm + ((size_t)bx*128 + r0)*K + kq0*8;
    const short* gb1 = (const short*)Bm + ((size_t)bx*128 + r1)*K + kq1*8;
    char* la0 = smem + w*1024;
    char* la1 = smem + 4096 + w*1024;
    char* lb0 = smem + 8192 + w*1024;
    char* lb1 = smem + 12288 + w*1024;

    auto stage = [&](int off){
        load_lds16(ga0, la0 + off); load_lds16(ga1, la1 + off);
        load_lds16(gb0, lb0 + off); load_lds16(gb1, lb1 + off);
        ga0 += 32; ga1 += 32; gb0 += 32; gb1 += 32;
    };
    auto compute = [&](int off){
        const short* As = (const short*)(smem + off);
        const short* Bs = (const short*)(smem + off + 8192);
        short8 af[4], bfr[4];
        #pragma unroll
        for (int i = 0; i < 4; ++i){
            af[i]  = *(const short8*)(As + (mrow + i*16 + lf)*32 + slot*8);
            bfr[i] = *(const short8*)(Bs + (ncol + i*16 + lf)*32 + slot*8);
        }
        #pragma unroll
        for (int i = 0; i < 4; ++i)
            #pragma unroll
            for (int j = 0; j < 4; ++j)
                acc[i][j] = __builtin_amdgcn_mfma_f32_16x16x32_bf16(af[i], bfr[j], acc[i][j], 0, 0, 0);
    };

    const int T = K >> 5;
    stage(0);
    stage(16384);
    int oc = 0, on = 16384, on2 = 32768;
    for (int kt = 0; kt < T - 2; ++kt){
        asm volatile("s_waitcnt vmcnt(4)" ::: "memory");
        __builtin_amdgcn_s_barrier();
        asm volatile("" ::: "memory");
        stage(on2);
        compute(oc);
        int tmp = oc; oc = on; on = on2; on2 = tmp;
    }
    asm volatile("s_waitcnt vmcnt(4)" ::: "memory");
    __builtin_amdgcn_s_barrier();
    asm volatile("" ::: "memory");
    compute(oc);
    { int tmp = oc; oc = on; on = on2; on2 = tmp; }
    asm volatile("s_waitcnt vmcnt(0)" ::: "memory");
    __builtin_amdgcn_s_barrier();
    asm volatile("" ::: "memory");
    compute(oc);
    __syncthreads();

    if constexpr (EPI == 2){
        const int lr = ko*4;
        #pragma unroll
        for (int j = 0; j < 4; ++j){
            int gcol = bx*128 + ncol + j*16 + lf;
            float bv = bias[gcol];
            #pragma unroll
            for (int i = 0; i < 4; ++i){
                #pragma unroll
                for (int r = 0; r < 4; ++r){
                    size_t grow = (size_t)by*128 + mrow + i*16 + lr + r;
                    float v = acc[i][j][r] + bv + x2[grow*ldc + gcol];
                    store_out(&C[grow*ldc + gcol], v);
                }
            }
        }
    } else {
        short* cs = CsBase + w*(64*72);
        const int odd = lf & 1;
        const int rsel = odd*2;
        #pragma unroll
        for (int j = 0; j < 4; ++j){
            float bv = bias[bx*128 + ncol + j*16 + lf];
            #pragma unroll
            for (int i = 0; i < 4; ++i){
                unsigned long long self = 0;
                #pragma unroll
                for (int r = 0; r < 4; ++r){
                    float v = acc[i][j][r] + bv;
                    if constexpr (EPI == 1) v = gelu_f(v);
                    self |= ((unsigned long long)f2bf_bits(v)) << (16*r);
                }
                unsigned long long nbr = __shfl_xor(self, 1);
                unsigned long long lo = odd ? nbr : self;
                unsigned long long hi = odd ? self : nbr;
                int colb = 16*j + (lf & ~1);
                unsigned int w0 = (unsigned int)((lo >> (16*rsel)) & 0xffffu)
                                | ((unsigned int)((hi >> (16*rsel)) & 0xffffu) << 16);
                unsigned int w1 = (unsigned int)((lo >> (16*(rsel+1))) & 0xffffu)
                                | ((unsigned int)((hi >> (16*(rsel+1))) & 0xffffu) << 16);
                *(unsigned int*)(cs + (16*i + 4*ko + rsel    )*72 + colb) = w0;
                *(unsigned int*)(cs + (16*i + 4*ko + rsel + 1)*72 + colb) = w1;
            }
        }
        const int subrow = lane >> 3, cq = lane & 7;
        #pragma unroll
        for (int rr = 0; rr < 8; ++rr){
            int rl = rr*8 + subrow;
            short8 vv = *(const short8*)(cs + rl*72 + cq*8);
            if constexpr (EPI == 3){
                int grow = by*128 + mrow + rl;
                int b = grow >> 11, s = grow & 2047;
                int gc = bx*128 + ncol + cq*8;
                int h = (gc >> 6) & 7, d = gc & 63;
                bf16* dst = (gc < 512) ? (bf16*)C : Vhm;
                *(short8*)((short*)dst + (((size_t)(b*NH + h))*SEQ + s)*DHEAD + d) = vv;
            } else {
                size_t grow = (size_t)by*128 + mrow + rl;
                int gcol = bx*128 + ncol + cq*8;
                *(short8*)((short*)C + grow*ldc + gcol) = vv;
            }
        }
    }
}

// ---------------------------------------------------------------------------
// merged prep — selmap init + 3 fp32->bf16 weight converts in ONE launch.
// ---------------------------------------------------------------------------
__global__ __launch_bounds__(256) void prep_kernel(const float* __restrict__ in_w,
                                                   const float* __restrict__ w1,
                                                   const float* __restrict__ w2,
                                                   bf16* __restrict__ kvw_b,
                                                   bf16* __restrict__ w1_b,
                                                   bf16* __restrict__ w2_b,
                                                   int* __restrict__ selmap)
{
    int bid = blockIdx.x, t = threadIdx.x;
    if (bid < 64){
        selmap[bid*256 + t] = -1;
        return;
    }
    const float* src; bf16* dst; int i;
    if (bid < 576){      src = in_w + (size_t)DIM*DIM; dst = kvw_b; i = ((bid - 64)*256 + t)*4; }
    else if (bid < 1600){ src = w1;  dst = w1_b; i = ((bid - 576)*256 + t)*4; }
    else {               src = w2;  dst = w2_b; i = ((bid - 1600)*256 + t)*4; }
    float4 v = *(const float4*)(src + i);
    dst[i+0] = __float2bfloat16(v.x);
    dst[i+1] = __float2bfloat16(v.y);
    dst[i+2] = __float2bfloat16(v.z);
    dst[i+3] = __float2bfloat16(v.w);
}

// ---------------------------------------------------------------------------
// LN1: ONE-PASS paired fp64 reduction (Σx, Σx²) -> var = E[x²]-m². 1 barrier.
// ---------------------------------------------------------------------------
__global__ __launch_bounds__(256) void ln1_kernel(const float* __restrict__ x,
                                                  const float* __restrict__ g,
                                                  const float* __restrict__ bt,
                                                  float* __restrict__ xn,
                                                  bf16* __restrict__ xnb)
{
    __shared__ double sbuf[8];
    int row = blockIdx.x;
    int t = threadIdx.x;
    size_t base = (size_t)row*DIM;
    double x0 = (double)x[base + t];
    double x1 = (double)x[base + t + 256];
    double a = x0 + x1, q = x0*x0 + x1*x1;
    #pragma unroll
    for (int off = 32; off > 0; off >>= 1){
        a += __shfl_down(a, off);
        q += __shfl_down(q, off);
    }
    if ((t & 63) == 0){ sbuf[t >> 6] = a; sbuf[4 + (t >> 6)] = q; }
    __syncthreads();
    double sx  = sbuf[0] + sbuf[1] + sbuf[2] + sbuf[3];
    double sxx = sbuf[4] + sbuf[5] + sbuf[6] + sbuf[7];
    double m   = sx*(1.0/DIM);
    double var = sxx*(1.0/DIM) - m*m;
    double r = 1.0/sqrt(var + 1e-5);
    double y0 = (x0 - m)*r*(double)g[t]     + (double)bt[t];
    double y1 = (x1 - m)*r*(double)g[t+256] + (double)bt[t+256];
    xn[base+t] = (float)y0;       xn[base+t+256] = (float)y1;
    xnb[base+t] = __float2bfloat16((float)y0);
    xnb[base+t+256] = __float2bfloat16((float)y1);
}

// column-mean of xn per batch, fp64 two-stage
__global__ __launch_bounds__(512) void xbar_part_kernel(const float* __restrict__ xn, double* __restrict__ part){
    int b = blockIdx.y, c = blockIdx.x, d = threadIdx.x;
    const float* p = xn + ((size_t)b*SEQ + c*64)*DIM + d;
    double s = 0.0;
    for (int i = 0; i < 64; ++i) s += (double)p[(size_t)i*DIM];
    part[((size_t)(b*32 + c))*DIM + d] = s;
}
__global__ __launch_bounds__(512) void xbar_fin_kernel(const double* __restrict__ part,
                                                       double* __restrict__ xbar_d,
                                                       float* __restrict__ xbar_f){
    int b = blockIdx.x, d = threadIdx.x;
    double s = 0.0;
    for (int c = 0; c < 32; ++c) s += part[((size_t)(b*32 + c))*DIM + d];
    s *= (1.0/SEQ);
    xbar_d[(size_t)b*DIM + d] = s;
    xbar_f[(size_t)b*DIM + d] = (float)s;
}

// sparsity*sqrt(D) = Σxn² - dot(xn_row, xbar); fp64 over the SAME fp32 xn
// values ref uses -> ranking margin >> ref's own fp32 noise.
__global__ __launch_bounds__(256) void sparsity_kernel(const float* __restrict__ xn,
                                                       const double* __restrict__ xbar,
                                                       double* __restrict__ sp)
{
    int row  = blockIdx.x*4 + (threadIdx.x >> 6);
    int lane = threadIdx.x & 63;
    int b    = row >> 11;
    const float* xr = xn + (size_t)row*DIM;
    const double* xb = xbar + (size_t)b*DIM;
    double s = 0.0, d2 = 0.0;
    for (int e = lane; e < DIM; e += 64){
        double xv = (double)xr[e];
        s  += xv*xb[e];
        d2 += xv*xv;
    }
    #pragma unroll
    for (int off = 32; off > 0; off >>= 1){
        s  += __shfl_down(s, off);
        d2 += __shfl_down(d2, off);
    }
    if (lane == 0) sp[row] = d2 - s;
}

// ---------------------------------------------------------------------------
// register-resident top-39 (proven): packed monotone u64 order keys.
// ---------------------------------------------------------------------------
__global__ __launch_bounds__(256) void topk_kernel(const double* __restrict__ sp,
                                                   int* __restrict__ topidx,
                                                   int* __restrict__ selmap,
                                                   float* __restrict__ dout)
{
    __shared__ unsigned long long wmax[4];
    int b = blockIdx.x, t = threadIdx.x;
    int lane = t & 63, w = t >> 6;

    unsigned long long pk[8];
    #pragma unroll
    for (int i = 0; i < 8; ++i){
        int idx = i*256 + t;                          // coalesced
        unsigned long long bits =
            (unsigned long long)__double_as_longlong(sp[(size_t)b*SEQ + idx]);
        unsigned long long m = (bits & 0x8000000000000000ull)
                             ? ~bits : (bits | 0x8000000000000000ull);
        pk[i] = (m & ~2047ull) | (unsigned long long)(2047 - idx);
    }
    unsigned long long lm = pk[0];
    #pragma unroll
    for (int i = 1; i < 8; ++i) lm = (pk[i] > lm) ? pk[i] : lm;

    for (int it = 0; it < TOPQ; ++it){
        unsigned long long m = lm;
        #pragma unroll
        for (int off = 32; off > 0; off >>= 1){
            unsigned long long o = __shfl_xor(m, off);
            m = (o > m) ? o : m;
        }
        if (lane == 0) wmax[w] = m;
        __syncthreads();
        unsigned long long g01 = (wmax[0] > wmax[1]) ? wmax[0] : wmax[1];
        unsigned long long g23 = (wmax[2] > wmax[3]) ? wmax[2] : wmax[3];
        unsigned long long g = (g01 > g23) ? g01 : g23;
        int idx = 2047 - (int)(g & 2047ull);
        if (t == 0){
            topidx[b*64 + it] = idx;
            selmap[(size_t)b*SEQ + idx] = it;
        }
        if ((idx & 255) == t){                        // owner removes + recompute
            int slot = idx >> 8;
            #pragma unroll
            for (int i = 0; i < 8; ++i) if (i == slot) pk[i] = 0;
            lm = pk[0];
            #pragma unroll
            for (int i = 1; i < 8; ++i) lm = (pk[i] > lm) ? pk[i] : lm;
        }
        __syncthreads();                              // wmax reuse safety
    }
    if (b == 0 && t == 0) dout[(size_t)MROWS*DIM] = (float)TOPQ/(float)SEQ;
}

// ---------------------------------------------------------------------------
// Round-16 qproj v2: 32x-parallel. Old: 384 blocks, 512-FMA serial chains
// over L2-latency in_w loads -> latency-bound (hidden ~40-60us). New: grid
// (32, QPAD, BATCH) = 12288 blocks; block = 16 outputs x 16-lane K-split
// (32 elems/lane, 32-FMA chain). Lane-interleaved e = i*64 + k*4: 16-lane
// group reads 256B contiguous per step (coalesced; LDS 2-way = free).
// ---------------------------------------------------------------------------
__global__ __launch_bounds__(256) void qproj_kernel(const float* __restrict__ xn,
                                                    const float* __restrict__ in_w,
                                                    const float* __restrict__ in_b,
                                                    const int* __restrict__ topidx,
                                                    bf16* __restrict__ Qhm)
{
    __shared__ float qr[DIM];
    int dblk = blockIdx.x, j = blockIdx.y, b = blockIdx.z;
    int t = threadIdx.x;
    int o = t >> 4, ks = t & 15;
    int d0 = dblk*16 + o;
    int h = d0 >> 6, d = d0 & 63;
    if (j >= TOPQ){
        if (ks == 0)
            Qhm[((size_t)(b*NH + h)*QPAD + j)*DHEAD + d] = __float2bfloat16(0.f);
        return;
    }
    int srow = topidx[b*64 + j];
    const float* xr = xn + ((size_t)(b*SEQ + srow))*DIM;
    qr[t] = xr[t]; qr[t + 256] = xr[t + 256];
    __syncthreads();
    const float* wr = in_w + (size_t)d0*DIM;
    float s = 0.f;
    #pragma unroll
    for (int i = 0; i < 8; ++i){
        int e = i*64 + ks*4;
        float4 wv = *(const float4*)(wr + e);
        float4 cv = *(const float4*)(qr + e);
        s += cv.x*wv.x + cv.y*wv.y + cv.z*wv.z + cv.w*wv.w;
    }
    #pragma unroll
    for (int off = 8; off > 0; off >>= 1) s += __shfl_down(s, off, 16);
    if (ks == 0)
        Qhm[((size_t)(b*NH + h)*QPAD + j)*DHEAD + d] = __float2bfloat16(s + in_b[d0]);
}

// ---------------------------------------------------------------------------
// MFMA split-K attention partial (KC=64, 2 blocks/CU).
// ---------------------------------------------------------------------------
__global__ __launch_bounds__(256, 1) void attn_mfma_kernel(const bf16* __restrict__ Qhm,
                                                           const bf16* __restrict__ Khm,
                                                           const bf16* __restrict__ Vhm,
                                                           float* __restrict__ part)
{
    __shared__ __align__(16) short vsm[4*4096];   // 32 KB: 4 waves x (64k x 64d)
    const int bh   = blockIdx.z*NH + blockIdx.y;
    const int w    = threadIdx.x >> 6;
    const int lane = threadIdx.x & 63;
    const int ch   = blockIdx.x*4 + w;           // chunk 0..31
    const int kb   = ch*KC;                      // first key of chunk
    const int lf   = lane & 15;
    const int g    = lane >> 4;

    short* vbase = vsm + w*4096;
    const short* vg = (const short*)Vhm + ((size_t)bh*SEQ + kb)*DHEAD;
    {
        const int kh = lane >> 1, dh = (lane & 1)*8;
        #pragma unroll
        for (int L = 0; L < 8; ++L){
            int k = (L & 1)*32 + kh;
            int d = (L >> 1)*16 + dh;
            load_lds16(vg + (size_t)k*DHEAD + d, vbase + L*512);
        }
    }

    short8 qf[3][2];
    const short* qp = (const short*)Qhm + (size_t)bh*QPAD*DHEAD;
    #pragma unroll
    for (int nt = 0; nt < 3; ++nt)
        #pragma unroll
        for (int s = 0; s < 2; ++s)
            qf[nt][s] = *(const short8*)(qp + (nt*16 + lf)*DHEAD + s*32 + g*8);

    floatx4 sa[4][3];
    floatx4 z = {0.f,0.f,0.f,0.f};
    #pragma unroll
    for (int mt = 0; mt < 4; ++mt)
        #pragma unroll
        for (int nt = 0; nt < 3; ++nt) sa[mt][nt] = z;

    const short* kp = (const short*)Khm + ((size_t)bh*SEQ + kb)*DHEAD;
    #pragma unroll
    for (int mt = 0; mt < 4; ++mt){
        const short* kr = kp + (size_t)(mt*16 + lf)*DHEAD + g*8;
        short8 kf0 = *(const short8*)(kr);
        short8 kf1 = *(const short8*)(kr + 32);
        #pragma unroll
        for (int nt = 0; nt < 3; ++nt){
            sa[mt][nt] = __builtin_amdgcn_mfma_f32_16x16x32_bf16(kf0, qf[nt][0], sa[mt][nt], 0, 0, 0);
            sa[mt][nt] = __builtin_amdgcn_mfma_f32_16x16x32_bf16(kf1, qf[nt][1], sa[mt][nt], 0, 0, 0);
        }
    }

    float mx[3], ls[3];
    #pragma unroll
    for (int nt = 0; nt < 3; ++nt){
        float m = sa[0][nt][0];
        #pragma unroll
        for (int mt = 0; mt < 4; ++mt)
            #pragma unroll
            for (int r = 0; r < 4; ++r) m = fmaxf(m, sa[mt][nt][r]);
        m = fmaxf(m, __shfl_xor(m, 16));
        m = fmaxf(m, __shfl_xor(m, 32));
        float l = 0.f;
        #pragma unroll
        for (int mt = 0; mt < 4; ++mt){
            #pragma unroll
            for (int r = 0; r < 4; ++r){
                float p = __expf((sa[mt][nt][r] - m)*0.125f);   // 1/sqrt(64)
                sa[mt][nt][r] = p;
                l += p;
            }
        }
        l += __shfl_xor(l, 16);
        l += __shfl_xor(l, 32);
        mx[nt] = m; ls[nt] = l;
    }

    asm volatile("s_waitcnt vmcnt(0)" ::: "memory");   // V staging landed
    floatx4 oacc[3][4];
    #pragma unroll
    for (int mi = 0; mi < 3; ++mi)
        #pragma unroll
        for (int dt = 0; dt < 4; ++dt) oacc[mi][dt] = z;

    #pragma unroll
    for (int t = 0; t < 4; ++t){
        sh4 pa[3];
        #pragma unroll
        for (int mi = 0; mi < 3; ++mi){
            union { sh4 v; unsigned u[2]; } pk;
            pk.u[0] = f2bf_bits(sa[t][mi][0]) | (f2bf_bits(sa[t][mi][1]) << 16);
            pk.u[1] = f2bf_bits(sa[t][mi][2]) | (f2bf_bits(sa[t][mi][3]) << 16);
            pa[mi] = pk.v;
        }
        #pragma unroll
        for (int dt = 0; dt < 4; ++dt){
            sh4 vf = tr16_read(vbase + dt*1024 + (t*16 + 4*g)*16 + lf);
            #pragma unroll
            for (int mi = 0; mi < 3; ++mi)
                oacc[mi][dt] = mfma16(pa[mi], vf, oacc[mi][dt]);
        }
    }

    float* pbase = part + ((size_t)bh*TOPQ*NKC + ch)*PSTR;
    #pragma unroll
    for (int mi = 0; mi < 3; ++mi){
        #pragma unroll
        for (int r = 0; r < 4; ++r){
            int q = mi*16 + 4*g + r;
            if (q < TOPQ){
                float* pp = pbase + (size_t)q*NKC*PSTR;
                #pragma unroll
                for (int dt = 0; dt < 4; ++dt)
                    pp[dt*16 + lf] = oacc[mi][dt][r];
            }
        }
    }
    #pragma unroll
    for (int nt = 0; nt < 3; ++nt){
        int q = nt*16 + lf;
        if (g == 3 && q < TOPQ){
            float* pp = pbase + (size_t)q*NKC*PSTR;
            pp[64] = mx[nt]*0.125f;
            pp[65] = ls[nt];
        }
    }
}

// pass 2: merge 32 partials per (b,h,q); wave per (q,h), 4 q per block
__global__ __launch_bounds__(256) void attn_reduce_kernel(const float* __restrict__ part,
                                                          float* __restrict__ ctx)
{
    int qc = blockIdx.x, h = blockIdx.y, b = blockIdx.z;
    int w = threadIdx.x >> 6, lane = threadIdx.x & 63;
    int q = qc*4 + w;
    if (q >= TOPQ) return;
    const float* pb = part + (((size_t)(b*NH + h))*TOPQ + q)*NKC*PSTR;
    float M = -3.402823466e38f;
    #pragma unroll
    for (int i = 0; i < NKC; ++i) M = fmaxf(M, pb[i*PSTR + 64]);
    float L = 0.f, a = 0.f;
    #pragma unroll
    for (int i = 0; i < NKC; ++i){
        float sc = __expf(pb[i*PSTR + 64] - M);
        L += pb[i*PSTR + 65]*sc;
        a += pb[i*PSTR + lane]*sc;
    }
    ctx[((size_t)(b*TOPQ + q))*DIM + h*DHEAD + lane] = a/L;
}

// ---------------------------------------------------------------------------
// Round-16 outproj v2: 32x-parallel (was the hidden 60us latency disaster:
// 312 blocks, 512-FMA serial chains). Grid (32, TOPQ, BATCH) = 9984 blocks;
// block = 16 outputs x 16-lane K-split; lane-interleaved coalesced reads.
// ---------------------------------------------------------------------------
__global__ __launch_bounds__(256) void outproj_kernel(const float* __restrict__ ctx,
                                                      const float* __restrict__ ow,
                                                      const float* __restrict__ ob,
                                                      float* __restrict__ sout)
{
    __shared__ float cr[DIM];
    int dblk = blockIdx.x, q = blockIdx.y, b = blockIdx.z;
    int t = threadIdx.x;
    const float* xr = ctx + ((size_t)(b*TOPQ + q))*DIM;
    cr[t] = xr[t]; cr[t + 256] = xr[t + 256];
    __syncthreads();
    int o = t >> 4, ks = t & 15;
    int d0 = dblk*16 + o;
    const float* wr = ow + (size_t)d0*DIM;
    float s = 0.f;
    #pragma unroll
    for (int i = 0; i < 8; ++i){
        int e = i*64 + ks*4;
        float4 wv = *(const float4*)(wr + e);
        float4 cv = *(const float4*)(cr + e);
        s += cv.x*wv.x + cv.y*wv.y + cv.z*wv.z + cv.w*wv.w;
    }
    #pragma unroll
    for (int off = 8; off > 0; off >>= 1) s += __shfl_down(s, off, 16);
    if (ks == 0) sout[((size_t)(b*TOPQ + q))*DIM + d0] = s + ob[d0];
}

// ---------------------------------------------------------------------------
// res+LN2: ONE-PASS paired fp32 reduction (Σv, Σv²); 1 barrier.
// ---------------------------------------------------------------------------
__global__ __launch_bounds__(256) void res_ln2_kernel(const float* __restrict__ x,
                                                      const float* __restrict__ xbar,
                                                      const float* __restrict__ sout,
                                                      const int* __restrict__ selmap,
                                                      const float* __restrict__ g2,
                                                      const float* __restrict__ bt2,
                                                      float* __restrict__ x2,
                                                      bf16* __restrict__ hb)
{
    __shared__ float sbuf[8];
    int row = blockIdx.x;
    int b = row >> 11;
    int t = threadIdx.x;
    int slot = selmap[row];
    const float* ar = (slot >= 0) ? (sout + ((size_t)(b*TOPQ + slot))*DIM)
                                  : (xbar + (size_t)b*DIM);
    size_t base = (size_t)row*DIM;
    float v0 = x[base + t]       + ar[t];
    float v1 = x[base + t + 256] + ar[t + 256];
    x2[base + t] = v0; x2[base + t + 256] = v1;
    float a = v0 + v1, q = v0*v0 + v1*v1;
    #pragma unroll
    for (int off = 32; off > 0; off >>= 1){
        a += __shfl_down(a, off);
        q += __shfl_down(q, off);
    }
    if ((t & 63) == 0){ sbuf[t >> 6] = a; sbuf[4 + (t >> 6)] = q; }
    __syncthreads();
    float sv  = sbuf[0] + sbuf[1] + sbuf[2] + sbuf[3];
    float svv = sbuf[4] + sbuf[5] + sbuf[6] + sbuf[7];
    float m   = sv*(1.f/DIM);
    float var = svv*(1.f/DIM) - m*m;
    float r = 1.f/sqrtf(var + 1e-5f);
    hb[base + t]       = __float2bfloat16((v0 - m)*r*g2[t]     + bt2[t]);
    hb[base + t + 256] = __float2bfloat16((v1 - m)*r*g2[t+256] + bt2[t+256]);
}

// ---------------------------------------------------------------------------
extern "C" void kernel_launch(void* const* d_in, const int* in_sizes, int n_in,
                              void* d_out, int out_size, void* d_ws, size_t ws_size,
                              hipStream_t stream)
{
    (void)in_sizes; (void)n_in; (void)out_size; (void)ws_size;
    const float* x     = (const float*)d_in[0];
    const float* ln1_g = (const float*)d_in[1];
    const float* ln1_b = (const float*)d_in[2];
    const float* in_w  = (const float*)d_in[3];
    const float* in_b  = (const float*)d_in[4];
    const float* out_w = (const float*)d_in[5];
    const float* out_b = (const float*)d_in[6];
    const float* ln2_g = (const float*)d_in[7];
    const float* ln2_b = (const float*)d_in[8];
    const float* w1    = (const float*)d_in[9];
    const float* b1    = (const float*)d_in[10];
    const float* w2    = (const float*)d_in[11];
    const float* b2    = (const float*)d_in[12];
    float* out = (float*)d_out;

    const size_t MB = 1024*1024;
    char* base = (char*)d_ws;
    float* xn_f  = (float*)base;                 // [0,32MiB); reused as x2_f later
    bf16*  xn_b  = (bf16*)(base + 32*MB);        // dead after kv-gemm -> h_b
    bf16*  Khm   = (bf16*)(base + 48*MB);
    bf16*  Vhm   = (bf16*)(base + 64*MB);
    bf16*  h_b   = (bf16*)(base + 32*MB);
    bf16*  h1_b  = (bf16*)(base + 48*MB);        // overwrites Khm/Vhm after attn
    float* x2_f  = xn_f;
    // apart (21 MiB) lives at [80,101) MiB: free during attention (h1_b rows
    // covering it are written only by FFN1, after attn_reduce consumed apart).
    float* apart = (float*)(base + 80*MB);
    char* p = base + 112*MB;
    bf16*  kvw_b  = (bf16*)p;  p += (size_t)1024*DIM*2;        // in_w rows [512,1536) bf16
    bf16*  w1_b   = (bf16*)p;  p += (size_t)FFD*DIM*2;
    bf16*  w2_b   = (bf16*)p;  p += (size_t)DIM*FFD*2;
    double* xbpart= (double*)p; p += (size_t)BATCH*32*DIM*8;
    double* xbar_d= (double*)p; p += (size_t)BATCH*DIM*8;
    float* xbar_f = (float*)p;  p += (size_t)BATCH*DIM*4;
    double* spars = (double*)p; p += (size_t)MROWS*8;
    int*   topidx = (int*)p;    p += (size_t)BATCH*64*4;
    int*   selmap = (int*)p;    p += (size_t)MROWS*4;
    bf16*  Qhm    = (bf16*)p;   p += (size_t)BATCH*NH*QPAD*DHEAD*2;   // 384 KiB
    float* ctxb   = (float*)p;  p += (size_t)BATCH*TOPQ*DIM*4;
    float* sout   = (float*)p;  p += (size_t)BATCH*TOPQ*DIM*4;

    prep_kernel<<<2624, 256, 0, stream>>>(in_w, w1, w2, kvw_b, w1_b, w2_b, selmap);
    ln1_kernel<<<MROWS, 256, 0, stream>>>(x, ln1_g, ln1_b, xn_f, xn_b);
    xbar_part_kernel<<<dim3(32, BATCH), 512, 0, stream>>>(xn_f, xbpart);
    xbar_fin_kernel<<<BATCH, 512, 0, stream>>>(xbpart, xbar_d, xbar_f);
    sparsity_kernel<<<MROWS/4, 256, 0, stream>>>(xn_f, xbar_d, spars);
    topk_kernel<<<BATCH, 256, 0, stream>>>(spars, topidx, selmap, out);
    // KV projection (N=1024 -> head-major K/V): grid 8x128 -> 1024 blocks, lgGX=3
    gemm128_kernel<3, bf16><<<1024, 256, 0, stream>>>(
        xn_b, kvw_b, in_b + DIM, Khm, nullptr, Vhm, DIM, 0, 3);
    qproj_kernel<<<dim3(32, QPAD, BATCH), 256, 0, stream>>>(xn_f, in_w, in_b, topidx, Qhm);
    attn_mfma_kernel<<<dim3(NKC/4, NH, BATCH), 256, 0, stream>>>(Qhm, Khm, Vhm, apart);
    attn_reduce_kernel<<<dim3((TOPQ + 3)/4, NH, BATCH), 256, 0, stream>>>(apart, ctxb);
    outproj_kernel<<<dim3(32, TOPQ, BATCH), 256, 0, stream>>>(ctxb, out_w, out_b, sout);
    res_ln2_kernel<<<MROWS, 256, 0, stream>>>(x, xbar_f, sout, selmap, ln2_g, ln2_b, x2_f, h_b);
    // FFN1: grid 16x128 -> 2048 blocks, lgGX=4
    gemm128_kernel<1, bf16><<<2048, 256, 0, stream>>>(
        h_b, w1_b, b1, h1_b, nullptr, nullptr, DIM, FFD, 4);
    // FFN2: grid 4x128 -> 512 blocks, lgGX=2
    gemm128_kernel<2, float><<<512, 256, 0, stream>>>(
        h1_b, w2_b, b2, out, x2_f, nullptr, FFD, DIM, 2);
}

// Round 10
// 357.520 us; speedup vs baseline: 1.3962x; 1.0215x over previous
//
#include <hip/hip_runtime.h>
#include <hip/hip_bf16.h>
#include <math.h>

#define BATCH 8
#define SEQ   2048
#define DIM   512
#define NH    8
#define DHEAD 64
#define FFD   2048
#define TOPQ  39            // ceil(5*ln(2048)) with factor=5, min_k=5 (fixed harness inputs)
#define MROWS (BATCH*SEQ)   // 16384
#define KC    64            // keys per attention partial chunk (one wave)
#define NKC   (SEQ/KC)      // 32
#define PSTR  66            // partial stride: 64 ctx + m + l
#define QPAD  48            // TOPQ padded to 3 MFMA row-tiles

typedef __hip_bfloat16 bf16;
typedef __attribute__((ext_vector_type(8))) short short8;
typedef __attribute__((ext_vector_type(4))) short sh4;
typedef __attribute__((ext_vector_type(4))) float floatx4;

__device__ __forceinline__ float bf2f(short u){
    return __uint_as_float(((unsigned int)(unsigned short)u) << 16);
}
// pack 2 floats -> 2 bf16 (RNE) in one u32 via intrinsic casts: compiler
// lowers to v_cvt(_pk)_bf16_f32 (guide m240: intrinsic casts are the fast
// path; manual bit-math f2bf_bits blocked the pattern match). Bit-identical.
__device__ __forceinline__ unsigned int pk_bf16(float a, float b){
    union { bf16 h; unsigned short u; } ca, cb;
    ca.h = __float2bfloat16(a); cb.h = __float2bfloat16(b);
    return (unsigned int)ca.u | ((unsigned int)cb.u << 16);
}
// fast gelu, sigmoid form: v*sigmoid(2u) == 0.5v(2-2/(e+1)) exactly; 7 ops
// (was 10). rcp approx ~1ulp << bf16 rounding. Finite v: inf/0 ends safe.
__device__ __forceinline__ float gelu_f(float v){
    float u = v*(0.7978845608028654f + 0.0356774081363f*v*v);
    float e = __expf(-2.f*u);
    return v*__builtin_amdgcn_rcpf(1.f + e);
}

// async global->LDS, 16 B per lane; LDS dest = wave-uniform base + lane*16
__device__ __forceinline__ void load_lds16(const void* g, void* l){
    auto gp = reinterpret_cast<const uint32_t __attribute__((address_space(1)))*>(
        reinterpret_cast<uintptr_t>(g));
    auto lp = reinterpret_cast<uint32_t __attribute__((address_space(3)))*>(
        reinterpret_cast<uintptr_t>(l));
    __builtin_amdgcn_global_load_lds(gp, lp, 16, 0, 0);
}

// 16x16x16 bf16 MFMA (K=16): A/B = 4 bf16/lane (k = (lane>>4)*4 + j), C/D std 16x16 map
__device__ __forceinline__ floatx4 mfma16(sh4 a, sh4 b, floatx4 c){
#if __has_builtin(__builtin_amdgcn_mfma_f32_16x16x16bf16_1k)
    return __builtin_amdgcn_mfma_f32_16x16x16bf16_1k(a, b, c, 0, 0, 0);
#elif __has_builtin(__builtin_amdgcn_mfma_f32_16x16x16_bf16)
    return __builtin_amdgcn_mfma_f32_16x16x16_bf16(a, b, c, 0, 0, 0);
#else
    asm volatile("v_mfma_f32_16x16x16_bf16 %0, %1, %2, %0\n\ts_nop 7\n\ts_nop 7"
                 : "+v"(c) : "v"(a), "v"(b));
    return c;
#endif
}

// transpose-read: 4 bf16 at elem strides {0,16,32,48} from per-lane LDS addr
__device__ __forceinline__ sh4 tr16_read(const short* p){
#if __has_builtin(__builtin_amdgcn_ds_read_tr16_b64_v4i16)
    auto lp = (__attribute__((address_space(3))) sh4*)(uintptr_t)p;
    return __builtin_amdgcn_ds_read_tr16_b64_v4i16(lp);
#elif __has_builtin(__builtin_amdgcn_ds_read_tr16_b64)
    auto lp = (__attribute__((address_space(3))) sh4*)(uintptr_t)p;
    return __builtin_amdgcn_ds_read_tr16_b64(lp);
#else
    sh4 r; r[0] = p[0]; r[1] = p[16]; r[2] = p[32]; r[3] = p[48]; return r;
#endif
}

__device__ __forceinline__ void store_out(bf16* p, float v){ *p = __float2bfloat16(v); }
__device__ __forceinline__ void store_out(float* p, float v){ *p = v; }

// ---------------------------------------------------------------------------
// 128x128-tile GEMM (round-10 proven structure): C = A(MxK)·B(NxK)^T + bias.
// Depth-2 pipeline, counted vmcnt (T4). 3 x 16 KB LDS buffers.
// Round-17: epilogue VALU cut — cvt-based bf16 packing (pk_bf16) + sigmoid
// gelu; K-loop untouched. (VALUBusy 56% was epilogue-dominated: ~1700 VALU
// ops/thread in pack+gelu vs ~480 in the K-loop.)
// EPI: 1 = gelu->bf16, 2 = +x2 -> fp32 (direct stores), 3 = KV head-major.
// ---------------------------------------------------------------------------
template<int EPI, typename OUT_T>
__global__ __launch_bounds__(256, 3) void gemm128_kernel(const bf16* __restrict__ A,
                                                         const bf16* __restrict__ Bm,
                                                         const float* __restrict__ bias,
                                                         OUT_T* __restrict__ C,
                                                         const float* __restrict__ x2,
                                                         bf16* __restrict__ Vhm,
                                                         int K, int ldc, int lgGX)
{
    __shared__ __align__(16) char smem[49152];   // 3 x (As 8KB | Bs 8KB)
    short* CsBase = (short*)smem;

    const int bid = blockIdx.x;
    const int per = gridDim.x >> 3;
    const int lid = (bid & 7)*per + (bid >> 3);
    const int bx  = lid & ((1 << lgGX) - 1);
    const int by  = lid >> lgGX;

    const int t    = threadIdx.x;
    const int lane = t & 63;
    const int w    = t >> 6;
    const int lf   = lane & 15;
    const int ko   = lane >> 4;
    const int slot = ko ^ ((lf >> 1) & 3);
    const int mrow = (w >> 1)*64, ncol = (w & 1)*64;

    floatx4 acc[4][4];
    floatx4 z = {0.f,0.f,0.f,0.f};
    #pragma unroll
    for (int i = 0; i < 4; ++i)
        #pragma unroll
        for (int j = 0; j < 4; ++j) acc[i][j] = z;

    const int srow = w*16 + (lane >> 2);
    const int sq   = lane & 3;
    const int r0 = srow,      kq0 = sq ^ ((r0 >> 1) & 3);
    const int r1 = 64 + srow, kq1 = sq ^ ((r1 >> 1) & 3);
    const short* ga0 = (const short*)A  + ((size_t)by*128 + r0)*K + kq0*8;
    const short* ga1 = (const short*)A  + ((size_t)by*128 + r1)*K + kq1*8;
    const short* gb0 = (const short*)Bm + ((size_t)bx*128 + r0)*K + kq0*8;
    const short* gb1 = (const short*)Bm + ((size_t)bx*128 + r1)*K + kq1*8;
    char* la0 = smem + w*1024;
    char* la1 = smem + 4096 + w*1024;
    char* lb0 = smem + 8192 + w*1024;
    char* lb1 = smem + 12288 + w*1024;

    auto stage = [&](int off){
        load_lds16(ga0, la0 + off); load_lds16(ga1, la1 + off);
        load_lds16(gb0, lb0 + off); load_lds16(gb1, lb1 + off);
        ga0 += 32; ga1 += 32; gb0 += 32; gb1 += 32;
    };
    auto compute = [&](int off){
        const short* As = (const short*)(smem + off);
        const short* Bs = (const short*)(smem + off + 8192);
        short8 af[4], bfr[4];
        #pragma unroll
        for (int i = 0; i < 4; ++i){
            af[i]  = *(const short8*)(As + (mrow + i*16 + lf)*32 + slot*8);
            bfr[i] = *(const short8*)(Bs + (ncol + i*16 + lf)*32 + slot*8);
        }
        #pragma unroll
        for (int i = 0; i < 4; ++i)
            #pragma unroll
            for (int j = 0; j < 4; ++j)
                acc[i][j] = __builtin_amdgcn_mfma_f32_16x16x32_bf16(af[i], bfr[j], acc[i][j], 0, 0, 0);
    };

    const int T = K >> 5;
    stage(0);
    stage(16384);
    int oc = 0, on = 16384, on2 = 32768;
    for (int kt = 0; kt < T - 2; ++kt){
        asm volatile("s_waitcnt vmcnt(4)" ::: "memory");
        __builtin_amdgcn_s_barrier();
        asm volatile("" ::: "memory");
        stage(on2);
        compute(oc);
        int tmp = oc; oc = on; on = on2; on2 = tmp;
    }
    asm volatile("s_waitcnt vmcnt(4)" ::: "memory");
    __builtin_amdgcn_s_barrier();
    asm volatile("" ::: "memory");
    compute(oc);
    { int tmp = oc; oc = on; on = on2; on2 = tmp; }
    asm volatile("s_waitcnt vmcnt(0)" ::: "memory");
    __builtin_amdgcn_s_barrier();
    asm volatile("" ::: "memory");
    compute(oc);
    __syncthreads();

    if constexpr (EPI == 2){
        const int lr = ko*4;
        #pragma unroll
        for (int j = 0; j < 4; ++j){
            int gcol = bx*128 + ncol + j*16 + lf;
            float bv = bias[gcol];
            #pragma unroll
            for (int i = 0; i < 4; ++i){
                #pragma unroll
                for (int r = 0; r < 4; ++r){
                    size_t grow = (size_t)by*128 + mrow + i*16 + lr + r;
                    float v = acc[i][j][r] + bv + x2[grow*ldc + gcol];
                    store_out(&C[grow*ldc + gcol], v);
                }
            }
        }
    } else {
        short* cs = CsBase + w*(64*72);
        const int odd = lf & 1;
        const int rsel = odd*2;
        #pragma unroll
        for (int j = 0; j < 4; ++j){
            float bv = bias[bx*128 + ncol + j*16 + lf];
            #pragma unroll
            for (int i = 0; i < 4; ++i){
                float vv0 = acc[i][j][0] + bv;
                float vv1 = acc[i][j][1] + bv;
                float vv2 = acc[i][j][2] + bv;
                float vv3 = acc[i][j][3] + bv;
                if constexpr (EPI == 1){
                    vv0 = gelu_f(vv0); vv1 = gelu_f(vv1);
                    vv2 = gelu_f(vv2); vv3 = gelu_f(vv3);
                }
                unsigned long long self = (unsigned long long)pk_bf16(vv0, vv1)
                                        | ((unsigned long long)pk_bf16(vv2, vv3) << 32);
                unsigned long long nbr = __shfl_xor(self, 1);
                unsigned long long lo = odd ? nbr : self;
                unsigned long long hi = odd ? self : nbr;
                int colb = 16*j + (lf & ~1);
                unsigned int w0 = (unsigned int)((lo >> (16*rsel)) & 0xffffu)
                                | ((unsigned int)((hi >> (16*rsel)) & 0xffffu) << 16);
                unsigned int w1 = (unsigned int)((lo >> (16*(rsel+1))) & 0xffffu)
                                | ((unsigned int)((hi >> (16*(rsel+1))) & 0xffffu) << 16);
                *(unsigned int*)(cs + (16*i + 4*ko + rsel    )*72 + colb) = w0;
                *(unsigned int*)(cs + (16*i + 4*ko + rsel + 1)*72 + colb) = w1;
            }
        }
        const int subrow = lane >> 3, cq = lane & 7;
        #pragma unroll
        for (int rr = 0; rr < 8; ++rr){
            int rl = rr*8 + subrow;
            short8 vv = *(const short8*)(cs + rl*72 + cq*8);
            if constexpr (EPI == 3){
                int grow = by*128 + mrow + rl;
                int b = grow >> 11, s = grow & 2047;
                int gc = bx*128 + ncol + cq*8;
                int h = (gc >> 6) & 7, d = gc & 63;
                bf16* dst = (gc < 512) ? (bf16*)C : Vhm;
                *(short8*)((short*)dst + (((size_t)(b*NH + h))*SEQ + s)*DHEAD + d) = vv;
            } else {
                size_t grow = (size_t)by*128 + mrow + rl;
                int gcol = bx*128 + ncol + cq*8;
                *(short8*)((short*)C + grow*ldc + gcol) = vv;
            }
        }
    }
}

// ---------------------------------------------------------------------------
// merged prep — selmap init + 3 fp32->bf16 weight converts in ONE launch.
// ---------------------------------------------------------------------------
__global__ __launch_bounds__(256) void prep_kernel(const float* __restrict__ in_w,
                                                   const float* __restrict__ w1,
                                                   const float* __restrict__ w2,
                                                   bf16* __restrict__ kvw_b,
                                                   bf16* __restrict__ w1_b,
                                                   bf16* __restrict__ w2_b,
                                                   int* __restrict__ selmap)
{
    int bid = blockIdx.x, t = threadIdx.x;
    if (bid < 64){
        selmap[bid*256 + t] = -1;
        return;
    }
    const float* src; bf16* dst; int i;
    if (bid < 576){      src = in_w + (size_t)DIM*DIM; dst = kvw_b; i = ((bid - 64)*256 + t)*4; }
    else if (bid < 1600){ src = w1;  dst = w1_b; i = ((bid - 576)*256 + t)*4; }
    else {               src = w2;  dst = w2_b; i = ((bid - 1600)*256 + t)*4; }
    float4 v = *(const float4*)(src + i);
    dst[i+0] = __float2bfloat16(v.x);
    dst[i+1] = __float2bfloat16(v.y);
    dst[i+2] = __float2bfloat16(v.z);
    dst[i+3] = __float2bfloat16(v.w);
}

// ---------------------------------------------------------------------------
// LN1: ONE-PASS paired fp64 reduction (Σx, Σx²) -> var = E[x²]-m². 1 barrier.
// ---------------------------------------------------------------------------
__global__ __launch_bounds__(256) void ln1_kernel(const float* __restrict__ x,
                                                  const float* __restrict__ g,
                                                  const float* __restrict__ bt,
                                                  float* __restrict__ xn,
                                                  bf16* __restrict__ xnb)
{
    __shared__ double sbuf[8];
    int row = blockIdx.x;
    int t = threadIdx.x;
    size_t base = (size_t)row*DIM;
    double x0 = (double)x[base + t];
    double x1 = (double)x[base + t + 256];
    double a = x0 + x1, q = x0*x0 + x1*x1;
    #pragma unroll
    for (int off = 32; off > 0; off >>= 1){
        a += __shfl_down(a, off);
        q += __shfl_down(q, off);
    }
    if ((t & 63) == 0){ sbuf[t >> 6] = a; sbuf[4 + (t >> 6)] = q; }
    __syncthreads();
    double sx  = sbuf[0] + sbuf[1] + sbuf[2] + sbuf[3];
    double sxx = sbuf[4] + sbuf[5] + sbuf[6] + sbuf[7];
    double m   = sx*(1.0/DIM);
    double var = sxx*(1.0/DIM) - m*m;
    double r = 1.0/sqrt(var + 1e-5);
    double y0 = (x0 - m)*r*(double)g[t]     + (double)bt[t];
    double y1 = (x1 - m)*r*(double)g[t+256] + (double)bt[t+256];
    xn[base+t] = (float)y0;       xn[base+t+256] = (float)y1;
    xnb[base+t] = __float2bfloat16((float)y0);
    xnb[base+t+256] = __float2bfloat16((float)y1);
}

// column-mean of xn per batch, fp64 two-stage
__global__ __launch_bounds__(512) void xbar_part_kernel(const float* __restrict__ xn, double* __restrict__ part){
    int b = blockIdx.y, c = blockIdx.x, d = threadIdx.x;
    const float* p = xn + ((size_t)b*SEQ + c*64)*DIM + d;
    double s = 0.0;
    #pragma unroll 8
    for (int i = 0; i < 64; ++i) s += (double)p[(size_t)i*DIM];
    part[((size_t)(b*32 + c))*DIM + d] = s;
}
__global__ __launch_bounds__(512) void xbar_fin_kernel(const double* __restrict__ part,
                                                       double* __restrict__ xbar_d,
                                                       float* __restrict__ xbar_f){
    int b = blockIdx.x, d = threadIdx.x;
    double s = 0.0;
    for (int c = 0; c < 32; ++c) s += part[((size_t)(b*32 + c))*DIM + d];
    s *= (1.0/SEQ);
    xbar_d[(size_t)b*DIM + d] = s;
    xbar_f[(size_t)b*DIM + d] = (float)s;
}

// sparsity*sqrt(D) = Σxn² - dot(xn_row, xbar); fp64 over the SAME fp32 xn
// values ref uses -> ranking margin >> ref's own fp32 noise.
__global__ __launch_bounds__(256) void sparsity_kernel(const float* __restrict__ xn,
                                                       const double* __restrict__ xbar,
                                                       double* __restrict__ sp)
{
    int row  = blockIdx.x*4 + (threadIdx.x >> 6);
    int lane = threadIdx.x & 63;
    int b    = row >> 11;
    const float* xr = xn + (size_t)row*DIM;
    const double* xb = xbar + (size_t)b*DIM;
    double s = 0.0, d2 = 0.0;
    for (int e = lane; e < DIM; e += 64){
        double xv = (double)xr[e];
        s  += xv*xb[e];
        d2 += xv*xv;
    }
    #pragma unroll
    for (int off = 32; off > 0; off >>= 1){
        s  += __shfl_down(s, off);
        d2 += __shfl_down(d2, off);
    }
    if (lane == 0) sp[row] = d2 - s;
}

// ---------------------------------------------------------------------------
// register-resident top-39 (proven): packed monotone u64 order keys.
// ---------------------------------------------------------------------------
__global__ __launch_bounds__(256) void topk_kernel(const double* __restrict__ sp,
                                                   int* __restrict__ topidx,
                                                   int* __restrict__ selmap,
                                                   float* __restrict__ dout)
{
    __shared__ unsigned long long wmax[4];
    int b = blockIdx.x, t = threadIdx.x;
    int lane = t & 63, w = t >> 6;

    unsigned long long pk[8];
    #pragma unroll
    for (int i = 0; i < 8; ++i){
        int idx = i*256 + t;                          // coalesced
        unsigned long long bits =
            (unsigned long long)__double_as_longlong(sp[(size_t)b*SEQ + idx]);
        unsigned long long m = (bits & 0x8000000000000000ull)
                             ? ~bits : (bits | 0x8000000000000000ull);
        pk[i] = (m & ~2047ull) | (unsigned long long)(2047 - idx);
    }
    unsigned long long lm = pk[0];
    #pragma unroll
    for (int i = 1; i < 8; ++i) lm = (pk[i] > lm) ? pk[i] : lm;

    for (int it = 0; it < TOPQ; ++it){
        unsigned long long m = lm;
        #pragma unroll
        for (int off = 32; off > 0; off >>= 1){
            unsigned long long o = __shfl_xor(m, off);
            m = (o > m) ? o : m;
        }
        if (lane == 0) wmax[w] = m;
        __syncthreads();
        unsigned long long g01 = (wmax[0] > wmax[1]) ? wmax[0] : wmax[1];
        unsigned long long g23 = (wmax[2] > wmax[3]) ? wmax[2] : wmax[3];
        unsigned long long g = (g01 > g23) ? g01 : g23;
        int idx = 2047 - (int)(g & 2047ull);
        if (t == 0){
            topidx[b*64 + it] = idx;
            selmap[(size_t)b*SEQ + idx] = it;
        }
        if ((idx & 255) == t){                        // owner removes + recompute
            int slot = idx >> 8;
            #pragma unroll
            for (int i = 0; i < 8; ++i) if (i == slot) pk[i] = 0;
            lm = pk[0];
            #pragma unroll
            for (int i = 1; i < 8; ++i) lm = (pk[i] > lm) ? pk[i] : lm;
        }
        __syncthreads();                              // wmax reuse safety
    }
    if (b == 0 && t == 0) dout[(size_t)MROWS*DIM] = (float)TOPQ/(float)SEQ;
}

// ---------------------------------------------------------------------------
// qproj v2: 32x-parallel (proven round-16). grid (32, QPAD, BATCH); block =
// 16 outputs x 16-lane K-split; lane-interleaved coalesced reads.
// ---------------------------------------------------------------------------
__global__ __launch_bounds__(256) void qproj_kernel(const float* __restrict__ xn,
                                                    const float* __restrict__ in_w,
                                                    const float* __restrict__ in_b,
                                                    const int* __restrict__ topidx,
                                                    bf16* __restrict__ Qhm)
{
    __shared__ float qr[DIM];
    int dblk = blockIdx.x, j = blockIdx.y, b = blockIdx.z;
    int t = threadIdx.x;
    int o = t >> 4, ks = t & 15;
    int d0 = dblk*16 + o;
    int h = d0 >> 6, d = d0 & 63;
    if (j >= TOPQ){
        if (ks == 0)
            Qhm[((size_t)(b*NH + h)*QPAD + j)*DHEAD + d] = __float2bfloat16(0.f);
        return;
    }
    int srow = topidx[b*64 + j];
    const float* xr = xn + ((size_t)(b*SEQ + srow))*DIM;
    qr[t] = xr[t]; qr[t + 256] = xr[t + 256];
    __syncthreads();
    const float* wr = in_w + (size_t)d0*DIM;
    float s = 0.f;
    #pragma unroll
    for (int i = 0; i < 8; ++i){
        int e = i*64 + ks*4;
        float4 wv = *(const float4*)(wr + e);
        float4 cv = *(const float4*)(qr + e);
        s += cv.x*wv.x + cv.y*wv.y + cv.z*wv.z + cv.w*wv.w;
    }
    #pragma unroll
    for (int off = 8; off > 0; off >>= 1) s += __shfl_down(s, off, 16);
    if (ks == 0)
        Qhm[((size_t)(b*NH + h)*QPAD + j)*DHEAD + d] = __float2bfloat16(s + in_b[d0]);
}

// ---------------------------------------------------------------------------
// MFMA split-K attention partial (KC=64, 2 blocks/CU).
// ---------------------------------------------------------------------------
__global__ __launch_bounds__(256, 1) void attn_mfma_kernel(const bf16* __restrict__ Qhm,
                                                           const bf16* __restrict__ Khm,
                                                           const bf16* __restrict__ Vhm,
                                                           float* __restrict__ part)
{
    __shared__ __align__(16) short vsm[4*4096];   // 32 KB: 4 waves x (64k x 64d)
    const int bh   = blockIdx.z*NH + blockIdx.y;
    const int w    = threadIdx.x >> 6;
    const int lane = threadIdx.x & 63;
    const int ch   = blockIdx.x*4 + w;           // chunk 0..31
    const int kb   = ch*KC;                      // first key of chunk
    const int lf   = lane & 15;
    const int g    = lane >> 4;

    short* vbase = vsm + w*4096;
    const short* vg = (const short*)Vhm + ((size_t)bh*SEQ + kb)*DHEAD;
    {
        const int kh = lane >> 1, dh = (lane & 1)*8;
        #pragma unroll
        for (int L = 0; L < 8; ++L){
            int k = (L & 1)*32 + kh;
            int d = (L >> 1)*16 + dh;
            load_lds16(vg + (size_t)k*DHEAD + d, vbase + L*512);
        }
    }

    short8 qf[3][2];
    const short* qp = (const short*)Qhm + (size_t)bh*QPAD*DHEAD;
    #pragma unroll
    for (int nt = 0; nt < 3; ++nt)
        #pragma unroll
        for (int s = 0; s < 2; ++s)
            qf[nt][s] = *(const short8*)(qp + (nt*16 + lf)*DHEAD + s*32 + g*8);

    floatx4 sa[4][3];
    floatx4 z = {0.f,0.f,0.f,0.f};
    #pragma unroll
    for (int mt = 0; mt < 4; ++mt)
        #pragma unroll
        for (int nt = 0; nt < 3; ++nt) sa[mt][nt] = z;

    const short* kp = (const short*)Khm + ((size_t)bh*SEQ + kb)*DHEAD;
    #pragma unroll
    for (int mt = 0; mt < 4; ++mt){
        const short* kr = kp + (size_t)(mt*16 + lf)*DHEAD + g*8;
        short8 kf0 = *(const short8*)(kr);
        short8 kf1 = *(const short8*)(kr + 32);
        #pragma unroll
        for (int nt = 0; nt < 3; ++nt){
            sa[mt][nt] = __builtin_amdgcn_mfma_f32_16x16x32_bf16(kf0, qf[nt][0], sa[mt][nt], 0, 0, 0);
            sa[mt][nt] = __builtin_amdgcn_mfma_f32_16x16x32_bf16(kf1, qf[nt][1], sa[mt][nt], 0, 0, 0);
        }
    }

    float mx[3], ls[3];
    #pragma unroll
    for (int nt = 0; nt < 3; ++nt){
        float m = sa[0][nt][0];
        #pragma unroll
        for (int mt = 0; mt < 4; ++mt)
            #pragma unroll
            for (int r = 0; r < 4; ++r) m = fmaxf(m, sa[mt][nt][r]);
        m = fmaxf(m, __shfl_xor(m, 16));
        m = fmaxf(m, __shfl_xor(m, 32));
        float l = 0.f;
        #pragma unroll
        for (int mt = 0; mt < 4; ++mt){
            #pragma unroll
            for (int r = 0; r < 4; ++r){
                float p = __expf((sa[mt][nt][r] - m)*0.125f);   // 1/sqrt(64)
                sa[mt][nt][r] = p;
                l += p;
            }
        }
        l += __shfl_xor(l, 16);
        l += __shfl_xor(l, 32);
        mx[nt] = m; ls[nt] = l;
    }

    asm volatile("s_waitcnt vmcnt(0)" ::: "memory");   // V staging landed
    floatx4 oacc[3][4];
    #pragma unroll
    for (int mi = 0; mi < 3; ++mi)
        #pragma unroll
        for (int dt = 0; dt < 4; ++dt) oacc[mi][dt] = z;

    #pragma unroll
    for (int t = 0; t < 4; ++t){
        sh4 pa[3];
        #pragma unroll
        for (int mi = 0; mi < 3; ++mi){
            union { sh4 v; unsigned u[2]; } pk;
            pk.u[0] = pk_bf16(sa[t][mi][0], sa[t][mi][1]);
            pk.u[1] = pk_bf16(sa[t][mi][2], sa[t][mi][3]);
            pa[mi] = pk.v;
        }
        #pragma unroll
        for (int dt = 0; dt < 4; ++dt){
            sh4 vf = tr16_read(vbase + dt*1024 + (t*16 + 4*g)*16 + lf);
            #pragma unroll
            for (int mi = 0; mi < 3; ++mi)
                oacc[mi][dt] = mfma16(pa[mi], vf, oacc[mi][dt]);
        }
    }

    float* pbase = part + ((size_t)bh*TOPQ*NKC + ch)*PSTR;
    #pragma unroll
    for (int mi = 0; mi < 3; ++mi){
        #pragma unroll
        for (int r = 0; r < 4; ++r){
            int q = mi*16 + 4*g + r;
            if (q < TOPQ){
                float* pp = pbase + (size_t)q*NKC*PSTR;
                #pragma unroll
                for (int dt = 0; dt < 4; ++dt)
                    pp[dt*16 + lf] = oacc[mi][dt][r];
            }
        }
    }
    #pragma unroll
    for (int nt = 0; nt < 3; ++nt){
        int q = nt*16 + lf;
        if (g == 3 && q < TOPQ){
            float* pp = pbase + (size_t)q*NKC*PSTR;
            pp[64] = mx[nt]*0.125f;
            pp[65] = ls[nt];
        }
    }
}

// pass 2: merge 32 partials per (b,h,q); wave per (q,h), 4 q per block
__global__ __launch_bounds__(256) void attn_reduce_kernel(const float* __restrict__ part,
                                                          float* __restrict__ ctx)
{
    int qc = blockIdx.x, h = blockIdx.y, b = blockIdx.z;
    int w = threadIdx.x >> 6, lane = threadIdx.x & 63;
    int q = qc*4 + w;
    if (q >= TOPQ) return;
    const float* pb = part + (((size_t)(b*NH + h))*TOPQ + q)*NKC*PSTR;
    float M = -3.402823466e38f;
    #pragma unroll
    for (int i = 0; i < NKC; ++i) M = fmaxf(M, pb[i*PSTR + 64]);
    float L = 0.f, a = 0.f;
    #pragma unroll
    for (int i = 0; i < NKC; ++i){
        float sc = __expf(pb[i*PSTR + 64] - M);
        L += pb[i*PSTR + 65]*sc;
        a += pb[i*PSTR + lane]*sc;
    }
    ctx[((size_t)(b*TOPQ + q))*DIM + h*DHEAD + lane] = a/L;
}

// ---------------------------------------------------------------------------
// outproj v2: 32x-parallel (proven round-16).
// ---------------------------------------------------------------------------
__global__ __launch_bounds__(256) void outproj_kernel(const float* __restrict__ ctx,
                                                      const float* __restrict__ ow,
                                                      const float* __restrict__ ob,
                                                      float* __restrict__ sout)
{
    __shared__ float cr[DIM];
    int dblk = blockIdx.x, q = blockIdx.y, b = blockIdx.z;
    int t = threadIdx.x;
    const float* xr = ctx + ((size_t)(b*TOPQ + q))*DIM;
    cr[t] = xr[t]; cr[t + 256] = xr[t + 256];
    __syncthreads();
    int o = t >> 4, ks = t & 15;
    int d0 = dblk*16 + o;
    const float* wr = ow + (size_t)d0*DIM;
    float s = 0.f;
    #pragma unroll
    for (int i = 0; i < 8; ++i){
        int e = i*64 + ks*4;
        float4 wv = *(const float4*)(wr + e);
        float4 cv = *(const float4*)(cr + e);
        s += cv.x*wv.x + cv.y*wv.y + cv.z*wv.z + cv.w*wv.w;
    }
    #pragma unroll
    for (int off = 8; off > 0; off >>= 1) s += __shfl_down(s, off, 16);
    if (ks == 0) sout[((size_t)(b*TOPQ + q))*DIM + d0] = s + ob[d0];
}

// ---------------------------------------------------------------------------
// res+LN2: ONE-PASS paired fp32 reduction (Σv, Σv²); 1 barrier.
// ---------------------------------------------------------------------------
__global__ __launch_bounds__(256) void res_ln2_kernel(const float* __restrict__ x,
                                                      const float* __restrict__ xbar,
                                                      const float* __restrict__ sout,
                                                      const int* __restrict__ selmap,
                                                      const float* __restrict__ g2,
                                                      const float* __restrict__ bt2,
                                                      float* __restrict__ x2,
                                                      bf16* __restrict__ hb)
{
    __shared__ float sbuf[8];
    int row = blockIdx.x;
    int b = row >> 11;
    int t = threadIdx.x;
    int slot = selmap[row];
    const float* ar = (slot >= 0) ? (sout + ((size_t)(b*TOPQ + slot))*DIM)
                                  : (xbar + (size_t)b*DIM);
    size_t base = (size_t)row*DIM;
    float v0 = x[base + t]       + ar[t];
    float v1 = x[base + t + 256] + ar[t + 256];
    x2[base + t] = v0; x2[base + t + 256] = v1;
    float a = v0 + v1, q = v0*v0 + v1*v1;
    #pragma unroll
    for (int off = 32; off > 0; off >>= 1){
        a += __shfl_down(a, off);
        q += __shfl_down(q, off);
    }
    if ((t & 63) == 0){ sbuf[t >> 6] = a; sbuf[4 + (t >> 6)] = q; }
    __syncthreads();
    float sv  = sbuf[0] + sbuf[1] + sbuf[2] + sbuf[3];
    float svv = sbuf[4] + sbuf[5] + sbuf[6] + sbuf[7];
    float m   = sv*(1.f/DIM);
    float var = svv*(1.f/DIM) - m*m;
    float r = 1.f/sqrtf(var + 1e-5f);
    hb[base + t]       = __float2bfloat16((v0 - m)*r*g2[t]     + bt2[t]);
    hb[base + t + 256] = __float2bfloat16((v1 - m)*r*g2[t+256] + bt2[t+256]);
}

// ---------------------------------------------------------------------------
extern "C" void kernel_launch(void* const* d_in, const int* in_sizes, int n_in,
                              void* d_out, int out_size, void* d_ws, size_t ws_size,
                              hipStream_t stream)
{
    (void)in_sizes; (void)n_in; (void)out_size; (void)ws_size;
    const float* x     = (const float*)d_in[0];
    const float* ln1_g = (const float*)d_in[1];
    const float* ln1_b = (const float*)d_in[2];
    const float* in_w  = (const float*)d_in[3];
    const float* in_b  = (const float*)d_in[4];
    const float* out_w = (const float*)d_in[5];
    const float* out_b = (const float*)d_in[6];
    const float* ln2_g = (const float*)d_in[7];
    const float* ln2_b = (const float*)d_in[8];
    const float* w1    = (const float*)d_in[9];
    const float* b1    = (const float*)d_in[10];
    const float* w2    = (const float*)d_in[11];
    const float* b2    = (const float*)d_in[12];
    float* out = (float*)d_out;

    const size_t MB = 1024*1024;
    char* base = (char*)d_ws;
    float* xn_f  = (float*)base;                 // [0,32MiB); reused as x2_f later
    bf16*  xn_b  = (bf16*)(base + 32*MB);        // dead after kv-gemm -> h_b
    bf16*  Khm   = (bf16*)(base + 48*MB);
    bf16*  Vhm   = (bf16*)(base + 64*MB);
    bf16*  h_b   = (bf16*)(base + 32*MB);
    bf16*  h1_b  = (bf16*)(base + 48*MB);        // overwrites Khm/Vhm after attn
    float* x2_f  = xn_f;
    // apart (21 MiB) lives at [80,101) MiB: free during attention (h1_b rows
    // covering it are written only by FFN1, after attn_reduce consumed apart).
    float* apart = (float*)(base + 80*MB);
    char* p = base + 112*MB;
    bf16*  kvw_b  = (bf16*)p;  p += (size_t)1024*DIM*2;        // in_w rows [512,1536) bf16
    bf16*  w1_b   = (bf16*)p;  p += (size_t)FFD*DIM*2;
    bf16*  w2_b   = (bf16*)p;  p += (size_t)DIM*FFD*2;
    double* xbpart= (double*)p; p += (size_t)BATCH*32*DIM*8;
    double* xbar_d= (double*)p; p += (size_t)BATCH*DIM*8;
    float* xbar_f = (float*)p;  p += (size_t)BATCH*DIM*4;
    double* spars = (double*)p; p += (size_t)MROWS*8;
    int*   topidx = (int*)p;    p += (size_t)BATCH*64*4;
    int*   selmap = (int*)p;    p += (size_t)MROWS*4;
    bf16*  Qhm    = (bf16*)p;   p += (size_t)BATCH*NH*QPAD*DHEAD*2;   // 384 KiB
    float* ctxb   = (float*)p;  p += (size_t)BATCH*TOPQ*DIM*4;
    float* sout   = (float*)p;  p += (size_t)BATCH*TOPQ*DIM*4;

    prep_kernel<<<2624, 256, 0, stream>>>(in_w, w1, w2, kvw_b, w1_b, w2_b, selmap);
    ln1_kernel<<<MROWS, 256, 0, stream>>>(x, ln1_g, ln1_b, xn_f, xn_b);
    xbar_part_kernel<<<dim3(32, BATCH), 512, 0, stream>>>(xn_f, xbpart);
    xbar_fin_kernel<<<BATCH, 512, 0, stream>>>(xbpart, xbar_d, xbar_f);
    sparsity_kernel<<<MROWS/4, 256, 0, stream>>>(xn_f, xbar_d, spars);
    topk_kernel<<<BATCH, 256, 0, stream>>>(spars, topidx, selmap, out);
    // KV projection (N=1024 -> head-major K/V): grid 8x128 -> 1024 blocks, lgGX=3
    gemm128_kernel<3, bf16><<<1024, 256, 0, stream>>>(
        xn_b, kvw_b, in_b + DIM, Khm, nullptr, Vhm, DIM, 0, 3);
    qproj_kernel<<<dim3(32, QPAD, BATCH), 256, 0, stream>>>(xn_f, in_w, in_b, topidx, Qhm);
    attn_mfma_kernel<<<dim3(NKC/4, NH, BATCH), 256, 0, stream>>>(Qhm, Khm, Vhm, apart);
    attn_reduce_kernel<<<dim3((TOPQ + 3)/4, NH, BATCH), 256, 0, stream>>>(apart, ctxb);
    outproj_kernel<<<dim3(32, TOPQ, BATCH), 256, 0, stream>>>(ctxb, out_w, out_b, sout);
    res_ln2_kernel<<<MROWS, 256, 0, stream>>>(x, xbar_f, sout, selmap, ln2_g, ln2_b, x2_f, h_b);
    // FFN1: grid 16x128 -> 2048 blocks, lgGX=4
    gemm128_kernel<1, bf16><<<2048, 256, 0, stream>>>(
        h_b, w1_b, b1, h1_b, nullptr, nullptr, DIM, FFD, 4);
    // FFN2: grid 4x128 -> 512 blocks, lgGX=2
    gemm128_kernel<2, float><<<512, 256, 0, stream>>>(
        h1_b, w2_b, b2, out, x2_f, nullptr, FFD, DIM, 2);
}